// Round 2
// baseline (962.193 us; speedup 1.0000x reference)
//
#include <hip/hip_runtime.h>
#include <hip/hip_bf16.h>
#include <math.h>

typedef unsigned short u16;
typedef __attribute__((ext_vector_type(8))) unsigned short u16v8;
typedef __attribute__((ext_vector_type(8))) __bf16 bf16v8;
typedef __attribute__((ext_vector_type(4))) float f32v4;

#define BB 2
#define MM 16384           // H*W
#define CC 256
#define NHH 8
#define PTS 4
#define BMTOT 32768        // B*M
#define SCALEF 0.17677669529663687f
#define PECOEF 0.03597789207803197f   // ln(10000)/256

__device__ __forceinline__ u16 f2bf(float f) {
    union { float f; unsigned u; } v; v.f = f;
    unsigned u = v.u;
    return (u16)((u + 0x7fffu + ((u >> 16) & 1u)) >> 16);
}
__device__ __forceinline__ float bf2f(u16 u) {
    union { unsigned u; float f; } v; v.u = ((unsigned)u) << 16; return v.f;
}
__device__ __forceinline__ float rsum32(float v) {
    #pragma unroll
    for (int m = 16; m; m >>= 1) v += __shfl_xor(v, m, 32);
    return v;
}

// ---------------- prep: zero page + weight bf16 conversions ----------------
__global__ __launch_bounds__(256)
void prep_kernel(const float* __restrict__ off_w1, const float* __restrict__ wq,
                 const float* __restrict__ wx, const float* __restrict__ fw2,
                 u16* zp, u16* w1t, u16* wqb, u16* wxb, u16* fw2b)
{
    const size_t n_zp = 128, n_w1 = 589824, n_q = 65536, n_f2 = 131072;
    const size_t total = n_zp + n_w1 + 2 * n_q + n_f2;
    for (size_t i = (size_t)blockIdx.x * 256 + threadIdx.x; i < total;
         i += (size_t)gridDim.x * 256) {
        size_t j = i;
        if (j < n_zp) { zp[j] = 0; continue; }
        j -= n_zp;
        if (j < n_w1) {  // w1t[oc][tap*256+ic] = off_w1[oc][ic][tap]
            size_t oc = j / 2304, r = j % 2304, tap = r >> 8, ic = r & 255;
            w1t[j] = f2bf(off_w1[(oc * 256 + ic) * 9 + tap]);
            continue;
        }
        j -= n_w1;
        if (j < n_q) { wqb[j] = f2bf(wq[j]); continue; }
        j -= n_q;
        if (j < n_q) { wxb[j] = f2bf(wx[j]); continue; }
        j -= n_q;
        fw2b[j] = f2bf(fw2[j]);
    }
}

// ---------------- add positional encoding, transpose to pixel-major bf16 ----
__global__ __launch_bounds__(256)
void addpe_kernel(const float* __restrict__ q, const float* __restrict__ x,
                  u16* __restrict__ qpe, u16* __restrict__ xpe)
{
    __shared__ float lq[64][65], lx[64][65];
    const int m0 = blockIdx.x * 64, c0 = blockIdx.y * 64, b = blockIdx.z;
    const int tid = threadIdx.x;
    {
        const int ml = tid & 63, c4 = tid >> 6;
        for (int s = 0; s < 16; ++s) {
            int cl = s * 4 + c4;
            int c = c0 + cl, m = m0 + ml;
            float dv = expf(-(float)(c & ~1) * PECOEF);
            float a = (float)m * dv;
            float pe = (c & 1) ? cosf(a) : sinf(a);
            size_t gi = ((size_t)b * CC + c) * MM + m;
            lq[cl][ml] = q[gi] + pe;
            lx[cl][ml] = x[gi] + pe;
        }
    }
    __syncthreads();
    {
        const int cl = tid & 63, m4 = tid >> 6;
        for (int s = 0; s < 16; ++s) {
            int ml = s * 4 + m4;
            size_t oi = ((size_t)b * MM + m0 + ml) * CC + c0 + cl;
            qpe[oi] = f2bf(lq[cl][ml]);
            xpe[oi] = f2bf(lx[cl][ml]);
        }
    }
}

// ---------------- bf16 MFMA GEMM: C[row,col] = sum_k A[row,k]*W[col,k] (+bias)
// AMODE 0: A is row-major bf16 (rows x K). AMODE 1: implicit im2col 3x3 pad=1.
// OUTBF: 1 -> store bf16, 0 -> store fp32.
template<int AMODE, int OUTBF>
__global__ __launch_bounds__(256, 2)
void gemm_bt(const u16* __restrict__ A, const u16* __restrict__ Bw,
             const float* __restrict__ bias, void* __restrict__ Cout,
             int K, int N, const u16* __restrict__ zp)
{
    __shared__ u16 lA[128 * 32];
    __shared__ u16 lB[128 * 32];
    const int tid = threadIdx.x;
    const int w = tid >> 6, l = tid & 63;
    const int gm = blockIdx.x, gn = blockIdx.y;
    const int wm = w >> 1, wn = w & 1;
    const int arow = (w << 4) + (l >> 2);   // 0..63 per staging round
    const int kq = (l & 3) << 3;            // k offset 0,8,16,24
    f32v4 acc[4][4] = {};

    for (int k0 = 0; k0 < K; k0 += 32) {
        u16v8 ra[2], rb[2];
        #pragma unroll
        for (int r = 0; r < 2; ++r) {
            const int row = (r << 6) + arow;
            const u16* gp;
            if (AMODE == 0) {
                gp = A + (size_t)(gm * 128 + row) * K + (k0 + kq);
            } else {
                int grow = gm * 128 + row;
                int b = grow >> 14, m = grow & 16383;
                int y = m >> 7, xx = m & 127;
                int kk = k0 + kq;
                int tap = kk >> 8, ic = kk & 255;
                int t3 = tap / 3;
                int py = y + t3 - 1, px = xx + (tap - t3 * 3) - 1;
                bool ok = ((unsigned)py < 128u) && ((unsigned)px < 128u);
                gp = ok ? (A + (((size_t)((b << 14) + (py << 7) + px)) << 8) + ic) : zp;
            }
            ra[r] = *(const u16v8*)gp;
        }
        #pragma unroll
        for (int r = 0; r < 2; ++r) {
            const int col = (r << 6) + arow;
            rb[r] = *(const u16v8*)(Bw + (size_t)(gn * 128 + col) * K + (k0 + kq));
        }
        #pragma unroll
        for (int r = 0; r < 2; ++r) {
            *(u16v8*)&lA[r * 2048 + w * 512 + l * 8] = ra[r];
            *(u16v8*)&lB[r * 2048 + w * 512 + l * 8] = rb[r];
        }
        __syncthreads();
        bf16v8 af[4], bf[4];
        #pragma unroll
        for (int i = 0; i < 4; ++i) {
            af[i] = *(const bf16v8*)&lA[((wm << 6) + (i << 4) + (l & 15)) * 32 + ((l >> 4) << 3)];
            bf[i] = *(const bf16v8*)&lB[((wn << 6) + (i << 4) + (l & 15)) * 32 + ((l >> 4) << 3)];
        }
        #pragma unroll
        for (int i = 0; i < 4; ++i)
            #pragma unroll
            for (int j = 0; j < 4; ++j)
                acc[i][j] = __builtin_amdgcn_mfma_f32_16x16x32_bf16(af[i], bf[j], acc[i][j], 0, 0, 0);
        __syncthreads();
    }

    const int l15 = l & 15, l4 = l >> 4;
    #pragma unroll
    for (int i = 0; i < 4; ++i) {
        int row = gm * 128 + (wm << 6) + (i << 4) + (l4 << 2);
        #pragma unroll
        for (int j = 0; j < 4; ++j) {
            int col = gn * 128 + (wn << 6) + (j << 4) + l15;
            float bv = bias ? bias[col] : 0.0f;
            #pragma unroll
            for (int r = 0; r < 4; ++r) {
                float val = acc[i][j][r] + bv;
                if (OUTBF) ((u16*)Cout)[(size_t)(row + r) * N + col] = f2bf(val);
                else       ((float*)Cout)[(size_t)(row + r) * N + col] = val;
            }
        }
    }
}

// ---------------- GroupNorm stats stage 1 (bf16 input) ----------------
__global__ __launch_bounds__(256)
void stats1_bf_kernel(const u16* __restrict__ a, float* __restrict__ part)
{
    __shared__ float ls[256], lss[256];
    const int blk = blockIdx.x;           // B*32 blocks
    const int bb = blk >> 5, ch = blk & 31;
    const size_t base = ((size_t)bb * MM + ch * 512) * CC;
    const int tid = threadIdx.x;
    float s = 0.f, ss = 0.f;
    for (int p = 0; p < 512; ++p) {
        float v = bf2f(a[base + (size_t)p * CC + tid]);
        s += v; ss += v * v;
    }
    ls[tid] = s; lss[tid] = ss;
    __syncthreads();
    if (tid < 8) {
        float S = 0.f, SS = 0.f;
        for (int j = 0; j < 32; ++j) { S += ls[tid * 32 + j]; SS += lss[tid * 32 + j]; }
        part[(blk * 8 + tid) * 2] = S;
        part[(blk * 8 + tid) * 2 + 1] = SS;
    }
}

// stage 1, mixed fp32 + bf16 inputs (for y2 + res2)
__global__ __launch_bounds__(256)
void stats1_mix_kernel(const float* __restrict__ a, const u16* __restrict__ b2,
                       float* __restrict__ part)
{
    __shared__ float ls[256], lss[256];
    const int blk = blockIdx.x;
    const int bb = blk >> 5, ch = blk & 31;
    const size_t base = ((size_t)bb * MM + ch * 512) * CC;
    const int tid = threadIdx.x;
    float s = 0.f, ss = 0.f;
    for (int p = 0; p < 512; ++p) {
        float v = a[base + (size_t)p * CC + tid] + bf2f(b2[base + (size_t)p * CC + tid]);
        s += v; ss += v * v;
    }
    ls[tid] = s; lss[tid] = ss;
    __syncthreads();
    if (tid < 8) {
        float S = 0.f, SS = 0.f;
        for (int j = 0; j < 32; ++j) { S += ls[tid * 32 + j]; SS += lss[tid * 32 + j]; }
        part[(blk * 8 + tid) * 2] = S;
        part[(blk * 8 + tid) * 2 + 1] = SS;
    }
}

__global__ __launch_bounds__(64)
void stats2_kernel(const float* __restrict__ part, float2* __restrict__ stats, int NG)
{
    const int t = threadIdx.x;
    if (t >= 2 * NG) return;
    const int bb = t / NG, g = t % NG;
    const int gsub = 8 / NG;
    float S = 0.f, SS = 0.f;
    for (int ch = 0; ch < 32; ++ch)
        for (int j = 0; j < gsub; ++j) {
            int idx = (bb * 32 + ch) * 8 + g * gsub + j;
            S += part[idx * 2]; SS += part[idx * 2 + 1];
        }
    const float cnt = (256.0f / NG) * 16384.0f;
    float mu = S / cnt;
    float var = SS / cnt - mu * mu;
    stats[bb * NG + g] = make_float2(mu, rsqrtf(var + 1e-5f));
}

// ---------------- conv_offset tail: GN(1)+ReLU -> grouped 1x1 -> tanh -------
// stores only the tanh value (bf16); sampling coord = pixel + 0.5 + tanh.
__global__ __launch_bounds__(256)
void offset_kernel(const u16* __restrict__ t, const float2* __restrict__ stats_t,
                   const float* __restrict__ gng, const float* __restrict__ gnb,
                   const float* __restrict__ w2, u16* __restrict__ pos)
{
    __shared__ float lt[4 * 256];
    const int tid = threadIdx.x;
    const int bm0 = blockIdx.x * 4;
    const int b = bm0 >> 14;
    const float2 st = stats_t[b];
    for (int idx = tid; idx < 1024; idx += 256) {
        int pix = idx >> 8, c = idx & 255;
        float v = bf2f(t[(size_t)(bm0 + pix) * CC + c]);
        v = (v - st.x) * st.y * gng[c] + gnb[c];
        lt[idx] = fmaxf(v, 0.0f);
    }
    __syncthreads();
    const int pix = tid >> 6, go = tid & 63;
    const int g = go >> 3, o = go & 7;
    float s = 0.f;
    #pragma unroll
    for (int ci = 0; ci < 32; ++ci) {
        int ce = (ci + g * 4) & 31;                 // bank rotation
        s += w2[(g * 8 + o) * 32 + ce] * lt[pix * 256 + g * 32 + ce];
    }
    const int m = (bm0 + pix) & 16383;
    const int p = o >> 1, c2 = o & 1;
    pos[((((size_t)b * NHH + g) * PTS + p) * MM + m) * 2 + c2] = f2bf(tanhf(s));
}

// ---------------- channel-attention pooling + gate + weight folding --------
__global__ __launch_bounds__(256)
void pool1_kernel(const u16* __restrict__ xc, float* __restrict__ pmax,
                  float* __restrict__ psum)
{
    const int blk = blockIdx.x;
    const int bb = blk >> 5, ch = blk & 31;
    const size_t base = ((size_t)bb * MM + ch * 512) * CC;
    const int tid = threadIdx.x;
    float mx = -1e30f, s = 0.f;
    for (int p = 0; p < 512; ++p) {
        float v = bf2f(xc[base + (size_t)p * CC + tid]);
        mx = fmaxf(mx, v); s += v;
    }
    pmax[blk * 256 + tid] = mx;
    psum[blk * 256 + tid] = s;
}

__global__ __launch_bounds__(256)
void pool2_gate_kernel(const float* __restrict__ pmax, const float* __restrict__ psum,
                       const float* __restrict__ ca_w, float* __restrict__ gate)
{
    __shared__ float sv[256];
    const int bb = blockIdx.x, tid = threadIdx.x;
    float mx = -1e30f, s = 0.f;
    for (int ch = 0; ch < 32; ++ch) {
        mx = fmaxf(mx, pmax[(bb * 32 + ch) * 256 + tid]);
        s += psum[(bb * 32 + ch) * 256 + tid];
    }
    sv[tid] = mx + s * (1.0f / 16384.0f);   // mx + av
    __syncthreads();
    float acc = 0.f;
    for (int ci = 0; ci < 256; ++ci) acc += ca_w[tid * 256 + ci] * sv[ci];
    gate[bb * 256 + tid] = 1.0f / (1.0f + expf(-acc));
}

// fold (1+gate[b,c]) into wkh/wvh columns, per batch -> bf16
__global__ __launch_bounds__(256)
void scalekv_kernel(const float* __restrict__ wkh, const float* __restrict__ wvh,
                    const float* __restrict__ gate, u16* __restrict__ wkhs,
                    u16* __restrict__ wvhs)
{
    const int n1 = 512 * 256;                   // per-batch weight count
    for (int i = blockIdx.x * 256 + threadIdx.x; i < 4 * n1;
         i += gridDim.x * 256) {
        int which = i / (2 * n1);               // 0: kh, 1: vh
        int r = i % (2 * n1);
        int b = r / n1, j = r % n1;
        float gsc = 1.0f + gate[b * 256 + (j & 255)];
        if (which == 0) wkhs[b * n1 + j] = f2bf(wkh[j] * gsc);
        else            wvhs[b * n1 + j] = f2bf(wvh[j] * gsc);
    }
}

// ---------------- fused deformable sampling + k/v proj + attention ----------
__global__ __launch_bounds__(256)
void attn_kernel(const u16* __restrict__ qp, const u16* __restrict__ xc,
                 const u16* __restrict__ kh, const u16* __restrict__ vh,
                 const u16* __restrict__ pos, const float* __restrict__ wk,
                 const float* __restrict__ wv, u16* __restrict__ attno)
{
    __shared__ float smp[8][4][32];
    const int tid = threadIdx.x;
    const int g = tid >> 5, d = tid & 31;
    const int bh = blockIdx.y;
    const int b = bh >> 3, nh = bh & 7;
    const int m0 = blockIdx.x * 64;
    float wkr[32], wvr[32];
    #pragma unroll
    for (int e = 0; e < 32; ++e) {
        wkr[e] = wk[(nh * 32 + d) * 32 + e];
        wvr[e] = wv[(nh * 32 + d) * 32 + e];
    }
    for (int i = 0; i < 8; ++i) {
        const int m = m0 + i * 8 + g;
        const size_t bm = (size_t)b * MM + m;
        const float qd = bf2f(qp[bm * CC + nh * 32 + d]);
        const int yy = m >> 7, xx = m & 127;
        #pragma unroll
        for (int p = 0; p < 4; ++p) {
            const u16* pp = pos + ((((size_t)b * NHH + nh) * PTS + p) * MM + m) * 2;
            float gy = (float)yy + 0.5f + bf2f(pp[0]);
            float gx = (float)xx + 0.5f + bf2f(pp[1]);
            int ix0 = (int)floorf(gx), iy0 = (int)floorf(gy);
            float fx = gx - (float)ix0, fy = gy - (float)iy0;
            float w00 = (1.f - fx) * (1.f - fy), w10 = fx * (1.f - fy);
            float w01 = (1.f - fx) * fy, w11 = fx * fy;
            float sv = 0.f;
            const size_t hb = (size_t)b * MM;
            const int co = nh * 32 + d;
            if ((unsigned)ix0 < 128u && (unsigned)iy0 < 128u)
                sv += w00 * bf2f(xc[(hb + iy0 * 128 + ix0) * CC + co]);
            if ((unsigned)(ix0 + 1) < 128u && (unsigned)iy0 < 128u)
                sv += w10 * bf2f(xc[(hb + iy0 * 128 + ix0 + 1) * CC + co]);
            if ((unsigned)ix0 < 128u && (unsigned)(iy0 + 1) < 128u)
                sv += w01 * bf2f(xc[(hb + (iy0 + 1) * 128 + ix0) * CC + co]);
            if ((unsigned)(ix0 + 1) < 128u && (unsigned)(iy0 + 1) < 128u)
                sv += w11 * bf2f(xc[(hb + (iy0 + 1) * 128 + ix0 + 1) * CC + co]);
            smp[g][p][d] = sv;
        }
        __syncthreads();
        float s[6];
        #pragma unroll
        for (int p = 0; p < 4; ++p) {
            float kd = 0.f;
            #pragma unroll
            for (int e = 0; e < 32; ++e) kd += wkr[e] * smp[g][p][e];
            s[p] = rsum32(qd * kd) * SCALEF;
        }
        #pragma unroll
        for (int p = 0; p < 2; ++p) {
            float khd = bf2f(kh[bm * 512 + nh * 64 + p * 32 + d]);
            s[4 + p] = rsum32(qd * khd) * SCALEF;
        }
        float mx = s[0];
        #pragma unroll
        for (int p = 1; p < 6; ++p) mx = fmaxf(mx, s[p]);
        float es[6], ssum = 0.f;
        #pragma unroll
        for (int p = 0; p < 6; ++p) { es[p] = expf(s[p] - mx); ssum += es[p]; }
        const float inv = 1.0f / ssum;
        float od = 0.f;
        #pragma unroll
        for (int p = 0; p < 4; ++p) {
            float vd = 0.f;
            #pragma unroll
            for (int e = 0; e < 32; ++e) vd += wvr[e] * smp[g][p][e];
            od += es[p] * inv * vd;
        }
        #pragma unroll
        for (int p = 0; p < 2; ++p)
            od += es[4 + p] * inv * bf2f(vh[bm * 512 + nh * 64 + p * 32 + d]);
        attno[bm * CC + nh * 32 + d] = f2bf(od);
        __syncthreads();
    }
}

// ---------------- w_out grouped conv + bias + residual1(x, NCHW) ------------
__global__ __launch_bounds__(256)
void r1_kernel(const u16* __restrict__ attno, const float* __restrict__ w_out,
               const float* __restrict__ b_out, const float* __restrict__ x_in,
               u16* __restrict__ r1)
{
    __shared__ float la[256];
    const int tid = threadIdx.x;
    const int g = tid >> 5;
    float wr[32];
    #pragma unroll
    for (int dd = 0; dd < 32; ++dd) wr[dd] = w_out[tid * 32 + dd]; // (g*32+oc)*32+d
    const float bo = b_out[tid];
    const int m0 = blockIdx.x * 32;
    for (int i = 0; i < 32; ++i) {
        const size_t bm = m0 + i;
        la[tid] = bf2f(attno[bm * CC + tid]);
        __syncthreads();
        float o = 0.f;
        #pragma unroll
        for (int dd = 0; dd < 32; ++dd) o += wr[dd] * la[g * 32 + dd];
        const int b = (int)(bm >> 14), m = (int)(bm & 16383);
        float xv = x_in[((size_t)b * CC + tid) * MM + m];
        r1[bm * CC + tid] = f2bf(xv + o + bo);
        __syncthreads();
    }
}

// ---------------- GN normalize (bf16 in place) ----------------
__global__ __launch_bounds__(256)
void gnorm_kernel(u16* __restrict__ r1, const float2* __restrict__ stats,
                  const float* __restrict__ gg, const float* __restrict__ gb, int NG)
{
    const size_t total = (size_t)BMTOT * CC;
    for (size_t i = (size_t)blockIdx.x * 256 + threadIdx.x; i < total;
         i += (size_t)gridDim.x * 256) {
        int c = (int)(i & 255);
        int bb = (int)(i >> 22);
        int g = (NG == 8) ? (c >> 5) : 0;
        float2 st = stats[bb * NG + g];
        r1[i] = f2bf((bf2f(r1[i]) - st.x) * st.y * gg[c] + gb[c]);
    }
}

// ---------------- FFN first grouped conv + bias + relu -> bf16 --------------
__global__ __launch_bounds__(256)
void ffn1_kernel(const u16* __restrict__ res2, const float* __restrict__ w1,
                 const float* __restrict__ b1, u16* __restrict__ y1bf)
{
    __shared__ float la[256];
    const int tid = threadIdx.x;
    float wr0[32], wr1[32];
    #pragma unroll
    for (int dd = 0; dd < 32; ++dd) {
        wr0[dd] = w1[tid * 32 + dd];
        wr1[dd] = w1[(tid + 256) * 32 + dd];
    }
    const float bb0 = b1[tid], bb1 = b1[tid + 256];
    const int g0 = tid >> 6, g1 = 4 + (tid >> 6);
    const int m0 = blockIdx.x * 32;
    for (int i = 0; i < 32; ++i) {
        const size_t bm = m0 + i;
        la[tid] = bf2f(res2[bm * CC + tid]);
        __syncthreads();
        float o0 = bb0, o1 = bb1;
        #pragma unroll
        for (int dd = 0; dd < 32; ++dd) {
            o0 += wr0[dd] * la[g0 * 32 + dd];
            o1 += wr1[dd] * la[g1 * 32 + dd];
        }
        y1bf[bm * 512 + tid] = f2bf(fmaxf(o0, 0.f));
        y1bf[bm * 512 + tid + 256] = f2bf(fmaxf(o1, 0.f));
        __syncthreads();
    }
}

// ---------------- final GN2 normalize + transpose to NCHW -------------------
__global__ __launch_bounds__(256)
void final_kernel(const float* __restrict__ y2, const u16* __restrict__ res2,
                  const float2* __restrict__ stats, const float* __restrict__ gg,
                  const float* __restrict__ gb, float* __restrict__ out)
{
    __shared__ float lt[64][65];
    const int m0 = blockIdx.x * 64, c0 = blockIdx.y * 64, b = blockIdx.z;
    const int tid = threadIdx.x;
    const float2 st = stats[b];
    {
        const int cl = tid & 63, m4 = tid >> 6;
        for (int s = 0; s < 16; ++s) {
            int ml = s * 4 + m4;
            size_t idx = ((size_t)b * MM + m0 + ml) * CC + c0 + cl;
            float v = y2[idx] + bf2f(res2[idx]);
            lt[cl][ml] = (v - st.x) * st.y * gg[c0 + cl] + gb[c0 + cl];
        }
    }
    __syncthreads();
    {
        const int mlw = tid & 63, c4 = tid >> 6;
        for (int s = 0; s < 16; ++s) {
            int clw = s * 4 + c4;
            out[((size_t)b * CC + c0 + clw) * MM + m0 + mlw] = lt[clw][mlw];
        }
    }
}

// diagnostic: written iff workspace is too small (absmax ~1000 signals it)
__global__ void sentinel_kernel(float* out) { out[threadIdx.x] = 1000.0f; }

// ============================ host side ============================
extern "C" void kernel_launch(void* const* d_in, const int* in_sizes, int n_in,
                              void* d_out, int out_size, void* d_ws, size_t ws_size,
                              hipStream_t stream)
{
    const float* q_in   = (const float*)d_in[0];
    const float* x_in   = (const float*)d_in[1];
    const float* off_w1 = (const float*)d_in[2];
    const float* off_b1 = (const float*)d_in[3];
    const float* off_gn_g = (const float*)d_in[4];
    const float* off_gn_b = (const float*)d_in[5];
    const float* off_w2 = (const float*)d_in[6];
    const float* wq     = (const float*)d_in[7];
    const float* wk     = (const float*)d_in[8];
    const float* wv     = (const float*)d_in[9];
    const float* wx     = (const float*)d_in[10];
    const float* w_out  = (const float*)d_in[11];
    const float* b_out  = (const float*)d_in[12];
    const float* wkh    = (const float*)d_in[13];
    const float* wvh    = (const float*)d_in[14];
    const float* ca_w   = (const float*)d_in[15];
    const float* gn1_g  = (const float*)d_in[16];
    const float* gn1_b  = (const float*)d_in[17];
    const float* ffn_w1 = (const float*)d_in[18];
    const float* ffn_b1 = (const float*)d_in[19];
    const float* ffn_w2 = (const float*)d_in[20];
    const float* ffn_b2 = (const float*)d_in[21];
    const float* gn2_g  = (const float*)d_in[22];
    const float* gn2_b  = (const float*)d_in[23];
    float* out = (float*)d_out;

    char* W = (char*)d_ws;
    size_t off = 0;
    auto AL = [&](size_t sz) -> char* {
        char* p = W + off;
        off += (sz + 255) & ~(size_t)255;
        return p;
    };
    u16* zp    = (u16*)AL(256);
    u16* w1t   = (u16*)AL(589824 * 2);
    u16* wqb   = (u16*)AL(65536 * 2);
    u16* wxb   = (u16*)AL(65536 * 2);
    u16* fw2b  = (u16*)AL(131072 * 2);
    u16* wkhs  = (u16*)AL(2 * 131072 * 2);     // per-batch gate-folded
    u16* wvhs  = (u16*)AL(2 * 131072 * 2);
    u16* slotA = (u16*)AL((size_t)BMTOT * CC * 2);   // qpe -> attno -> y2(lo)
    u16* slotC = (u16*)AL((size_t)BMTOT * CC * 2);   // t -> xc -> y2(hi)
    u16* slotD = (u16*)AL((size_t)BMTOT * CC * 2);   // qp
    u16* slotB = (u16*)AL((size_t)BMTOT * CC * 2);   // xpe -> r1/res2
    u16* slotG = (u16*)AL((size_t)BMTOT * 512 * 2);  // vh -> y1bf
    u16* pos   = (u16*)AL((size_t)BB * NHH * PTS * MM * 2 * 2);
    float* part  = (float*)AL(64 * 8 * 2 * 4);
    float* pmax  = (float*)AL(64 * 256 * 4);
    float* psum  = (float*)AL(64 * 256 * 4);
    float* gate  = (float*)AL(2 * 256 * 4);
    float2* stats_t  = (float2*)AL(2 * sizeof(float2));
    float2* stats_g1 = (float2*)AL(16 * sizeof(float2));
    float2* stats_g2 = (float2*)AL(2 * sizeof(float2));

    u16* qpe = slotA;  u16* attno = slotA;
    u16* t_b = slotC;  u16* xc  = slotC;
    u16* qp  = slotD;
    u16* xpe = slotB;  u16* r1  = slotB;     // res2 after gnorm
    u16* vh  = slotG;  u16* y1bf = slotG;
    u16* kh  = (u16*)d_out;                  // 33.5 MB, dead before final_kernel
    float* y2 = (float*)slotA;               // spans slotA+slotC (contiguous)

    if (off > ws_size) {                     // ws too small: absmax ~1000 signals it
        sentinel_kernel<<<1, 256, 0, stream>>>(out);
        return;
    }

    prep_kernel<<<3329, 256, 0, stream>>>(off_w1, wq, wx, ffn_w2,
                                          zp, w1t, wqb, wxb, fw2b);
    addpe_kernel<<<dim3(256, 4, 2), 256, 0, stream>>>(q_in, x_in, qpe, xpe);

    // conv_offset 3x3 (implicit im2col) -> t
    gemm_bt<1, 1><<<dim3(256, 2), 256, 0, stream>>>(qpe, w1t, off_b1, t_b, 2304, 256, zp);
    stats1_bf_kernel<<<64, 256, 0, stream>>>(t_b, part);
    stats2_kernel<<<1, 64, 0, stream>>>(part, stats_t, 1);
    offset_kernel<<<8192, 256, 0, stream>>>(t_b, stats_t, off_gn_g, off_gn_b, off_w2, pos);

    // qp projection (after conv GEMM so slotC reuse is safe)
    gemm_bt<0, 1><<<dim3(256, 2), 256, 0, stream>>>(qpe, wqb, nullptr, qp, 256, 256, zp);
    // x branch: conv -> xc (overwrites t, which is now dead)
    gemm_bt<0, 1><<<dim3(256, 2), 256, 0, stream>>>(xpe, wxb, nullptr, xc, 256, 256, zp);
    pool1_kernel<<<64, 256, 0, stream>>>(xc, pmax, psum);
    pool2_gate_kernel<<<2, 256, 0, stream>>>(pmax, psum, ca_w, gate);
    scalekv_kernel<<<2048, 256, 0, stream>>>(wkh, wvh, gate, wkhs, wvhs);

    // kh/vh GEMMs with gate-folded per-batch weights
    for (int b = 0; b < 2; ++b) {
        gemm_bt<0, 1><<<dim3(128, 4), 256, 0, stream>>>(
            xc + (size_t)b * MM * CC, wkhs + (size_t)b * 131072, nullptr,
            kh + (size_t)b * MM * 512, 256, 512, zp);
        gemm_bt<0, 1><<<dim3(128, 4), 256, 0, stream>>>(
            xc + (size_t)b * MM * CC, wvhs + (size_t)b * 131072, nullptr,
            vh + (size_t)b * MM * 512, 256, 512, zp);
    }

    // fused deformable attention
    attn_kernel<<<dim3(256, 16), 256, 0, stream>>>(qp, xc, kh, vh, pos, wk, wv, attno);

    // out proj + residual + GN1
    r1_kernel<<<1024, 256, 0, stream>>>(attno, w_out, b_out, x_in, r1);
    stats1_bf_kernel<<<64, 256, 0, stream>>>(r1, part);
    stats2_kernel<<<1, 64, 0, stream>>>(part, stats_g1, 8);
    gnorm_kernel<<<4096, 256, 0, stream>>>(r1, stats_g1, gn1_g, gn1_b, 8);  // -> res2

    // FFN
    ffn1_kernel<<<1024, 256, 0, stream>>>(r1, ffn_w1, ffn_b1, y1bf);
    gemm_bt<0, 0><<<dim3(256, 2), 256, 0, stream>>>(y1bf, fw2b, ffn_b2, y2, 512, 256, zp);

    // GN2 + output transpose (overwrites d_out, incl. dead kh)
    stats1_mix_kernel<<<64, 256, 0, stream>>>(y2, r1, part);
    stats2_kernel<<<1, 64, 0, stream>>>(part, stats_g2, 1);
    final_kernel<<<dim3(256, 4, 2), 256, 0, stream>>>(y2, r1, stats_g2, gn2_g, gn2_b, out);
}

// Round 6
// 823.971 us; speedup vs baseline: 1.1678x; 1.1678x over previous
//
#include <hip/hip_runtime.h>
#include <hip/hip_bf16.h>
#include <math.h>

typedef unsigned short u16;
typedef __attribute__((ext_vector_type(8))) unsigned short u16v8;
typedef __attribute__((ext_vector_type(8))) __bf16 bf16v8;
typedef __attribute__((ext_vector_type(4))) float f32v4;

#define BB 2
#define MM 16384           // H*W
#define CC 256
#define NHH 8
#define PTS 4
#define BMTOT 32768        // B*M
#define SCALEF 0.17677669529663687f
#define PECOEF 0.03597789207803197f   // ln(10000)/256

__device__ __forceinline__ u16 f2bf(float f) {
    union { float f; unsigned u; } v; v.f = f;
    unsigned u = v.u;
    return (u16)((u + 0x7fffu + ((u >> 16) & 1u)) >> 16);
}
__device__ __forceinline__ float bf2f(u16 u) {
    union { unsigned u; float f; } v; v.u = ((unsigned)u) << 16; return v.f;
}
__device__ __forceinline__ float rsum32(float v) {
    #pragma unroll
    for (int m = 16; m; m >>= 1) v += __shfl_xor(v, m, 32);
    return v;
}
__device__ __forceinline__ void gload16(const void* g, void* l) {
    __builtin_amdgcn_global_load_lds(
        (const __attribute__((address_space(1))) void*)g,
        (__attribute__((address_space(3))) void*)l, 16, 0, 0);
}

// ---------------- prep: zero page + weight bf16 conversions ----------------
__global__ __launch_bounds__(256)
void prep_kernel(const float* __restrict__ off_w1, const float* __restrict__ wq,
                 const float* __restrict__ wx, const float* __restrict__ fw2,
                 u16* zp, u16* w1t, u16* wqb, u16* wxb, u16* fw2b)
{
    const size_t n_zp = 128, n_w1 = 589824, n_q = 65536, n_f2 = 131072;
    const size_t total = n_zp + n_w1 + 2 * n_q + n_f2;
    for (size_t i = (size_t)blockIdx.x * 256 + threadIdx.x; i < total;
         i += (size_t)gridDim.x * 256) {
        size_t j = i;
        if (j < n_zp) { zp[j] = 0; continue; }
        j -= n_zp;
        if (j < n_w1) {  // w1t[oc][tap*256+ic] = off_w1[oc][ic][tap]
            size_t oc = j / 2304, r = j % 2304, tap = r >> 8, ic = r & 255;
            w1t[j] = f2bf(off_w1[(oc * 256 + ic) * 9 + tap]);
            continue;
        }
        j -= n_w1;
        if (j < n_q) { wqb[j] = f2bf(wq[j]); continue; }
        j -= n_q;
        if (j < n_q) { wxb[j] = f2bf(wx[j]); continue; }
        j -= n_q;
        fw2b[j] = f2bf(fw2[j]);
    }
}

// ---------------- add positional encoding, transpose to pixel-major bf16 ----
__global__ __launch_bounds__(256)
void addpe_kernel(const float* __restrict__ q, const float* __restrict__ x,
                  u16* __restrict__ qpe, u16* __restrict__ xpe)
{
    __shared__ float lq[64][65], lx[64][65];
    const int m0 = blockIdx.x * 64, c0 = blockIdx.y * 64, b = blockIdx.z;
    const int tid = threadIdx.x;
    {
        const int ml = tid & 63, c4 = tid >> 6;
        for (int s = 0; s < 16; ++s) {
            int cl = s * 4 + c4;
            int c = c0 + cl, m = m0 + ml;
            float dv = expf(-(float)(c & ~1) * PECOEF);
            float a = (float)m * dv;
            float pe = (c & 1) ? cosf(a) : sinf(a);
            size_t gi = ((size_t)b * CC + c) * MM + m;
            lq[cl][ml] = q[gi] + pe;
            lx[cl][ml] = x[gi] + pe;
        }
    }
    __syncthreads();
    {
        const int cl = tid & 63, m4 = tid >> 6;
        for (int s = 0; s < 16; ++s) {
            int ml = s * 4 + m4;
            size_t oi = ((size_t)b * MM + m0 + ml) * CC + c0 + cl;
            qpe[oi] = f2bf(lq[cl][ml]);
            xpe[oi] = f2bf(lx[cl][ml]);
        }
    }
}

// ---------------- bf16 MFMA GEMM (global_load_lds staging) ------------------
// C[row,col] = sum_k A[row,k]*W[col,k] (+bias)
// AMODE 0: A row-major bf16 (rows x K). AMODE 1: implicit im2col 3x3 pad=1.
// OUTBF: 1 -> store bf16, 0 -> store fp32.
template<int AMODE, int OUTBF>
__global__ __launch_bounds__(256, 2)
void gemm_bt(const u16* __restrict__ A, const u16* __restrict__ Bw,
             const float* __restrict__ bias, void* __restrict__ Cout,
             int K, int N, const u16* __restrict__ zp)
{
    __shared__ u16 lA[128 * 32];
    __shared__ u16 lB[128 * 32];
    const int tid = threadIdx.x;
    const int w = tid >> 6, l = tid & 63;
    const int gm = blockIdx.x, gn = blockIdx.y;
    const int wm = w >> 1, wn = w & 1;
    const int rowIn = l >> 2;            // 0..15 within 16-row segment
    const int kc = (l & 3) << 3;         // k offset 0,8,16,24
    f32v4 acc[4][4] = {};

    for (int k0 = 0; k0 < K; k0 += 32) {
        // stage A and B tiles: 2 segments per wave, 1 KB per gload (64 lanes x 16B).
        // LDS dest is wave-uniform base + lane*16 -> row-major [128][32] exactly.
        #pragma unroll
        for (int r = 0; r < 2; ++r) {
            const int seg = r * 4 + w;          // 0..7
            const int row = seg * 16 + rowIn;   // 0..127
            const u16* gpA;
            if (AMODE == 0) {
                gpA = A + (size_t)(gm * 128 + row) * K + (k0 + kc);
            } else {
                int grow = gm * 128 + row;
                int bimg = grow >> 14, m = grow & 16383;
                int y = m >> 7, xx2 = m & 127;
                int kk2 = k0 + kc;
                int tap = kk2 >> 8, ic = kk2 & 255;
                int t3 = tap / 3;
                int py = y + t3 - 1, px = xx2 + (tap - t3 * 3) - 1;
                bool ok = ((unsigned)py < 128u) && ((unsigned)px < 128u);
                gpA = ok ? (A + (((size_t)((bimg << 14) + (py << 7) + px)) << 8) + ic) : zp;
            }
            gload16(gpA, lA + seg * 512);
            const u16* gpB = Bw + (size_t)(gn * 128 + row) * K + (k0 + kc);
            gload16(gpB, lB + seg * 512);
        }
        __syncthreads();
        bf16v8 af[4], bf[4];
        #pragma unroll
        for (int i = 0; i < 4; ++i) {
            af[i] = *(const bf16v8*)&lA[((wm << 6) + (i << 4) + (l & 15)) * 32 + ((l >> 4) << 3)];
            bf[i] = *(const bf16v8*)&lB[((wn << 6) + (i << 4) + (l & 15)) * 32 + ((l >> 4) << 3)];
        }
        #pragma unroll
        for (int i = 0; i < 4; ++i)
            #pragma unroll
            for (int j = 0; j < 4; ++j)
                acc[i][j] = __builtin_amdgcn_mfma_f32_16x16x32_bf16(af[i], bf[j], acc[i][j], 0, 0, 0);
        __syncthreads();
    }

    const int l15 = l & 15, l4 = l >> 4;
    #pragma unroll
    for (int i = 0; i < 4; ++i) {
        int row = gm * 128 + (wm << 6) + (i << 4) + (l4 << 2);
        #pragma unroll
        for (int j = 0; j < 4; ++j) {
            int col = gn * 128 + (wn << 6) + (j << 4) + l15;
            float bv = bias ? bias[col] : 0.0f;
            #pragma unroll
            for (int r = 0; r < 4; ++r) {
                float val = acc[i][j][r] + bv;
                if (OUTBF) ((u16*)Cout)[(size_t)(row + r) * N + col] = f2bf(val);
                else       ((float*)Cout)[(size_t)(row + r) * N + col] = val;
            }
        }
    }
}

// ---------------- GroupNorm stats stage 1 (bf16 input) ----------------
__global__ __launch_bounds__(256)
void stats1_bf_kernel(const u16* __restrict__ a, float* __restrict__ part)
{
    __shared__ float ls[256], lss[256];
    const int blk = blockIdx.x;           // B*32 blocks
    const int bb = blk >> 5, ch = blk & 31;
    const size_t base = ((size_t)bb * MM + ch * 512) * CC;
    const int tid = threadIdx.x;
    float s = 0.f, ss = 0.f;
    for (int p = 0; p < 512; ++p) {
        float v = bf2f(a[base + (size_t)p * CC + tid]);
        s += v; ss += v * v;
    }
    ls[tid] = s; lss[tid] = ss;
    __syncthreads();
    if (tid < 8) {
        float S = 0.f, SS = 0.f;
        for (int j = 0; j < 32; ++j) { S += ls[tid * 32 + j]; SS += lss[tid * 32 + j]; }
        part[(blk * 8 + tid) * 2] = S;
        part[(blk * 8 + tid) * 2 + 1] = SS;
    }
}

// stage 1, mixed fp32 + bf16 inputs (for y2 + res2)
__global__ __launch_bounds__(256)
void stats1_mix_kernel(const float* __restrict__ a, const u16* __restrict__ b2,
                       float* __restrict__ part)
{
    __shared__ float ls[256], lss[256];
    const int blk = blockIdx.x;
    const int bb = blk >> 5, ch = blk & 31;
    const size_t base = ((size_t)bb * MM + ch * 512) * CC;
    const int tid = threadIdx.x;
    float s = 0.f, ss = 0.f;
    for (int p = 0; p < 512; ++p) {
        float v = a[base + (size_t)p * CC + tid] + bf2f(b2[base + (size_t)p * CC + tid]);
        s += v; ss += v * v;
    }
    ls[tid] = s; lss[tid] = ss;
    __syncthreads();
    if (tid < 8) {
        float S = 0.f, SS = 0.f;
        for (int j = 0; j < 32; ++j) { S += ls[tid * 32 + j]; SS += lss[tid * 32 + j]; }
        part[(blk * 8 + tid) * 2] = S;
        part[(blk * 8 + tid) * 2 + 1] = SS;
    }
}

__global__ __launch_bounds__(64)
void stats2_kernel(const float* __restrict__ part, float2* __restrict__ stats, int NG)
{
    const int t = threadIdx.x;
    if (t >= 2 * NG) return;
    const int bb = t / NG, g = t % NG;
    const int gsub = 8 / NG;
    float S = 0.f, SS = 0.f;
    for (int ch = 0; ch < 32; ++ch)
        for (int j = 0; j < gsub; ++j) {
            int idx = (bb * 32 + ch) * 8 + g * gsub + j;
            S += part[idx * 2]; SS += part[idx * 2 + 1];
        }
    const float cnt = (256.0f / NG) * 16384.0f;
    float mu = S / cnt;
    float var = SS / cnt - mu * mu;
    stats[bb * NG + g] = make_float2(mu, rsqrtf(var + 1e-5f));
}

// ---------------- conv_offset tail: GN(1)+ReLU -> grouped 1x1 -> tanh -------
// stores only the tanh value (bf16); sampling coord = pixel + 0.5 + tanh.
__global__ __launch_bounds__(256)
void offset_kernel(const u16* __restrict__ t, const float2* __restrict__ stats_t,
                   const float* __restrict__ gng, const float* __restrict__ gnb,
                   const float* __restrict__ w2, u16* __restrict__ pos)
{
    __shared__ float lt[4 * 256];
    const int tid = threadIdx.x;
    const int bm0 = blockIdx.x * 4;
    const int b = bm0 >> 14;
    const float2 st = stats_t[b];
    for (int idx = tid; idx < 1024; idx += 256) {
        int pix = idx >> 8, c = idx & 255;
        float v = bf2f(t[(size_t)(bm0 + pix) * CC + c]);
        v = (v - st.x) * st.y * gng[c] + gnb[c];
        lt[idx] = fmaxf(v, 0.0f);
    }
    __syncthreads();
    const int pix = tid >> 6, go = tid & 63;
    const int g = go >> 3, o = go & 7;
    float s = 0.f;
    #pragma unroll
    for (int ci = 0; ci < 32; ++ci) {
        int ce = (ci + g * 4) & 31;                 // bank rotation
        s += w2[(g * 8 + o) * 32 + ce] * lt[pix * 256 + g * 32 + ce];
    }
    const int m = (bm0 + pix) & 16383;
    const int p = o >> 1, c2 = o & 1;
    pos[((((size_t)b * NHH + g) * PTS + p) * MM + m) * 2 + c2] = f2bf(tanhf(s));
}

// ---------------- channel-attention pooling + gate + weight folding --------
__global__ __launch_bounds__(256)
void pool1_kernel(const u16* __restrict__ xc, float* __restrict__ pmax,
                  float* __restrict__ psum)
{
    const int blk = blockIdx.x;
    const int bb = blk >> 5, ch = blk & 31;
    const size_t base = ((size_t)bb * MM + ch * 512) * CC;
    const int tid = threadIdx.x;
    float mx = -1e30f, s = 0.f;
    for (int p = 0; p < 512; ++p) {
        float v = bf2f(xc[base + (size_t)p * CC + tid]);
        mx = fmaxf(mx, v); s += v;
    }
    pmax[blk * 256 + tid] = mx;
    psum[blk * 256 + tid] = s;
}

__global__ __launch_bounds__(256)
void pool2_gate_kernel(const float* __restrict__ pmax, const float* __restrict__ psum,
                       const float* __restrict__ ca_w, float* __restrict__ gate)
{
    __shared__ float sv[256];
    const int bb = blockIdx.x, tid = threadIdx.x;
    float mx = -1e30f, s = 0.f;
    for (int ch = 0; ch < 32; ++ch) {
        mx = fmaxf(mx, pmax[(bb * 32 + ch) * 256 + tid]);
        s += psum[(bb * 32 + ch) * 256 + tid];
    }
    sv[tid] = mx + s * (1.0f / 16384.0f);   // mx + av
    __syncthreads();
    float acc = 0.f;
    for (int ci = 0; ci < 256; ++ci) acc += ca_w[tid * 256 + ci] * sv[ci];
    gate[bb * 256 + tid] = 1.0f / (1.0f + expf(-acc));
}

// fold (1+gate[b,c]) into wkh/wvh columns, per batch -> bf16
__global__ __launch_bounds__(256)
void scalekv_kernel(const float* __restrict__ wkh, const float* __restrict__ wvh,
                    const float* __restrict__ gate, u16* __restrict__ wkhs,
                    u16* __restrict__ wvhs)
{
    const int n1 = 512 * 256;                   // per-batch weight count
    for (int i = blockIdx.x * 256 + threadIdx.x; i < 4 * n1;
         i += gridDim.x * 256) {
        int which = i / (2 * n1);               // 0: kh, 1: vh
        int r = i % (2 * n1);
        int b = r / n1, j = r % n1;
        float gsc = 1.0f + gate[b * 256 + (j & 255)];
        if (which == 0) wkhs[b * n1 + j] = f2bf(wkh[j] * gsc);
        else            wvhs[b * n1 + j] = f2bf(wvh[j] * gsc);
    }
}

// ---------------- per-head projection maps: xck/xcv = gconv(xc, wk/wv) ------
// sampling commutes with the channel projection, so sample these instead.
__global__ __launch_bounds__(256)
void projkv_kernel(const u16* __restrict__ xc, const float* __restrict__ wk,
                   const float* __restrict__ wv, u16* __restrict__ xck,
                   u16* __restrict__ xcv)
{
    __shared__ float la[256];
    const int tid = threadIdx.x;
    const int g = tid >> 5;
    float wkr[32], wvr[32];
    #pragma unroll
    for (int dd = 0; dd < 32; ++dd) {
        wkr[dd] = wk[tid * 32 + dd];   // wk[(nh*32+d)*32+e]
        wvr[dd] = wv[tid * 32 + dd];
    }
    const int m0 = blockIdx.x * 32;
    for (int i = 0; i < 32; ++i) {
        const size_t bm = m0 + i;
        la[tid] = bf2f(xc[bm * CC + tid]);
        __syncthreads();
        float ok = 0.f, ov = 0.f;
        #pragma unroll
        for (int dd = 0; dd < 32; ++dd) {
            ok += wkr[dd] * la[g * 32 + dd];
            ov += wvr[dd] * la[g * 32 + dd];
        }
        xck[bm * CC + tid] = f2bf(ok);
        xcv[bm * CC + tid] = f2bf(ov);
        __syncthreads();
    }
}

// ---------------- fused deformable sampling + attention ----------
__global__ __launch_bounds__(256)
void attn_kernel(const u16* __restrict__ qp, const u16* __restrict__ xck,
                 const u16* __restrict__ xcv, const u16* __restrict__ kh,
                 const u16* __restrict__ vh, const u16* __restrict__ pos,
                 u16* __restrict__ attno)
{
    const int tid = threadIdx.x;
    const int g = tid >> 5, d = tid & 31;
    const int bh = blockIdx.y;
    const int b = bh >> 3, nh = bh & 7;
    const int co = nh * 32 + d;
    const size_t hb = (size_t)b * MM;
    #pragma unroll
    for (int i = 0; i < 4; ++i) {
        const int m = blockIdx.x * 32 + i * 8 + g;
        const size_t bm = hb + m;
        const float qd = bf2f(qp[bm * CC + co]);
        const int yy = m >> 7, xx = m & 127;
        float kk[6], vv[6];
        #pragma unroll
        for (int p = 0; p < 4; ++p) {
            const u16* pp = pos + ((((size_t)b * NHH + nh) * PTS + p) * MM + m) * 2;
            float gy = (float)yy + 0.5f + bf2f(pp[0]);
            float gx = (float)xx + 0.5f + bf2f(pp[1]);
            int ix0 = (int)floorf(gx), iy0 = (int)floorf(gy);
            float fx = gx - (float)ix0, fy = gy - (float)iy0;
            float w00 = (1.f - fx) * (1.f - fy), w10 = fx * (1.f - fy);
            float w01 = (1.f - fx) * fy, w11 = fx * fy;
            float sk = 0.f, sv = 0.f;
            if ((unsigned)ix0 < 128u && (unsigned)iy0 < 128u) {
                size_t o = (hb + iy0 * 128 + ix0) * CC + co;
                sk += w00 * bf2f(xck[o]); sv += w00 * bf2f(xcv[o]);
            }
            if ((unsigned)(ix0 + 1) < 128u && (unsigned)iy0 < 128u) {
                size_t o = (hb + iy0 * 128 + ix0 + 1) * CC + co;
                sk += w10 * bf2f(xck[o]); sv += w10 * bf2f(xcv[o]);
            }
            if ((unsigned)ix0 < 128u && (unsigned)(iy0 + 1) < 128u) {
                size_t o = (hb + (iy0 + 1) * 128 + ix0) * CC + co;
                sk += w01 * bf2f(xck[o]); sv += w01 * bf2f(xcv[o]);
            }
            if ((unsigned)(ix0 + 1) < 128u && (unsigned)(iy0 + 1) < 128u) {
                size_t o = (hb + (iy0 + 1) * 128 + ix0 + 1) * CC + co;
                sk += w11 * bf2f(xck[o]); sv += w11 * bf2f(xcv[o]);
            }
            kk[p] = sk; vv[p] = sv;
        }
        #pragma unroll
        for (int p = 0; p < 2; ++p) {
            kk[4 + p] = bf2f(kh[bm * 512 + nh * 64 + p * 32 + d]);
            vv[4 + p] = bf2f(vh[bm * 512 + nh * 64 + p * 32 + d]);
        }
        float s[6];
        #pragma unroll
        for (int p = 0; p < 6; ++p) s[p] = rsum32(qd * kk[p]) * SCALEF;
        float mx = s[0];
        #pragma unroll
        for (int p = 1; p < 6; ++p) mx = fmaxf(mx, s[p]);
        float es[6], ssum = 0.f;
        #pragma unroll
        for (int p = 0; p < 6; ++p) { es[p] = expf(s[p] - mx); ssum += es[p]; }
        const float inv = 1.0f / ssum;
        float od = 0.f;
        #pragma unroll
        for (int p = 0; p < 6; ++p) od += es[p] * inv * vv[p];
        attno[bm * CC + co] = f2bf(od);
    }
}

// ---------------- w_out grouped conv + bias + residual1(x, NCHW) ------------
__global__ __launch_bounds__(256)
void r1_kernel(const u16* __restrict__ attno, const float* __restrict__ w_out,
               const float* __restrict__ b_out, const float* __restrict__ x_in,
               u16* __restrict__ r1)
{
    __shared__ float la[256];
    const int tid = threadIdx.x;
    const int g = tid >> 5;
    float wr[32];
    #pragma unroll
    for (int dd = 0; dd < 32; ++dd) wr[dd] = w_out[tid * 32 + dd]; // (g*32+oc)*32+d
    const float bo = b_out[tid];
    const int m0 = blockIdx.x * 32;
    for (int i = 0; i < 32; ++i) {
        const size_t bm = m0 + i;
        la[tid] = bf2f(attno[bm * CC + tid]);
        __syncthreads();
        float o = 0.f;
        #pragma unroll
        for (int dd = 0; dd < 32; ++dd) o += wr[dd] * la[g * 32 + dd];
        const int b = (int)(bm >> 14), m = (int)(bm & 16383);
        float xv = x_in[((size_t)b * CC + tid) * MM + m];
        r1[bm * CC + tid] = f2bf(xv + o + bo);
        __syncthreads();
    }
}

// ---------------- GN normalize (bf16 in place) ----------------
__global__ __launch_bounds__(256)
void gnorm_kernel(u16* __restrict__ r1, const float2* __restrict__ stats,
                  const float* __restrict__ gg, const float* __restrict__ gb, int NG)
{
    const size_t total = (size_t)BMTOT * CC;
    for (size_t i = (size_t)blockIdx.x * 256 + threadIdx.x; i < total;
         i += (size_t)gridDim.x * 256) {
        int c = (int)(i & 255);
        int bb = (int)(i >> 22);
        int g = (NG == 8) ? (c >> 5) : 0;
        float2 st = stats[bb * NG + g];
        r1[i] = f2bf((bf2f(r1[i]) - st.x) * st.y * gg[c] + gb[c]);
    }
}

// ---------------- FFN first grouped conv + bias + relu -> bf16 --------------
__global__ __launch_bounds__(256)
void ffn1_kernel(const u16* __restrict__ res2, const float* __restrict__ w1,
                 const float* __restrict__ b1, u16* __restrict__ y1bf)
{
    __shared__ float la[256];
    const int tid = threadIdx.x;
    float wr0[32], wr1[32];
    #pragma unroll
    for (int dd = 0; dd < 32; ++dd) {
        wr0[dd] = w1[tid * 32 + dd];
        wr1[dd] = w1[(tid + 256) * 32 + dd];
    }
    const float bb0 = b1[tid], bb1 = b1[tid + 256];
    const int g0 = tid >> 6, g1 = 4 + (tid >> 6);
    const int m0 = blockIdx.x * 32;
    for (int i = 0; i < 32; ++i) {
        const size_t bm = m0 + i;
        la[tid] = bf2f(res2[bm * CC + tid]);
        __syncthreads();
        float o0 = bb0, o1 = bb1;
        #pragma unroll
        for (int dd = 0; dd < 32; ++dd) {
            o0 += wr0[dd] * la[g0 * 32 + dd];
            o1 += wr1[dd] * la[g1 * 32 + dd];
        }
        y1bf[bm * 512 + tid] = f2bf(fmaxf(o0, 0.f));
        y1bf[bm * 512 + tid + 256] = f2bf(fmaxf(o1, 0.f));
        __syncthreads();
    }
}

// ---------------- final GN2 normalize + transpose to NCHW -------------------
__global__ __launch_bounds__(256)
void final_kernel(const float* __restrict__ y2, const u16* __restrict__ res2,
                  const float2* __restrict__ stats, const float* __restrict__ gg,
                  const float* __restrict__ gb, float* __restrict__ out)
{
    __shared__ float lt[64][65];
    const int m0 = blockIdx.x * 64, c0 = blockIdx.y * 64, b = blockIdx.z;
    const int tid = threadIdx.x;
    const float2 st = stats[b];
    {
        const int cl = tid & 63, m4 = tid >> 6;
        for (int s = 0; s < 16; ++s) {
            int ml = s * 4 + m4;
            size_t idx = ((size_t)b * MM + m0 + ml) * CC + c0 + cl;
            float v = y2[idx] + bf2f(res2[idx]);
            lt[cl][ml] = (v - st.x) * st.y * gg[c0 + cl] + gb[c0 + cl];
        }
    }
    __syncthreads();
    {
        const int mlw = tid & 63, c4 = tid >> 6;
        for (int s = 0; s < 16; ++s) {
            int clw = s * 4 + c4;
            out[((size_t)b * CC + c0 + clw) * MM + m0 + mlw] = lt[clw][mlw];
        }
    }
}

// diagnostic: written iff workspace is too small (absmax ~1000 signals it)
__global__ void sentinel_kernel(float* out) { out[threadIdx.x] = 1000.0f; }

// ============================ host side ============================
extern "C" void kernel_launch(void* const* d_in, const int* in_sizes, int n_in,
                              void* d_out, int out_size, void* d_ws, size_t ws_size,
                              hipStream_t stream)
{
    const float* q_in   = (const float*)d_in[0];
    const float* x_in   = (const float*)d_in[1];
    const float* off_w1 = (const float*)d_in[2];
    const float* off_b1 = (const float*)d_in[3];
    const float* off_gn_g = (const float*)d_in[4];
    const float* off_gn_b = (const float*)d_in[5];
    const float* off_w2 = (const float*)d_in[6];
    const float* wq     = (const float*)d_in[7];
    const float* wk     = (const float*)d_in[8];
    const float* wv     = (const float*)d_in[9];
    const float* wx     = (const float*)d_in[10];
    const float* w_out  = (const float*)d_in[11];
    const float* b_out  = (const float*)d_in[12];
    const float* wkh    = (const float*)d_in[13];
    const float* wvh    = (const float*)d_in[14];
    const float* ca_w   = (const float*)d_in[15];
    const float* gn1_g  = (const float*)d_in[16];
    const float* gn1_b  = (const float*)d_in[17];
    const float* ffn_w1 = (const float*)d_in[18];
    const float* ffn_b1 = (const float*)d_in[19];
    const float* ffn_w2 = (const float*)d_in[20];
    const float* ffn_b2 = (const float*)d_in[21];
    const float* gn2_g  = (const float*)d_in[22];
    const float* gn2_b  = (const float*)d_in[23];
    float* out = (float*)d_out;

    char* W = (char*)d_ws;
    size_t off = 0;
    auto AL = [&](size_t sz) -> char* {
        char* p = W + off;
        off += (sz + 255) & ~(size_t)255;
        return p;
    };
    u16* zp    = (u16*)AL(256);
    u16* w1t   = (u16*)AL(589824 * 2);
    u16* wqb   = (u16*)AL(65536 * 2);
    u16* wxb   = (u16*)AL(65536 * 2);
    u16* fw2b  = (u16*)AL(131072 * 2);
    u16* wkhs  = (u16*)AL(2 * 131072 * 2);     // per-batch gate-folded
    u16* wvhs  = (u16*)AL(2 * 131072 * 2);
    u16* slotA = (u16*)AL((size_t)BMTOT * CC * 2);   // qpe -> attno -> y2(lo)
    u16* slotC = (u16*)AL((size_t)BMTOT * CC * 2);   // t -> xc -> y2(hi)
    u16* slotD = (u16*)AL((size_t)BMTOT * CC * 2);   // qp
    u16* slotB = (u16*)AL((size_t)BMTOT * CC * 2);   // xpe -> xcv -> r1/res2
    u16* slotE = (u16*)AL((size_t)BMTOT * CC * 2);   // xck
    u16* slotG = (u16*)AL((size_t)BMTOT * 512 * 2);  // vh -> y1bf
    u16* pos   = (u16*)AL((size_t)BB * NHH * PTS * MM * 2 * 2);
    float* part  = (float*)AL(64 * 8 * 2 * 4);
    float* pmax  = (float*)AL(64 * 256 * 4);
    float* psum  = (float*)AL(64 * 256 * 4);
    float* gate  = (float*)AL(2 * 256 * 4);
    float2* stats_t  = (float2*)AL(2 * sizeof(float2));
    float2* stats_g1 = (float2*)AL(16 * sizeof(float2));
    float2* stats_g2 = (float2*)AL(2 * sizeof(float2));

    u16* qpe = slotA;  u16* attno = slotA;
    u16* t_b = slotC;  u16* xc  = slotC;
    u16* qp  = slotD;
    u16* xpe = slotB;  u16* xcv = slotB;  u16* r1 = slotB;   // res2 after gnorm
    u16* xck = slotE;
    u16* vh  = slotG;  u16* y1bf = slotG;
    u16* kh  = (u16*)d_out;                  // 33.5 MB, dead before final_kernel
    float* y2 = (float*)slotA;               // spans slotA+slotC (contiguous)

    if (off > ws_size) {                     // ws too small: absmax ~1000 signals it
        sentinel_kernel<<<1, 256, 0, stream>>>(out);
        return;
    }

    prep_kernel<<<3329, 256, 0, stream>>>(off_w1, wq, wx, ffn_w2,
                                          zp, w1t, wqb, wxb, fw2b);
    addpe_kernel<<<dim3(256, 4, 2), 256, 0, stream>>>(q_in, x_in, qpe, xpe);

    // conv_offset 3x3 (implicit im2col) -> t
    gemm_bt<1, 1><<<dim3(256, 2), 256, 0, stream>>>(qpe, w1t, off_b1, t_b, 2304, 256, zp);
    stats1_bf_kernel<<<64, 256, 0, stream>>>(t_b, part);
    stats2_kernel<<<1, 64, 0, stream>>>(part, stats_t, 1);
    offset_kernel<<<8192, 256, 0, stream>>>(t_b, stats_t, off_gn_g, off_gn_b, off_w2, pos);

    // qp projection (after conv GEMM so slotC reuse is safe)
    gemm_bt<0, 1><<<dim3(256, 2), 256, 0, stream>>>(qpe, wqb, nullptr, qp, 256, 256, zp);
    // x branch: conv -> xc (overwrites t, which is now dead)
    gemm_bt<0, 1><<<dim3(256, 2), 256, 0, stream>>>(xpe, wxb, nullptr, xc, 256, 256, zp);
    pool1_kernel<<<64, 256, 0, stream>>>(xc, pmax, psum);
    pool2_gate_kernel<<<2, 256, 0, stream>>>(pmax, psum, ca_w, gate);
    scalekv_kernel<<<2048, 256, 0, stream>>>(wkh, wvh, gate, wkhs, wvhs);
    // per-head k/v maps (xpe dead now; xcv overwrites it)
    projkv_kernel<<<1024, 256, 0, stream>>>(xc, wk, wv, xck, xcv);

    // kh/vh GEMMs with gate-folded per-batch weights
    for (int b = 0; b < 2; ++b) {
        gemm_bt<0, 1><<<dim3(128, 4), 256, 0, stream>>>(
            xc + (size_t)b * MM * CC, wkhs + (size_t)b * 131072, nullptr,
            kh + (size_t)b * MM * 512, 256, 512, zp);
        gemm_bt<0, 1><<<dim3(128, 4), 256, 0, stream>>>(
            xc + (size_t)b * MM * CC, wvhs + (size_t)b * 131072, nullptr,
            vh + (size_t)b * MM * 512, 256, 512, zp);
    }

    // fused deformable attention (samples xck/xcv maps)
    attn_kernel<<<dim3(512, 16), 256, 0, stream>>>(qp, xck, xcv, kh, vh, pos, attno);

    // out proj + residual + GN1
    r1_kernel<<<1024, 256, 0, stream>>>(attno, w_out, b_out, x_in, r1);
    stats1_bf_kernel<<<64, 256, 0, stream>>>(r1, part);
    stats2_kernel<<<1, 64, 0, stream>>>(part, stats_g1, 8);
    gnorm_kernel<<<4096, 256, 0, stream>>>(r1, stats_g1, gn1_g, gn1_b, 8);  // -> res2

    // FFN
    ffn1_kernel<<<1024, 256, 0, stream>>>(r1, ffn_w1, ffn_b1, y1bf);
    gemm_bt<0, 0><<<dim3(256, 2), 256, 0, stream>>>(y1bf, fw2b, ffn_b2, y2, 512, 256, zp);

    // GN2 + output transpose (overwrites d_out, incl. dead kh)
    stats1_mix_kernel<<<64, 256, 0, stream>>>(y2, r1, part);
    stats2_kernel<<<1, 64, 0, stream>>>(part, stats_g2, 1);
    final_kernel<<<dim3(256, 4, 2), 256, 0, stream>>>(y2, r1, stats_g2, gn2_g, gn2_b, out);
}

// Round 7
// 807.529 us; speedup vs baseline: 1.1915x; 1.0204x over previous
//
#include <hip/hip_runtime.h>
#include <hip/hip_bf16.h>
#include <math.h>

typedef unsigned short u16;
typedef __attribute__((ext_vector_type(8))) unsigned short u16v8;
typedef __attribute__((ext_vector_type(8))) __bf16 bf16v8;
typedef __attribute__((ext_vector_type(4))) float f32v4;

#define BB 2
#define MM 16384           // H*W
#define CC 256
#define NHH 8
#define PTS 4
#define BMTOT 32768        // B*M
#define SCALEF 0.17677669529663687f
#define PECOEF 0.03597789207803197f   // ln(10000)/256

__device__ __forceinline__ u16 f2bf(float f) {
    union { float f; unsigned u; } v; v.f = f;
    unsigned u = v.u;
    return (u16)((u + 0x7fffu + ((u >> 16) & 1u)) >> 16);
}
__device__ __forceinline__ float bf2f(u16 u) {
    union { unsigned u; float f; } v; v.u = ((unsigned)u) << 16; return v.f;
}
__device__ __forceinline__ float rsum32(float v) {
    #pragma unroll
    for (int m = 16; m; m >>= 1) v += __shfl_xor(v, m, 32);
    return v;
}
__device__ __forceinline__ void gload16(const void* g, void* l) {
    __builtin_amdgcn_global_load_lds(
        (const __attribute__((address_space(1))) void*)g,
        (__attribute__((address_space(3))) void*)l, 16, 0, 0);
}

// ---------------- prep: zero page + weight bf16 conversions ----------------
// wq is pre-scaled by SCALEF (folded out of the attention score).
__global__ __launch_bounds__(256)
void prep_kernel(const float* __restrict__ off_w1, const float* __restrict__ wq,
                 const float* __restrict__ wx, const float* __restrict__ fw2,
                 u16* zp, u16* w1t, u16* wqb, u16* wxb, u16* fw2b)
{
    const size_t n_zp = 128, n_w1 = 589824, n_q = 65536, n_f2 = 131072;
    const size_t total = n_zp + n_w1 + 2 * n_q + n_f2;
    for (size_t i = (size_t)blockIdx.x * 256 + threadIdx.x; i < total;
         i += (size_t)gridDim.x * 256) {
        size_t j = i;
        if (j < n_zp) { zp[j] = 0; continue; }
        j -= n_zp;
        if (j < n_w1) {  // w1t[oc][tap*256+ic] = off_w1[oc][ic][tap]
            size_t oc = j / 2304, r = j % 2304, tap = r >> 8, ic = r & 255;
            w1t[j] = f2bf(off_w1[(oc * 256 + ic) * 9 + tap]);
            continue;
        }
        j -= n_w1;
        if (j < n_q) { wqb[j] = f2bf(wq[j] * SCALEF); continue; }
        j -= n_q;
        if (j < n_q) { wxb[j] = f2bf(wx[j]); continue; }
        j -= n_q;
        fw2b[j] = f2bf(fw2[j]);
    }
}

// ---------------- add positional encoding, transpose to pixel-major bf16 ----
__global__ __launch_bounds__(256)
void addpe_kernel(const float* __restrict__ q, const float* __restrict__ x,
                  u16* __restrict__ qpe, u16* __restrict__ xpe)
{
    __shared__ float lq[64][65], lx[64][65];
    const int m0 = blockIdx.x * 64, c0 = blockIdx.y * 64, b = blockIdx.z;
    const int tid = threadIdx.x;
    {
        const int ml = tid & 63, c4 = tid >> 6;
        for (int s = 0; s < 16; ++s) {
            int cl = s * 4 + c4;
            int c = c0 + cl, m = m0 + ml;
            float dv = expf(-(float)(c & ~1) * PECOEF);
            float a = (float)m * dv;
            float pe = (c & 1) ? cosf(a) : sinf(a);
            size_t gi = ((size_t)b * CC + c) * MM + m;
            lq[cl][ml] = q[gi] + pe;
            lx[cl][ml] = x[gi] + pe;
        }
    }
    __syncthreads();
    {
        const int cl = tid & 63, m4 = tid >> 6;
        for (int s = 0; s < 16; ++s) {
            int ml = s * 4 + m4;
            size_t oi = ((size_t)b * MM + m0 + ml) * CC + c0 + cl;
            qpe[oi] = f2bf(lq[cl][ml]);
            xpe[oi] = f2bf(lx[cl][ml]);
        }
    }
}

// ---------------- bf16 MFMA GEMM (global_load_lds staging) ------------------
// C[row,col] = sum_k A[row,k]*W[col,k] (+bias)
// AMODE 0: A row-major bf16 (rows x K). AMODE 1: implicit im2col 3x3 pad=1.
// OUTBF: 1 -> store bf16, 0 -> store fp32.
template<int AMODE, int OUTBF>
__global__ __launch_bounds__(256, 2)
void gemm_bt(const u16* __restrict__ A, const u16* __restrict__ Bw,
             const float* __restrict__ bias, void* __restrict__ Cout,
             int K, int N, const u16* __restrict__ zp)
{
    __shared__ u16 lA[128 * 32];
    __shared__ u16 lB[128 * 32];
    const int tid = threadIdx.x;
    const int w = tid >> 6, l = tid & 63;
    const int gm = blockIdx.x, gn = blockIdx.y;
    const int wm = w >> 1, wn = w & 1;
    const int rowIn = l >> 2;            // 0..15 within 16-row segment
    const int kc = (l & 3) << 3;         // k offset 0,8,16,24
    f32v4 acc[4][4] = {};

    for (int k0 = 0; k0 < K; k0 += 32) {
        #pragma unroll
        for (int r = 0; r < 2; ++r) {
            const int seg = r * 4 + w;          // 0..7
            const int row = seg * 16 + rowIn;   // 0..127
            const u16* gpA;
            if (AMODE == 0) {
                gpA = A + (size_t)(gm * 128 + row) * K + (k0 + kc);
            } else {
                int grow = gm * 128 + row;
                int bimg = grow >> 14, m = grow & 16383;
                int y = m >> 7, xx2 = m & 127;
                int kk2 = k0 + kc;
                int tap = kk2 >> 8, ic = kk2 & 255;
                int t3 = tap / 3;
                int py = y + t3 - 1, px = xx2 + (tap - t3 * 3) - 1;
                bool ok = ((unsigned)py < 128u) && ((unsigned)px < 128u);
                gpA = ok ? (A + (((size_t)((bimg << 14) + (py << 7) + px)) << 8) + ic) : zp;
            }
            gload16(gpA, lA + seg * 512);
            const u16* gpB = Bw + (size_t)(gn * 128 + row) * K + (k0 + kc);
            gload16(gpB, lB + seg * 512);
        }
        __syncthreads();
        bf16v8 af[4], bf[4];
        #pragma unroll
        for (int i = 0; i < 4; ++i) {
            af[i] = *(const bf16v8*)&lA[((wm << 6) + (i << 4) + (l & 15)) * 32 + ((l >> 4) << 3)];
            bf[i] = *(const bf16v8*)&lB[((wn << 6) + (i << 4) + (l & 15)) * 32 + ((l >> 4) << 3)];
        }
        #pragma unroll
        for (int i = 0; i < 4; ++i)
            #pragma unroll
            for (int j = 0; j < 4; ++j)
                acc[i][j] = __builtin_amdgcn_mfma_f32_16x16x32_bf16(af[i], bf[j], acc[i][j], 0, 0, 0);
        __syncthreads();
    }

    const int l15 = l & 15, l4 = l >> 4;
    #pragma unroll
    for (int i = 0; i < 4; ++i) {
        int row = gm * 128 + (wm << 6) + (i << 4) + (l4 << 2);
        #pragma unroll
        for (int j = 0; j < 4; ++j) {
            int col = gn * 128 + (wn << 6) + (j << 4) + l15;
            float bv = bias ? bias[col] : 0.0f;
            #pragma unroll
            for (int r = 0; r < 4; ++r) {
                float val = acc[i][j][r] + bv;
                if (OUTBF) ((u16*)Cout)[(size_t)(row + r) * N + col] = f2bf(val);
                else       ((float*)Cout)[(size_t)(row + r) * N + col] = val;
            }
        }
    }
}

// ---------------- GroupNorm stats stage 1 (bf16 input) ----------------
__global__ __launch_bounds__(256)
void stats1_bf_kernel(const u16* __restrict__ a, float* __restrict__ part)
{
    __shared__ float ls[256], lss[256];
    const int blk = blockIdx.x;           // B*32 blocks
    const int bb = blk >> 5, ch = blk & 31;
    const size_t base = ((size_t)bb * MM + ch * 512) * CC;
    const int tid = threadIdx.x;
    float s = 0.f, ss = 0.f;
    for (int p = 0; p < 512; ++p) {
        float v = bf2f(a[base + (size_t)p * CC + tid]);
        s += v; ss += v * v;
    }
    ls[tid] = s; lss[tid] = ss;
    __syncthreads();
    if (tid < 8) {
        float S = 0.f, SS = 0.f;
        for (int j = 0; j < 32; ++j) { S += ls[tid * 32 + j]; SS += lss[tid * 32 + j]; }
        part[(blk * 8 + tid) * 2] = S;
        part[(blk * 8 + tid) * 2 + 1] = SS;
    }
}

// stage 1, fp32 y2 + inline-GN1(raw r1) (for GN2 stats)
__global__ __launch_bounds__(256)
void stats1_mix_kernel(const float* __restrict__ a, const u16* __restrict__ r1raw,
                       const float2* __restrict__ st1, const float* __restrict__ g1g,
                       const float* __restrict__ g1b, float* __restrict__ part)
{
    __shared__ float ls[256], lss[256];
    const int blk = blockIdx.x;
    const int bb = blk >> 5, ch = blk & 31;
    const size_t base = ((size_t)bb * MM + ch * 512) * CC;
    const int tid = threadIdx.x;
    const float2 st = st1[bb * 8 + (tid >> 5)];
    const float gg = g1g[tid], gb = g1b[tid];
    float s = 0.f, ss = 0.f;
    for (int p = 0; p < 512; ++p) {
        float rv = (bf2f(r1raw[base + (size_t)p * CC + tid]) - st.x) * st.y * gg + gb;
        float v = a[base + (size_t)p * CC + tid] + rv;
        s += v; ss += v * v;
    }
    ls[tid] = s; lss[tid] = ss;
    __syncthreads();
    if (tid < 8) {
        float S = 0.f, SS = 0.f;
        for (int j = 0; j < 32; ++j) { S += ls[tid * 32 + j]; SS += lss[tid * 32 + j]; }
        part[(blk * 8 + tid) * 2] = S;
        part[(blk * 8 + tid) * 2 + 1] = SS;
    }
}

__global__ __launch_bounds__(64)
void stats2_kernel(const float* __restrict__ part, float2* __restrict__ stats, int NG)
{
    const int t = threadIdx.x;
    if (t >= 2 * NG) return;
    const int bb = t / NG, g = t % NG;
    const int gsub = 8 / NG;
    float S = 0.f, SS = 0.f;
    for (int ch = 0; ch < 32; ++ch)
        for (int j = 0; j < gsub; ++j) {
            int idx = (bb * 32 + ch) * 8 + g * gsub + j;
            S += part[idx * 2]; SS += part[idx * 2 + 1];
        }
    const float cnt = (256.0f / NG) * 16384.0f;
    float mu = S / cnt;
    float var = SS / cnt - mu * mu;
    stats[bb * NG + g] = make_float2(mu, rsqrtf(var + 1e-5f));
}

// ---------------- conv_offset tail: GN(1)+ReLU -> grouped 1x1 -> tanh -------
__global__ __launch_bounds__(256)
void offset_kernel(const u16* __restrict__ t, const float2* __restrict__ stats_t,
                   const float* __restrict__ gng, const float* __restrict__ gnb,
                   const float* __restrict__ w2, u16* __restrict__ pos)
{
    __shared__ float lt[4 * 256];
    const int tid = threadIdx.x;
    const int bm0 = blockIdx.x * 4;
    const int b = bm0 >> 14;
    const float2 st = stats_t[b];
    for (int idx = tid; idx < 1024; idx += 256) {
        int pix = idx >> 8, c = idx & 255;
        float v = bf2f(t[(size_t)(bm0 + pix) * CC + c]);
        v = (v - st.x) * st.y * gng[c] + gnb[c];
        lt[idx] = fmaxf(v, 0.0f);
    }
    __syncthreads();
    const int pix = tid >> 6, go = tid & 63;
    const int g = go >> 3, o = go & 7;
    float s = 0.f;
    #pragma unroll
    for (int ci = 0; ci < 32; ++ci) {
        int ce = (ci + g * 4) & 31;                 // bank rotation
        s += w2[(g * 8 + o) * 32 + ce] * lt[pix * 256 + g * 32 + ce];
    }
    const int m = (bm0 + pix) & 16383;
    const int p = o >> 1, c2 = o & 1;
    pos[((((size_t)b * NHH + g) * PTS + p) * MM + m) * 2 + c2] = f2bf(tanhf(s));
}

// ---------------- channel-attention pooling + gate + weight folding --------
__global__ __launch_bounds__(256)
void pool1_kernel(const u16* __restrict__ xc, float* __restrict__ pmax,
                  float* __restrict__ psum)
{
    const int blk = blockIdx.x;
    const int bb = blk >> 5, ch = blk & 31;
    const size_t base = ((size_t)bb * MM + ch * 512) * CC;
    const int tid = threadIdx.x;
    float mx = -1e30f, s = 0.f;
    for (int p = 0; p < 512; ++p) {
        float v = bf2f(xc[base + (size_t)p * CC + tid]);
        mx = fmaxf(mx, v); s += v;
    }
    pmax[blk * 256 + tid] = mx;
    psum[blk * 256 + tid] = s;
}

__global__ __launch_bounds__(256)
void pool2_gate_kernel(const float* __restrict__ pmax, const float* __restrict__ psum,
                       const float* __restrict__ ca_w, float* __restrict__ gate)
{
    __shared__ float sv[256];
    const int bb = blockIdx.x, tid = threadIdx.x;
    float mx = -1e30f, s = 0.f;
    for (int ch = 0; ch < 32; ++ch) {
        mx = fmaxf(mx, pmax[(bb * 32 + ch) * 256 + tid]);
        s += psum[(bb * 32 + ch) * 256 + tid];
    }
    sv[tid] = mx + s * (1.0f / 16384.0f);   // mx + av
    __syncthreads();
    float acc = 0.f;
    for (int ci = 0; ci < 256; ++ci) acc += ca_w[tid * 256 + ci] * sv[ci];
    gate[bb * 256 + tid] = 1.0f / (1.0f + expf(-acc));
}

// fold (1+gate[b,c]) into wkh/wvh columns, per batch -> bf16
__global__ __launch_bounds__(256)
void scalekv_kernel(const float* __restrict__ wkh, const float* __restrict__ wvh,
                    const float* __restrict__ gate, u16* __restrict__ wkhs,
                    u16* __restrict__ wvhs)
{
    const int n1 = 512 * 256;                   // per-batch weight count
    for (int i = blockIdx.x * 256 + threadIdx.x; i < 4 * n1;
         i += gridDim.x * 256) {
        int which = i / (2 * n1);               // 0: kh, 1: vh
        int r = i % (2 * n1);
        int b = r / n1, j = r % n1;
        float gsc = 1.0f + gate[b * 256 + (j & 255)];
        if (which == 0) wkhs[b * n1 + j] = f2bf(wkh[j] * gsc);
        else            wvhs[b * n1 + j] = f2bf(wvh[j] * gsc);
    }
}

// ---------------- per-head projection maps, interleaved k|v -----------------
// xckv[pix*512 + c*2] = k-proj, [pix*512 + c*2 + 1] = v-proj (one u32 per c).
__global__ __launch_bounds__(256)
void projkv_kernel(const u16* __restrict__ xc, const float* __restrict__ wk,
                   const float* __restrict__ wv, u16* __restrict__ xckv)
{
    __shared__ float la[256];
    const int tid = threadIdx.x;
    const int g = tid >> 5;
    float wkr[32], wvr[32];
    #pragma unroll
    for (int dd = 0; dd < 32; ++dd) {
        wkr[dd] = wk[tid * 32 + dd];   // wk[(nh*32+d)*32+e]
        wvr[dd] = wv[tid * 32 + dd];
    }
    const int m0 = blockIdx.x * 32;
    for (int i = 0; i < 32; ++i) {
        const size_t bm = m0 + i;
        la[tid] = bf2f(xc[bm * CC + tid]);
        __syncthreads();
        float ok = 0.f, ov = 0.f;
        #pragma unroll
        for (int dd = 0; dd < 32; ++dd) {
            ok += wkr[dd] * la[g * 32 + dd];
            ov += wvr[dd] * la[g * 32 + dd];
        }
        unsigned pack = (unsigned)f2bf(ok) | ((unsigned)f2bf(ov) << 16);
        *(unsigned*)&xckv[bm * 512 + tid * 2] = pack;
        __syncthreads();
    }
}

// ---------------- fused deformable sampling + attention ----------
__global__ __launch_bounds__(256)
void attn_kernel(const u16* __restrict__ qp, const u16* __restrict__ xckv,
                 const u16* __restrict__ kh, const u16* __restrict__ vh,
                 const u16* __restrict__ pos, u16* __restrict__ attno)
{
    const int tid = threadIdx.x;
    const int g = tid >> 5, d = tid & 31;
    const int bh = blockIdx.y;
    const int b = bh >> 3, nh = bh & 7;
    const int co = nh * 32 + d;
    const size_t hb = (size_t)b * MM;
    #pragma unroll
    for (int i = 0; i < 4; ++i) {
        const int m = blockIdx.x * 32 + i * 8 + g;
        const size_t bm = hb + m;
        const float qd = bf2f(qp[bm * CC + co]);   // pre-scaled by SCALEF
        const int yy = m >> 7, xx = m & 127;
        float kk[6], vv[6];
        #pragma unroll
        for (int p = 0; p < 4; ++p) {
            const u16* pp = pos + ((((size_t)b * NHH + nh) * PTS + p) * MM + m) * 2;
            float gy = (float)yy + 0.5f + bf2f(pp[0]);
            float gx = (float)xx + 0.5f + bf2f(pp[1]);
            int ix0 = (int)floorf(gx), iy0 = (int)floorf(gy);
            float fx = gx - (float)ix0, fy = gy - (float)iy0;
            float w00 = (1.f - fx) * (1.f - fy), w10 = fx * (1.f - fy);
            float w01 = (1.f - fx) * fy, w11 = fx * fy;
            float sk = 0.f, sv = 0.f;
            if ((unsigned)ix0 < 128u && (unsigned)iy0 < 128u) {
                unsigned kv = *(const unsigned*)&xckv[(hb + iy0 * 128 + ix0) * 512 + co * 2];
                sk += w00 * bf2f((u16)kv); sv += w00 * bf2f((u16)(kv >> 16));
            }
            if ((unsigned)(ix0 + 1) < 128u && (unsigned)iy0 < 128u) {
                unsigned kv = *(const unsigned*)&xckv[(hb + iy0 * 128 + ix0 + 1) * 512 + co * 2];
                sk += w10 * bf2f((u16)kv); sv += w10 * bf2f((u16)(kv >> 16));
            }
            if ((unsigned)ix0 < 128u && (unsigned)(iy0 + 1) < 128u) {
                unsigned kv = *(const unsigned*)&xckv[(hb + (iy0 + 1) * 128 + ix0) * 512 + co * 2];
                sk += w01 * bf2f((u16)kv); sv += w01 * bf2f((u16)(kv >> 16));
            }
            if ((unsigned)(ix0 + 1) < 128u && (unsigned)(iy0 + 1) < 128u) {
                unsigned kv = *(const unsigned*)&xckv[(hb + (iy0 + 1) * 128 + ix0 + 1) * 512 + co * 2];
                sk += w11 * bf2f((u16)kv); sv += w11 * bf2f((u16)(kv >> 16));
            }
            kk[p] = sk; vv[p] = sv;
        }
        #pragma unroll
        for (int p = 0; p < 2; ++p) {
            kk[4 + p] = bf2f(kh[bm * 512 + nh * 64 + p * 32 + d]);
            vv[4 + p] = bf2f(vh[bm * 512 + nh * 64 + p * 32 + d]);
        }
        float s[6];
        #pragma unroll
        for (int p = 0; p < 6; ++p) s[p] = rsum32(qd * kk[p]);
        float mx = s[0];
        #pragma unroll
        for (int p = 1; p < 6; ++p) mx = fmaxf(mx, s[p]);
        float es[6], ssum = 0.f;
        #pragma unroll
        for (int p = 0; p < 6; ++p) { es[p] = expf(s[p] - mx); ssum += es[p]; }
        const float inv = 1.0f / ssum;
        float od = 0.f;
        #pragma unroll
        for (int p = 0; p < 6; ++p) od += es[p] * inv * vv[p];
        attno[bm * CC + co] = f2bf(od);
    }
}

// ---------------- w_out grouped conv + bias + residual1(x, NCHW) ------------
// writes RAW r1 (pre-GN1); GN1 is applied inline downstream.
__global__ __launch_bounds__(256)
void r1_kernel(const u16* __restrict__ attno, const float* __restrict__ w_out,
               const float* __restrict__ b_out, const float* __restrict__ x_in,
               u16* __restrict__ r1)
{
    __shared__ float la[256];
    const int tid = threadIdx.x;
    const int g = tid >> 5;
    float wr[32];
    #pragma unroll
    for (int dd = 0; dd < 32; ++dd) wr[dd] = w_out[tid * 32 + dd]; // (g*32+oc)*32+d
    const float bo = b_out[tid];
    const int m0 = blockIdx.x * 32;
    for (int i = 0; i < 32; ++i) {
        const size_t bm = m0 + i;
        la[tid] = bf2f(attno[bm * CC + tid]);
        __syncthreads();
        float o = 0.f;
        #pragma unroll
        for (int dd = 0; dd < 32; ++dd) o += wr[dd] * la[g * 32 + dd];
        const int b = (int)(bm >> 14), m = (int)(bm & 16383);
        float xv = x_in[((size_t)b * CC + tid) * MM + m];
        r1[bm * CC + tid] = f2bf(xv + o + bo);
        __syncthreads();
    }
}

// ---------------- FFN first grouped conv (inline GN1) + bias + relu ---------
__global__ __launch_bounds__(256)
void ffn1_kernel(const u16* __restrict__ r1raw, const float2* __restrict__ st1,
                 const float* __restrict__ g1g, const float* __restrict__ g1b,
                 const float* __restrict__ w1, const float* __restrict__ b1,
                 u16* __restrict__ y1bf)
{
    __shared__ float la[256];
    const int tid = threadIdx.x;
    float wr0[32], wr1[32];
    #pragma unroll
    for (int dd = 0; dd < 32; ++dd) {
        wr0[dd] = w1[tid * 32 + dd];
        wr1[dd] = w1[(tid + 256) * 32 + dd];
    }
    const float bb0 = b1[tid], bb1 = b1[tid + 256];
    const int g0 = tid >> 6, g1 = 4 + (tid >> 6);
    const int m0 = blockIdx.x * 32;
    const int bb = m0 >> 14;
    const float2 st = st1[bb * 8 + (tid >> 5)];
    const float gg = g1g[tid], gb = g1b[tid];
    for (int i = 0; i < 32; ++i) {
        const size_t bm = m0 + i;
        la[tid] = (bf2f(r1raw[bm * CC + tid]) - st.x) * st.y * gg + gb;
        __syncthreads();
        float o0 = bb0, o1 = bb1;
        #pragma unroll
        for (int dd = 0; dd < 32; ++dd) {
            o0 += wr0[dd] * la[g0 * 32 + dd];
            o1 += wr1[dd] * la[g1 * 32 + dd];
        }
        y1bf[bm * 512 + tid] = f2bf(fmaxf(o0, 0.f));
        y1bf[bm * 512 + tid + 256] = f2bf(fmaxf(o1, 0.f));
        __syncthreads();
    }
}

// ---------------- final: GN2( y2 + GN1(r1) ) + transpose to NCHW ------------
__global__ __launch_bounds__(256)
void final_kernel(const float* __restrict__ y2, const u16* __restrict__ r1raw,
                  const float2* __restrict__ st1, const float* __restrict__ g1g,
                  const float* __restrict__ g1b, const float2* __restrict__ stats,
                  const float* __restrict__ gg, const float* __restrict__ gb,
                  float* __restrict__ out)
{
    __shared__ float lt[64][65];
    const int m0 = blockIdx.x * 64, c0 = blockIdx.y * 64, b = blockIdx.z;
    const int tid = threadIdx.x;
    const float2 st = stats[b];
    {
        const int cl = tid & 63, m4 = tid >> 6;
        const int c = c0 + cl;
        const float2 s1 = st1[b * 8 + (c >> 5)];
        const float g1 = g1g[c], b1 = g1b[c];
        for (int s = 0; s < 16; ++s) {
            int ml = s * 4 + m4;
            size_t idx = ((size_t)b * MM + m0 + ml) * CC + c;
            float rv = (bf2f(r1raw[idx]) - s1.x) * s1.y * g1 + b1;
            float v = y2[idx] + rv;
            lt[cl][ml] = (v - st.x) * st.y * gg[c] + gb[c];
        }
    }
    __syncthreads();
    {
        const int mlw = tid & 63, c4 = tid >> 6;
        for (int s = 0; s < 16; ++s) {
            int clw = s * 4 + c4;
            out[((size_t)b * CC + c0 + clw) * MM + m0 + mlw] = lt[clw][mlw];
        }
    }
}

// diagnostic: written iff workspace is too small (absmax ~1000 signals it)
__global__ void sentinel_kernel(float* out) { out[threadIdx.x] = 1000.0f; }

// ============================ host side ============================
extern "C" void kernel_launch(void* const* d_in, const int* in_sizes, int n_in,
                              void* d_out, int out_size, void* d_ws, size_t ws_size,
                              hipStream_t stream)
{
    const float* q_in   = (const float*)d_in[0];
    const float* x_in   = (const float*)d_in[1];
    const float* off_w1 = (const float*)d_in[2];
    const float* off_b1 = (const float*)d_in[3];
    const float* off_gn_g = (const float*)d_in[4];
    const float* off_gn_b = (const float*)d_in[5];
    const float* off_w2 = (const float*)d_in[6];
    const float* wq     = (const float*)d_in[7];
    const float* wk     = (const float*)d_in[8];
    const float* wv     = (const float*)d_in[9];
    const float* wx     = (const float*)d_in[10];
    const float* w_out  = (const float*)d_in[11];
    const float* b_out  = (const float*)d_in[12];
    const float* wkh    = (const float*)d_in[13];
    const float* wvh    = (const float*)d_in[14];
    const float* ca_w   = (const float*)d_in[15];
    const float* gn1_g  = (const float*)d_in[16];
    const float* gn1_b  = (const float*)d_in[17];
    const float* ffn_w1 = (const float*)d_in[18];
    const float* ffn_b1 = (const float*)d_in[19];
    const float* ffn_w2 = (const float*)d_in[20];
    const float* ffn_b2 = (const float*)d_in[21];
    const float* gn2_g  = (const float*)d_in[22];
    const float* gn2_b  = (const float*)d_in[23];
    float* out = (float*)d_out;

    char* W = (char*)d_ws;
    size_t off = 0;
    auto AL = [&](size_t sz) -> char* {
        char* p = W + off;
        off += (sz + 255) & ~(size_t)255;
        return p;
    };
    u16* zp    = (u16*)AL(256);
    u16* w1t   = (u16*)AL(589824 * 2);
    u16* wqb   = (u16*)AL(65536 * 2);
    u16* wxb   = (u16*)AL(65536 * 2);
    u16* fw2b  = (u16*)AL(131072 * 2);
    u16* wkhs  = (u16*)AL(2 * 131072 * 2);     // per-batch gate-folded
    u16* wvhs  = (u16*)AL(2 * 131072 * 2);
    u16* slotA = (u16*)AL((size_t)BMTOT * CC * 2);   // qpe -> attno -> y2(lo)
    u16* slotC = (u16*)AL((size_t)BMTOT * CC * 2);   // t -> xc -> y2(hi)
    u16* slotD = (u16*)AL((size_t)BMTOT * CC * 2);   // qp
    u16* slotB = (u16*)AL((size_t)BMTOT * CC * 2);   // xpe -> xckv(lo) -> r1(raw)
    u16* slotE = (u16*)AL((size_t)BMTOT * CC * 2);   // xckv(hi)
    u16* slotG = (u16*)AL((size_t)BMTOT * 512 * 2);  // vh -> y1bf
    u16* pos   = (u16*)AL((size_t)BB * NHH * PTS * MM * 2 * 2);
    float* part  = (float*)AL(64 * 8 * 2 * 4);
    float* pmax  = (float*)AL(64 * 256 * 4);
    float* psum  = (float*)AL(64 * 256 * 4);
    float* gate  = (float*)AL(2 * 256 * 4);
    float2* stats_t  = (float2*)AL(2 * sizeof(float2));
    float2* stats_g1 = (float2*)AL(16 * sizeof(float2));
    float2* stats_g2 = (float2*)AL(2 * sizeof(float2));

    u16* qpe = slotA;  u16* attno = slotA;
    u16* t_b = slotC;  u16* xc  = slotC;
    u16* qp  = slotD;
    u16* xpe = slotB;
    u16* xckv = slotB;                       // spans slotB+slotE (contiguous, 33.5 MB)
    u16* r1  = slotB;                        // raw r1 after attn (xckv dead)
    u16* vh  = slotG;  u16* y1bf = slotG;
    u16* kh  = (u16*)d_out;                  // 33.5 MB, dead before final_kernel
    float* y2 = (float*)slotA;               // spans slotA+slotC (contiguous)

    if (off > ws_size) {                     // ws too small: absmax ~1000 signals it
        sentinel_kernel<<<1, 256, 0, stream>>>(out);
        return;
    }

    prep_kernel<<<3329, 256, 0, stream>>>(off_w1, wq, wx, ffn_w2,
                                          zp, w1t, wqb, wxb, fw2b);
    addpe_kernel<<<dim3(256, 4, 2), 256, 0, stream>>>(q_in, x_in, qpe, xpe);

    // conv_offset 3x3 (implicit im2col) -> t
    gemm_bt<1, 1><<<dim3(256, 2), 256, 0, stream>>>(qpe, w1t, off_b1, t_b, 2304, 256, zp);
    stats1_bf_kernel<<<64, 256, 0, stream>>>(t_b, part);
    stats2_kernel<<<1, 64, 0, stream>>>(part, stats_t, 1);
    offset_kernel<<<8192, 256, 0, stream>>>(t_b, stats_t, off_gn_g, off_gn_b, off_w2, pos);

    // qp projection (after conv GEMM so slotC reuse is safe)
    gemm_bt<0, 1><<<dim3(256, 2), 256, 0, stream>>>(qpe, wqb, nullptr, qp, 256, 256, zp);
    // x branch: conv -> xc (overwrites t, which is now dead)
    gemm_bt<0, 1><<<dim3(256, 2), 256, 0, stream>>>(xpe, wxb, nullptr, xc, 256, 256, zp);
    pool1_kernel<<<64, 256, 0, stream>>>(xc, pmax, psum);
    pool2_gate_kernel<<<2, 256, 0, stream>>>(pmax, psum, ca_w, gate);
    scalekv_kernel<<<2048, 256, 0, stream>>>(wkh, wvh, gate, wkhs, wvhs);
    // per-head k/v maps, interleaved (xpe dead now; xckv overwrites slotB+slotE)
    projkv_kernel<<<1024, 256, 0, stream>>>(xc, wk, wv, xckv);

    // kh/vh GEMMs with gate-folded per-batch weights
    for (int b = 0; b < 2; ++b) {
        gemm_bt<0, 1><<<dim3(128, 4), 256, 0, stream>>>(
            xc + (size_t)b * MM * CC, wkhs + (size_t)b * 131072, nullptr,
            kh + (size_t)b * MM * 512, 256, 512, zp);
        gemm_bt<0, 1><<<dim3(128, 4), 256, 0, stream>>>(
            xc + (size_t)b * MM * CC, wvhs + (size_t)b * 131072, nullptr,
            vh + (size_t)b * MM * 512, 256, 512, zp);
    }

    // fused deformable attention (samples interleaved xckv map)
    attn_kernel<<<dim3(512, 16), 256, 0, stream>>>(qp, xckv, kh, vh, pos, attno);

    // out proj + residual -> raw r1; GN1 stats; GN1 applied inline downstream
    r1_kernel<<<1024, 256, 0, stream>>>(attno, w_out, b_out, x_in, r1);
    stats1_bf_kernel<<<64, 256, 0, stream>>>(r1, part);
    stats2_kernel<<<1, 64, 0, stream>>>(part, stats_g1, 8);

    // FFN (GN1 inline)
    ffn1_kernel<<<1024, 256, 0, stream>>>(r1, stats_g1, gn1_g, gn1_b,
                                          ffn_w1, ffn_b1, y1bf);
    gemm_bt<0, 0><<<dim3(256, 2), 256, 0, stream>>>(y1bf, fw2b, ffn_b2, y2, 512, 256, zp);

    // GN2 stats over y2 + GN1(r1); final normalize + transpose
    stats1_mix_kernel<<<64, 256, 0, stream>>>(y2, r1, stats_g1, gn1_g, gn1_b, part);
    stats2_kernel<<<1, 64, 0, stream>>>(part, stats_g2, 1);
    final_kernel<<<dim3(256, 4, 2), 256, 0, stream>>>(y2, r1, stats_g1, gn1_g, gn1_b,
                                                      stats_g2, gn2_g, gn2_b, out);
}

// Round 8
// 724.477 us; speedup vs baseline: 1.3281x; 1.1146x over previous
//
#include <hip/hip_runtime.h>
#include <hip/hip_bf16.h>
#include <math.h>

typedef unsigned short u16;
typedef __attribute__((ext_vector_type(8))) unsigned short u16v8;
typedef __attribute__((ext_vector_type(8))) __bf16 bf16v8;
typedef __attribute__((ext_vector_type(4))) float f32v4;

#define BB 2
#define MM 16384           // H*W
#define CC 256
#define NHH 8
#define PTS 4
#define BMTOT 32768        // B*M
#define SCALEF 0.17677669529663687f
#define PECOEF 0.03597789207803197f   // ln(10000)/256
#define PD 131             // padded map dim (1 low, 2 high zero border)
#define PDPIX (PD*PD)      // 17161

__device__ __forceinline__ u16 f2bf(float f) {
    union { float f; unsigned u; } v; v.f = f;
    unsigned u = v.u;
    return (u16)((u + 0x7fffu + ((u >> 16) & 1u)) >> 16);
}
__device__ __forceinline__ float bf2f(u16 u) {
    union { unsigned u; float f; } v; v.u = ((unsigned)u) << 16; return v.f;
}
__device__ __forceinline__ float rsum32(float v) {
    #pragma unroll
    for (int m = 16; m; m >>= 1) v += __shfl_xor(v, m, 32);
    return v;
}
__device__ __forceinline__ void gload16(const void* g, void* l) {
    __builtin_amdgcn_global_load_lds(
        (const __attribute__((address_space(1))) void*)g,
        (__attribute__((address_space(3))) void*)l, 16, 0, 0);
}

// ---------------- prep: zero page + weight bf16 conversions ----------------
// wq is pre-scaled by SCALEF (folded out of the attention score).
__global__ __launch_bounds__(256)
void prep_kernel(const float* __restrict__ off_w1, const float* __restrict__ wq,
                 const float* __restrict__ wx, const float* __restrict__ fw2,
                 u16* zp, u16* w1t, u16* wqb, u16* wxb, u16* fw2b)
{
    const size_t n_zp = 128, n_w1 = 589824, n_q = 65536, n_f2 = 131072;
    const size_t total = n_zp + n_w1 + 2 * n_q + n_f2;
    for (size_t i = (size_t)blockIdx.x * 256 + threadIdx.x; i < total;
         i += (size_t)gridDim.x * 256) {
        size_t j = i;
        if (j < n_zp) { zp[j] = 0; continue; }
        j -= n_zp;
        if (j < n_w1) {  // w1t[oc][tap*256+ic] = off_w1[oc][ic][tap]
            size_t oc = j / 2304, r = j % 2304, tap = r >> 8, ic = r & 255;
            w1t[j] = f2bf(off_w1[(oc * 256 + ic) * 9 + tap]);
            continue;
        }
        j -= n_w1;
        if (j < n_q) { wqb[j] = f2bf(wq[j] * SCALEF); continue; }
        j -= n_q;
        if (j < n_q) { wxb[j] = f2bf(wx[j]); continue; }
        j -= n_q;
        fw2b[j] = f2bf(fw2[j]);
    }
}

// ---------------- add positional encoding, transpose to pixel-major bf16 ----
__global__ __launch_bounds__(256)
void addpe_kernel(const float* __restrict__ q, const float* __restrict__ x,
                  u16* __restrict__ qpe, u16* __restrict__ xpe)
{
    __shared__ float lq[64][65], lx[64][65];
    const int m0 = blockIdx.x * 64, c0 = blockIdx.y * 64, b = blockIdx.z;
    const int tid = threadIdx.x;
    {
        const int ml = tid & 63, c4 = tid >> 6;
        for (int s = 0; s < 16; ++s) {
            int cl = s * 4 + c4;
            int c = c0 + cl, m = m0 + ml;
            float dv = __expf(-(float)(c & ~1) * PECOEF);
            float a = (float)m * dv;
            float pe = (c & 1) ? __cosf(a) : __sinf(a);
            size_t gi = ((size_t)b * CC + c) * MM + m;
            lq[cl][ml] = q[gi] + pe;
            lx[cl][ml] = x[gi] + pe;
        }
    }
    __syncthreads();
    {
        const int cl = tid & 63, m4 = tid >> 6;
        for (int s = 0; s < 16; ++s) {
            int ml = s * 4 + m4;
            size_t oi = ((size_t)b * MM + m0 + ml) * CC + c0 + cl;
            qpe[oi] = f2bf(lq[cl][ml]);
            xpe[oi] = f2bf(lx[cl][ml]);
        }
    }
}

// ---------------- bf16 MFMA GEMM (global_load_lds staging) ------------------
template<int AMODE, int OUTBF>
__global__ __launch_bounds__(256, 2)
void gemm_bt(const u16* __restrict__ A, const u16* __restrict__ Bw,
             const float* __restrict__ bias, void* __restrict__ Cout,
             int K, int N, const u16* __restrict__ zp)
{
    __shared__ u16 lA[128 * 32];
    __shared__ u16 lB[128 * 32];
    const int tid = threadIdx.x;
    const int w = tid >> 6, l = tid & 63;
    const int gm = blockIdx.x, gn = blockIdx.y;
    const int wm = w >> 1, wn = w & 1;
    const int rowIn = l >> 2;            // 0..15 within 16-row segment
    const int kc = (l & 3) << 3;         // k offset 0,8,16,24
    f32v4 acc[4][4] = {};

    for (int k0 = 0; k0 < K; k0 += 32) {
        #pragma unroll
        for (int r = 0; r < 2; ++r) {
            const int seg = r * 4 + w;          // 0..7
            const int row = seg * 16 + rowIn;   // 0..127
            const u16* gpA;
            if (AMODE == 0) {
                gpA = A + (size_t)(gm * 128 + row) * K + (k0 + kc);
            } else {
                int grow = gm * 128 + row;
                int bimg = grow >> 14, m = grow & 16383;
                int y = m >> 7, xx2 = m & 127;
                int kk2 = k0 + kc;
                int tap = kk2 >> 8, ic = kk2 & 255;
                int t3 = tap / 3;
                int py = y + t3 - 1, px = xx2 + (tap - t3 * 3) - 1;
                bool ok = ((unsigned)py < 128u) && ((unsigned)px < 128u);
                gpA = ok ? (A + (((size_t)((bimg << 14) + (py << 7) + px)) << 8) + ic) : zp;
            }
            gload16(gpA, lA + seg * 512);
            const u16* gpB = Bw + (size_t)(gn * 128 + row) * K + (k0 + kc);
            gload16(gpB, lB + seg * 512);
        }
        __syncthreads();
        bf16v8 af[4], bf[4];
        #pragma unroll
        for (int i = 0; i < 4; ++i) {
            af[i] = *(const bf16v8*)&lA[((wm << 6) + (i << 4) + (l & 15)) * 32 + ((l >> 4) << 3)];
            bf[i] = *(const bf16v8*)&lB[((wn << 6) + (i << 4) + (l & 15)) * 32 + ((l >> 4) << 3)];
        }
        #pragma unroll
        for (int i = 0; i < 4; ++i)
            #pragma unroll
            for (int j = 0; j < 4; ++j)
                acc[i][j] = __builtin_amdgcn_mfma_f32_16x16x32_bf16(af[i], bf[j], acc[i][j], 0, 0, 0);
        __syncthreads();
    }

    const int l15 = l & 15, l4 = l >> 4;
    #pragma unroll
    for (int i = 0; i < 4; ++i) {
        int row = gm * 128 + (wm << 6) + (i << 4) + (l4 << 2);
        #pragma unroll
        for (int j = 0; j < 4; ++j) {
            int col = gn * 128 + (wn << 6) + (j << 4) + l15;
            float bv = bias ? bias[col] : 0.0f;
            #pragma unroll
            for (int r = 0; r < 4; ++r) {
                float val = acc[i][j][r] + bv;
                if (OUTBF) ((u16*)Cout)[(size_t)(row + r) * N + col] = f2bf(val);
                else       ((float*)Cout)[(size_t)(row + r) * N + col] = val;
            }
        }
    }
}

// ---------------- GroupNorm stats stage 1 (bf16 input) ----------------
__global__ __launch_bounds__(256)
void stats1_bf_kernel(const u16* __restrict__ a, float* __restrict__ part)
{
    __shared__ float ls[256], lss[256];
    const int blk = blockIdx.x;           // B*32 blocks
    const int bb = blk >> 5, ch = blk & 31;
    const size_t base = ((size_t)bb * MM + ch * 512) * CC;
    const int tid = threadIdx.x;
    float s = 0.f, ss = 0.f;
    for (int p = 0; p < 512; ++p) {
        float v = bf2f(a[base + (size_t)p * CC + tid]);
        s += v; ss += v * v;
    }
    ls[tid] = s; lss[tid] = ss;
    __syncthreads();
    if (tid < 8) {
        float S = 0.f, SS = 0.f;
        for (int j = 0; j < 32; ++j) { S += ls[tid * 32 + j]; SS += lss[tid * 32 + j]; }
        part[(blk * 8 + tid) * 2] = S;
        part[(blk * 8 + tid) * 2 + 1] = SS;
    }
}

// stage 1, fp32 y2 + inline-GN1(raw r1) (for GN2 stats)
__global__ __launch_bounds__(256)
void stats1_mix_kernel(const float* __restrict__ a, const u16* __restrict__ r1raw,
                       const float2* __restrict__ st1, const float* __restrict__ g1g,
                       const float* __restrict__ g1b, float* __restrict__ part)
{
    __shared__ float ls[256], lss[256];
    const int blk = blockIdx.x;
    const int bb = blk >> 5, ch = blk & 31;
    const size_t base = ((size_t)bb * MM + ch * 512) * CC;
    const int tid = threadIdx.x;
    const float2 st = st1[bb * 8 + (tid >> 5)];
    const float gg = g1g[tid], gb = g1b[tid];
    float s = 0.f, ss = 0.f;
    for (int p = 0; p < 512; ++p) {
        float rv = (bf2f(r1raw[base + (size_t)p * CC + tid]) - st.x) * st.y * gg + gb;
        float v = a[base + (size_t)p * CC + tid] + rv;
        s += v; ss += v * v;
    }
    ls[tid] = s; lss[tid] = ss;
    __syncthreads();
    if (tid < 8) {
        float S = 0.f, SS = 0.f;
        for (int j = 0; j < 32; ++j) { S += ls[tid * 32 + j]; SS += lss[tid * 32 + j]; }
        part[(blk * 8 + tid) * 2] = S;
        part[(blk * 8 + tid) * 2 + 1] = SS;
    }
}

__global__ __launch_bounds__(64)
void stats2_kernel(const float* __restrict__ part, float2* __restrict__ stats, int NG)
{
    const int t = threadIdx.x;
    if (t >= 2 * NG) return;
    const int bb = t / NG, g = t % NG;
    const int gsub = 8 / NG;
    float S = 0.f, SS = 0.f;
    for (int ch = 0; ch < 32; ++ch)
        for (int j = 0; j < gsub; ++j) {
            int idx = (bb * 32 + ch) * 8 + g * gsub + j;
            S += part[idx * 2]; SS += part[idx * 2 + 1];
        }
    const float cnt = (256.0f / NG) * 16384.0f;
    float mu = S / cnt;
    float var = SS / cnt - mu * mu;
    stats[bb * NG + g] = make_float2(mu, rsqrtf(var + 1e-5f));
}

// ---------------- conv_offset tail: GN(1)+ReLU -> grouped 1x1 -> tanh -------
__global__ __launch_bounds__(256)
void offset_kernel(const u16* __restrict__ t, const float2* __restrict__ stats_t,
                   const float* __restrict__ gng, const float* __restrict__ gnb,
                   const float* __restrict__ w2, u16* __restrict__ pos)
{
    __shared__ float lt[4 * 256];
    const int tid = threadIdx.x;
    const int bm0 = blockIdx.x * 4;
    const int b = bm0 >> 14;
    const float2 st = stats_t[b];
    for (int idx = tid; idx < 1024; idx += 256) {
        int pix = idx >> 8, c = idx & 255;
        float v = bf2f(t[(size_t)(bm0 + pix) * CC + c]);
        v = (v - st.x) * st.y * gng[c] + gnb[c];
        lt[idx] = fmaxf(v, 0.0f);
    }
    __syncthreads();
    const int pix = tid >> 6, go = tid & 63;
    const int g = go >> 3, o = go & 7;
    float s = 0.f;
    #pragma unroll
    for (int ci = 0; ci < 32; ++ci) {
        int ce = (ci + g * 4) & 31;                 // bank rotation
        s += w2[(g * 8 + o) * 32 + ce] * lt[pix * 256 + g * 32 + ce];
    }
    const int m = (bm0 + pix) & 16383;
    const int p = o >> 1, c2 = o & 1;
    pos[((((size_t)b * NHH + g) * PTS + p) * MM + m) * 2 + c2] = f2bf(tanhf(s));
}

// ---------------- channel-attention pooling + gate + weight folding --------
__global__ __launch_bounds__(256)
void pool1_kernel(const u16* __restrict__ xc, float* __restrict__ pmax,
                  float* __restrict__ psum)
{
    const int blk = blockIdx.x;
    const int bb = blk >> 5, ch = blk & 31;
    const size_t base = ((size_t)bb * MM + ch * 512) * CC;
    const int tid = threadIdx.x;
    float mx = -1e30f, s = 0.f;
    for (int p = 0; p < 512; ++p) {
        float v = bf2f(xc[base + (size_t)p * CC + tid]);
        mx = fmaxf(mx, v); s += v;
    }
    pmax[blk * 256 + tid] = mx;
    psum[blk * 256 + tid] = s;
}

__global__ __launch_bounds__(256)
void pool2_gate_kernel(const float* __restrict__ pmax, const float* __restrict__ psum,
                       const float* __restrict__ ca_w, float* __restrict__ gate)
{
    __shared__ float sv[256];
    const int bb = blockIdx.x, tid = threadIdx.x;
    float mx = -1e30f, s = 0.f;
    for (int ch = 0; ch < 32; ++ch) {
        mx = fmaxf(mx, pmax[(bb * 32 + ch) * 256 + tid]);
        s += psum[(bb * 32 + ch) * 256 + tid];
    }
    sv[tid] = mx + s * (1.0f / 16384.0f);   // mx + av
    __syncthreads();
    float acc = 0.f;
    for (int ci = 0; ci < 256; ++ci) acc += ca_w[tid * 256 + ci] * sv[ci];
    gate[bb * 256 + tid] = 1.0f / (1.0f + __expf(-acc));
}

// fold (1+gate[b,c]) into wkh/wvh columns, per batch -> bf16
__global__ __launch_bounds__(256)
void scalekv_kernel(const float* __restrict__ wkh, const float* __restrict__ wvh,
                    const float* __restrict__ gate, u16* __restrict__ wkhs,
                    u16* __restrict__ wvhs)
{
    const int n1 = 512 * 256;                   // per-batch weight count
    for (int i = blockIdx.x * 256 + threadIdx.x; i < 4 * n1;
         i += gridDim.x * 256) {
        int which = i / (2 * n1);               // 0: kh, 1: vh
        int r = i % (2 * n1);
        int b = r / n1, j = r % n1;
        float gsc = 1.0f + gate[b * 256 + (j & 255)];
        if (which == 0) wkhs[b * n1 + j] = f2bf(wkh[j] * gsc);
        else            wvhs[b * n1 + j] = f2bf(wvh[j] * gsc);
    }
}

// ---------------- zero the pad border of xckv (777 border pixels / batch) ---
__global__ __launch_bounds__(256)
void padzero_kernel(u16* __restrict__ xckv)
{
    const int total = 2 * 777 * 256;            // u32 writes
    for (int i = blockIdx.x * 256 + threadIdx.x; i < total;
         i += gridDim.x * 256) {
        int b = i / (777 * 256);
        int r = i % (777 * 256);
        int pix = r >> 8, w = r & 255;
        int py, px;
        if (pix < 393) {                        // rows 0, 129, 130 (full width)
            int rr = pix / PD;
            py = (rr == 0) ? 0 : (128 + rr);    // 0, 129, 130
            px = pix - rr * PD;
        } else {                                // cols 0, 129, 130 for rows 1..128
            int r2 = pix - 393;
            py = 1 + r2 / 3;
            int cc = r2 % 3;
            px = (cc == 0) ? 0 : (128 + cc);
        }
        *(unsigned*)&xckv[(((size_t)b * PDPIX + py * PD + px) << 9) + w * 2] = 0u;
    }
}

// ---------------- per-head projection maps, interleaved k|v, padded layout --
// xckv[b][y+1][x+1][c*2] = k-proj, +1 = v-proj.
__global__ __launch_bounds__(256)
void projkv_kernel(const u16* __restrict__ xc, const float* __restrict__ wk,
                   const float* __restrict__ wv, u16* __restrict__ xckv)
{
    __shared__ float la[256];
    const int tid = threadIdx.x;
    const int g = tid >> 5;
    float wkr[32], wvr[32];
    #pragma unroll
    for (int dd = 0; dd < 32; ++dd) {
        wkr[dd] = wk[tid * 32 + dd];   // wk[(nh*32+d)*32+e]
        wvr[dd] = wv[tid * 32 + dd];
    }
    const int m0 = blockIdx.x * 32;
    for (int i = 0; i < 32; ++i) {
        const size_t bm = m0 + i;
        la[tid] = bf2f(xc[bm * CC + tid]);
        __syncthreads();
        float ok = 0.f, ov = 0.f;
        #pragma unroll
        for (int dd = 0; dd < 32; ++dd) {
            ok += wkr[dd] * la[g * 32 + dd];
            ov += wvr[dd] * la[g * 32 + dd];
        }
        unsigned pack = (unsigned)f2bf(ok) | ((unsigned)f2bf(ov) << 16);
        const int b = (int)(bm >> 14), m = (int)(bm & 16383);
        const int y = m >> 7, x = m & 127;
        *(unsigned*)&xckv[(((size_t)b * PDPIX + (y + 1) * PD + (x + 1)) << 9) + tid * 2] = pack;
        __syncthreads();
    }
}

// ---------------- fused deformable sampling + attention (padded, no guards) -
__global__ __launch_bounds__(256)
void attn_kernel(const u16* __restrict__ qp, const u16* __restrict__ xckv,
                 const u16* __restrict__ kh, const u16* __restrict__ vh,
                 const u16* __restrict__ pos, u16* __restrict__ attno)
{
    const int tid = threadIdx.x;
    const int g = tid >> 5, d = tid & 31;
    const int bh = blockIdx.y;
    const int b = bh >> 3, nh = bh & 7;
    const int co = nh * 32 + d;
    const size_t hb = (size_t)b * MM;
    const u16* xb = xckv + (((size_t)b * PDPIX) << 9) + co * 2;
    #pragma unroll
    for (int i = 0; i < 4; ++i) {
        const int m = blockIdx.x * 32 + i * 8 + g;
        const size_t bm = hb + m;
        const float qd = bf2f(qp[bm * CC + co]);   // pre-scaled by SCALEF
        const int yy = m >> 7, xx = m & 127;
        float kk[6], vv[6];
        #pragma unroll
        for (int p = 0; p < 4; ++p) {
            unsigned pxy = *(const unsigned*)&pos[((((size_t)b * NHH + nh) * PTS + p) * MM + m) * 2];
            float gy = (float)yy + 0.5f + bf2f((u16)pxy);
            float gx = (float)xx + 0.5f + bf2f((u16)(pxy >> 16));
            float fy0 = floorf(gy), fx0 = floorf(gx);
            int iy0 = (int)fy0, ix0 = (int)fx0;
            float fx = gx - fx0, fy = gy - fy0;
            float w00 = (1.f - fx) * (1.f - fy), w10 = fx * (1.f - fy);
            float w01 = (1.f - fx) * fy, w11 = fx * fy;
            const u16* t0 = xb + ((size_t)((iy0 + 1) * PD + ix0 + 1) << 9);
            unsigned kv00 = *(const unsigned*)t0;
            unsigned kv10 = *(const unsigned*)(t0 + 512);
            unsigned kv01 = *(const unsigned*)(t0 + PD * 512);
            unsigned kv11 = *(const unsigned*)(t0 + PD * 512 + 512);
            kk[p] = w00 * bf2f((u16)kv00) + w10 * bf2f((u16)kv10)
                  + w01 * bf2f((u16)kv01) + w11 * bf2f((u16)kv11);
            vv[p] = w00 * bf2f((u16)(kv00 >> 16)) + w10 * bf2f((u16)(kv10 >> 16))
                  + w01 * bf2f((u16)(kv01 >> 16)) + w11 * bf2f((u16)(kv11 >> 16));
        }
        #pragma unroll
        for (int p = 0; p < 2; ++p) {
            kk[4 + p] = bf2f(kh[bm * 512 + nh * 64 + p * 32 + d]);
            vv[4 + p] = bf2f(vh[bm * 512 + nh * 64 + p * 32 + d]);
        }
        float s[6];
        #pragma unroll
        for (int p = 0; p < 6; ++p) s[p] = rsum32(qd * kk[p]);
        float mx = s[0];
        #pragma unroll
        for (int p = 1; p < 6; ++p) mx = fmaxf(mx, s[p]);
        float es[6], ssum = 0.f;
        #pragma unroll
        for (int p = 0; p < 6; ++p) { es[p] = __expf(s[p] - mx); ssum += es[p]; }
        const float inv = 1.0f / ssum;
        float od = 0.f;
        #pragma unroll
        for (int p = 0; p < 6; ++p) od += es[p] * inv * vv[p];
        attno[bm * CC + co] = f2bf(od);
    }
}

// ---------------- w_out grouped conv + bias + residual1(x, NCHW) ------------
__global__ __launch_bounds__(256)
void r1_kernel(const u16* __restrict__ attno, const float* __restrict__ w_out,
               const float* __restrict__ b_out, const float* __restrict__ x_in,
               u16* __restrict__ r1)
{
    __shared__ float la[256];
    const int tid = threadIdx.x;
    const int g = tid >> 5;
    float wr[32];
    #pragma unroll
    for (int dd = 0; dd < 32; ++dd) wr[dd] = w_out[tid * 32 + dd]; // (g*32+oc)*32+d
    const float bo = b_out[tid];
    const int m0 = blockIdx.x * 32;
    for (int i = 0; i < 32; ++i) {
        const size_t bm = m0 + i;
        la[tid] = bf2f(attno[bm * CC + tid]);
        __syncthreads();
        float o = 0.f;
        #pragma unroll
        for (int dd = 0; dd < 32; ++dd) o += wr[dd] * la[g * 32 + dd];
        const int b = (int)(bm >> 14), m = (int)(bm & 16383);
        float xv = x_in[((size_t)b * CC + tid) * MM + m];
        r1[bm * CC + tid] = f2bf(xv + o + bo);
        __syncthreads();
    }
}

// ---------------- FFN first grouped conv (inline GN1) + bias + relu ---------
__global__ __launch_bounds__(256)
void ffn1_kernel(const u16* __restrict__ r1raw, const float2* __restrict__ st1,
                 const float* __restrict__ g1g, const float* __restrict__ g1b,
                 const float* __restrict__ w1, const float* __restrict__ b1,
                 u16* __restrict__ y1bf)
{
    __shared__ float la[256];
    const int tid = threadIdx.x;
    float wr0[32], wr1[32];
    #pragma unroll
    for (int dd = 0; dd < 32; ++dd) {
        wr0[dd] = w1[tid * 32 + dd];
        wr1[dd] = w1[(tid + 256) * 32 + dd];
    }
    const float bb0 = b1[tid], bb1 = b1[tid + 256];
    const int g0 = tid >> 6, g1 = 4 + (tid >> 6);
    const int m0 = blockIdx.x * 32;
    const int bb = m0 >> 14;
    const float2 st = st1[bb * 8 + (tid >> 5)];
    const float gg = g1g[tid], gb = g1b[tid];
    for (int i = 0; i < 32; ++i) {
        const size_t bm = m0 + i;
        la[tid] = (bf2f(r1raw[bm * CC + tid]) - st.x) * st.y * gg + gb;
        __syncthreads();
        float o0 = bb0, o1 = bb1;
        #pragma unroll
        for (int dd = 0; dd < 32; ++dd) {
            o0 += wr0[dd] * la[g0 * 32 + dd];
            o1 += wr1[dd] * la[g1 * 32 + dd];
        }
        y1bf[bm * 512 + tid] = f2bf(fmaxf(o0, 0.f));
        y1bf[bm * 512 + tid + 256] = f2bf(fmaxf(o1, 0.f));
        __syncthreads();
    }
}

// ---------------- final: GN2( y2 + GN1(r1) ) + transpose to NCHW ------------
__global__ __launch_bounds__(256)
void final_kernel(const float* __restrict__ y2, const u16* __restrict__ r1raw,
                  const float2* __restrict__ st1, const float* __restrict__ g1g,
                  const float* __restrict__ g1b, const float2* __restrict__ stats,
                  const float* __restrict__ gg, const float* __restrict__ gb,
                  float* __restrict__ out)
{
    __shared__ float lt[64][65];
    const int m0 = blockIdx.x * 64, c0 = blockIdx.y * 64, b = blockIdx.z;
    const int tid = threadIdx.x;
    const float2 st = stats[b];
    {
        const int cl = tid & 63, m4 = tid >> 6;
        const int c = c0 + cl;
        const float2 s1 = st1[b * 8 + (c >> 5)];
        const float g1 = g1g[c], b1 = g1b[c];
        for (int s = 0; s < 16; ++s) {
            int ml = s * 4 + m4;
            size_t idx = ((size_t)b * MM + m0 + ml) * CC + c;
            float rv = (bf2f(r1raw[idx]) - s1.x) * s1.y * g1 + b1;
            float v = y2[idx] + rv;
            lt[cl][ml] = (v - st.x) * st.y * gg[c] + gb[c];
        }
    }
    __syncthreads();
    {
        const int mlw = tid & 63, c4 = tid >> 6;
        for (int s = 0; s < 16; ++s) {
            int clw = s * 4 + c4;
            out[((size_t)b * CC + c0 + clw) * MM + m0 + mlw] = lt[clw][mlw];
        }
    }
}

// diagnostic: written iff workspace is too small (absmax ~1000 signals it)
__global__ void sentinel_kernel(float* out) { out[threadIdx.x] = 1000.0f; }

// ============================ host side ============================
extern "C" void kernel_launch(void* const* d_in, const int* in_sizes, int n_in,
                              void* d_out, int out_size, void* d_ws, size_t ws_size,
                              hipStream_t stream)
{
    const float* q_in   = (const float*)d_in[0];
    const float* x_in   = (const float*)d_in[1];
    const float* off_w1 = (const float*)d_in[2];
    const float* off_b1 = (const float*)d_in[3];
    const float* off_gn_g = (const float*)d_in[4];
    const float* off_gn_b = (const float*)d_in[5];
    const float* off_w2 = (const float*)d_in[6];
    const float* wq     = (const float*)d_in[7];
    const float* wk     = (const float*)d_in[8];
    const float* wv     = (const float*)d_in[9];
    const float* wx     = (const float*)d_in[10];
    const float* w_out  = (const float*)d_in[11];
    const float* b_out  = (const float*)d_in[12];
    const float* wkh    = (const float*)d_in[13];
    const float* wvh    = (const float*)d_in[14];
    const float* ca_w   = (const float*)d_in[15];
    const float* gn1_g  = (const float*)d_in[16];
    const float* gn1_b  = (const float*)d_in[17];
    const float* ffn_w1 = (const float*)d_in[18];
    const float* ffn_b1 = (const float*)d_in[19];
    const float* ffn_w2 = (const float*)d_in[20];
    const float* ffn_b2 = (const float*)d_in[21];
    const float* gn2_g  = (const float*)d_in[22];
    const float* gn2_b  = (const float*)d_in[23];
    float* out = (float*)d_out;

    char* W = (char*)d_ws;
    size_t off = 0;
    auto AL = [&](size_t sz) -> char* {
        char* p = W + off;
        off += (sz + 255) & ~(size_t)255;
        return p;
    };
    u16* zp    = (u16*)AL(256);
    u16* w1t   = (u16*)AL(589824 * 2);
    u16* wqb   = (u16*)AL(65536 * 2);
    u16* wxb   = (u16*)AL(65536 * 2);
    u16* fw2b  = (u16*)AL(131072 * 2);
    u16* wkhs  = (u16*)AL(2 * 131072 * 2);     // per-batch gate-folded
    u16* wvhs  = (u16*)AL(2 * 131072 * 2);
    u16* slotA = (u16*)AL((size_t)BMTOT * CC * 2);   // qpe -> attno -> y2(lo)
    u16* slotC = (u16*)AL((size_t)BMTOT * CC * 2);   // t -> xc -> y2(hi)
    u16* slotD = (u16*)AL((size_t)BMTOT * CC * 2);   // qp
    u16* slotB = (u16*)AL((size_t)BMTOT * CC * 2);   // xpe -> xckv(lo) -> r1(raw)
    u16* slotE = (u16*)AL((size_t)BMTOT * CC * 2 + 1591296); // xckv(hi) + pad spill
    u16* slotG = (u16*)AL((size_t)BMTOT * 512 * 2);  // vh -> y1bf
    u16* pos   = (u16*)AL((size_t)BB * NHH * PTS * MM * 2 * 2);
    float* part  = (float*)AL(64 * 8 * 2 * 4);
    float* pmax  = (float*)AL(64 * 256 * 4);
    float* psum  = (float*)AL(64 * 256 * 4);
    float* gate  = (float*)AL(2 * 256 * 4);
    float2* stats_t  = (float2*)AL(2 * sizeof(float2));
    float2* stats_g1 = (float2*)AL(16 * sizeof(float2));
    float2* stats_g2 = (float2*)AL(2 * sizeof(float2));

    u16* qpe = slotA;  u16* attno = slotA;
    u16* t_b = slotC;  u16* xc  = slotC;
    u16* qp  = slotD;
    u16* xpe = slotB;
    u16* xckv = slotB;                       // spans slotB+slotE (35.1 MB padded)
    u16* r1  = slotB;                        // raw r1 after attn (xckv dead)
    u16* vh  = slotG;  u16* y1bf = slotG;
    u16* kh  = (u16*)d_out;                  // 33.5 MB, dead before final_kernel
    float* y2 = (float*)slotA;               // spans slotA+slotC (contiguous)

    if (off > ws_size) {                     // ws too small: absmax ~1000 signals it
        sentinel_kernel<<<1, 256, 0, stream>>>(out);
        return;
    }

    prep_kernel<<<3329, 256, 0, stream>>>(off_w1, wq, wx, ffn_w2,
                                          zp, w1t, wqb, wxb, fw2b);
    addpe_kernel<<<dim3(256, 4, 2), 256, 0, stream>>>(q_in, x_in, qpe, xpe);

    // conv_offset 3x3 (implicit im2col) -> t
    gemm_bt<1, 1><<<dim3(256, 2), 256, 0, stream>>>(qpe, w1t, off_b1, t_b, 2304, 256, zp);
    stats1_bf_kernel<<<64, 256, 0, stream>>>(t_b, part);
    stats2_kernel<<<1, 64, 0, stream>>>(part, stats_t, 1);
    offset_kernel<<<8192, 256, 0, stream>>>(t_b, stats_t, off_gn_g, off_gn_b, off_w2, pos);

    // qp projection (after conv GEMM so slotC reuse is safe)
    gemm_bt<0, 1><<<dim3(256, 2), 256, 0, stream>>>(qpe, wqb, nullptr, qp, 256, 256, zp);
    // x branch: conv -> xc (overwrites t, which is now dead)
    gemm_bt<0, 1><<<dim3(256, 2), 256, 0, stream>>>(xpe, wxb, nullptr, xc, 256, 256, zp);
    pool1_kernel<<<64, 256, 0, stream>>>(xc, pmax, psum);
    pool2_gate_kernel<<<2, 256, 0, stream>>>(pmax, psum, ca_w, gate);
    scalekv_kernel<<<2048, 256, 0, stream>>>(wkh, wvh, gate, wkhs, wvhs);
    // padded k/v maps (xpe dead after xc gemm; xckv overwrites slotB+slotE)
    padzero_kernel<<<1555, 256, 0, stream>>>(xckv);
    projkv_kernel<<<1024, 256, 0, stream>>>(xc, wk, wv, xckv);

    // kh/vh GEMMs with gate-folded per-batch weights
    for (int b = 0; b < 2; ++b) {
        gemm_bt<0, 1><<<dim3(128, 4), 256, 0, stream>>>(
            xc + (size_t)b * MM * CC, wkhs + (size_t)b * 131072, nullptr,
            kh + (size_t)b * MM * 512, 256, 512, zp);
        gemm_bt<0, 1><<<dim3(128, 4), 256, 0, stream>>>(
            xc + (size_t)b * MM * CC, wvhs + (size_t)b * 131072, nullptr,
            vh + (size_t)b * MM * 512, 256, 512, zp);
    }

    // fused deformable attention (padded map, no bounds checks)
    attn_kernel<<<dim3(512, 16), 256, 0, stream>>>(qp, xckv, kh, vh, pos, attno);

    // out proj + residual -> raw r1; GN1 stats; GN1 applied inline downstream
    r1_kernel<<<1024, 256, 0, stream>>>(attno, w_out, b_out, x_in, r1);
    stats1_bf_kernel<<<64, 256, 0, stream>>>(r1, part);
    stats2_kernel<<<1, 64, 0, stream>>>(part, stats_g1, 8);

    // FFN (GN1 inline)
    ffn1_kernel<<<1024, 256, 0, stream>>>(r1, stats_g1, gn1_g, gn1_b,
                                          ffn_w1, ffn_b1, y1bf);
    gemm_bt<0, 0><<<dim3(256, 2), 256, 0, stream>>>(y1bf, fw2b, ffn_b2, y2, 512, 256, zp);

    // GN2 stats over y2 + GN1(r1); final normalize + transpose
    stats1_mix_kernel<<<64, 256, 0, stream>>>(y2, r1, stats_g1, gn1_g, gn1_b, part);
    stats2_kernel<<<1, 64, 0, stream>>>(part, stats_g2, 1);
    final_kernel<<<dim3(256, 4, 2), 256, 0, stream>>>(y2, r1, stats_g1, gn1_g, gn1_b,
                                                      stats_g2, gn2_g, gn2_b, out);
}

// Round 11
// 596.426 us; speedup vs baseline: 1.6133x; 1.2147x over previous
//
#include <hip/hip_runtime.h>
#include <hip/hip_bf16.h>
#include <math.h>

typedef unsigned short u16;
typedef __attribute__((ext_vector_type(8))) unsigned short u16v8;
typedef __attribute__((ext_vector_type(8))) __bf16 bf16v8;
typedef __attribute__((ext_vector_type(4))) float f32v4;

#define BB 2
#define MM 16384           // H*W
#define CC 256
#define NHH 8
#define PTS 4
#define BMTOT 32768        // B*M
#define SCALEF 0.17677669529663687f
#define PECOEF 0.03597789207803197f   // ln(10000)/256
#define PD 131             // padded map dim (1 low, 2 high zero border)
#define PDPIX (PD*PD)      // 17161

__device__ __forceinline__ u16 f2bf(float f) {
    union { float f; unsigned u; } v; v.f = f;
    unsigned u = v.u;
    return (u16)((u + 0x7fffu + ((u >> 16) & 1u)) >> 16);
}
__device__ __forceinline__ float bf2f(u16 u) {
    union { unsigned u; float f; } v; v.u = ((unsigned)u) << 16; return v.f;
}
__device__ __forceinline__ float rsum32(float v) {
    #pragma unroll
    for (int m = 16; m; m >>= 1) v += __shfl_xor(v, m, 32);
    return v;
}
__device__ __forceinline__ void gload16(const void* g, void* l) {
    __builtin_amdgcn_global_load_lds(
        (const __attribute__((address_space(1))) void*)g,
        (__attribute__((address_space(3))) void*)l, 16, 0, 0);
}

// ---------------- prep: zero page + weight bf16 conversions ----------------
__global__ __launch_bounds__(256)
void prep_kernel(const float* __restrict__ off_w1, const float* __restrict__ wq,
                 const float* __restrict__ wx, const float* __restrict__ fw2,
                 u16* zp, u16* w1t, u16* wqb, u16* wxb, u16* fw2b)
{
    const size_t n_zp = 128, n_w1 = 589824, n_q = 65536, n_f2 = 131072;
    const size_t total = n_zp + n_w1 + 2 * n_q + n_f2;
    for (size_t i = (size_t)blockIdx.x * 256 + threadIdx.x; i < total;
         i += (size_t)gridDim.x * 256) {
        size_t j = i;
        if (j < n_zp) { zp[j] = 0; continue; }
        j -= n_zp;
        if (j < n_w1) {  // w1t[oc][tap*256+ic] = off_w1[oc][ic][tap]
            size_t oc = j / 2304, r = j % 2304, tap = r >> 8, ic = r & 255;
            w1t[j] = f2bf(off_w1[(oc * 256 + ic) * 9 + tap]);
            continue;
        }
        j -= n_w1;
        if (j < n_q) { wqb[j] = f2bf(wq[j] * SCALEF); continue; }
        j -= n_q;
        if (j < n_q) { wxb[j] = f2bf(wx[j]); continue; }
        j -= n_q;
        fw2b[j] = f2bf(fw2[j]);
    }
}

// ---------------- add positional encoding, transpose to pixel-major bf16 ----
__global__ __launch_bounds__(256)
void addpe_kernel(const float* __restrict__ q, const float* __restrict__ x,
                  u16* __restrict__ qpe, u16* __restrict__ xpe)
{
    __shared__ float lq[64][65], lx[64][65];
    const int m0 = blockIdx.x * 64, c0 = blockIdx.y * 64, b = blockIdx.z;
    const int tid = threadIdx.x;
    {
        const int ml = tid & 63, c4 = tid >> 6;
        for (int s = 0; s < 16; ++s) {
            int cl = s * 4 + c4;
            int c = c0 + cl, m = m0 + ml;
            float dv = __expf(-(float)(c & ~1) * PECOEF);
            float a = (float)m * dv;
            float pe = (c & 1) ? __cosf(a) : __sinf(a);
            size_t gi = ((size_t)b * CC + c) * MM + m;
            lq[cl][ml] = q[gi] + pe;
            lx[cl][ml] = x[gi] + pe;
        }
    }
    __syncthreads();
    {
        const int cl = tid & 63, m4 = tid >> 6;
        for (int s = 0; s < 16; ++s) {
            int ml = s * 4 + m4;
            size_t oi = ((size_t)b * MM + m0 + ml) * CC + c0 + cl;
            qpe[oi] = f2bf(lq[cl][ml]);
            xpe[oi] = f2bf(lx[cl][ml]);
        }
    }
}

// ---------------- bf16 MFMA GEMM (global_load_lds staging) ------------------
template<int AMODE, int OUTBF>
__global__ __launch_bounds__(256, 2)
void gemm_bt(const u16* __restrict__ A, const u16* __restrict__ Bw,
             const float* __restrict__ bias, void* __restrict__ Cout,
             int K, int N, const u16* __restrict__ zp)
{
    __shared__ u16 lA[128 * 32];
    __shared__ u16 lB[128 * 32];
    const int tid = threadIdx.x;
    const int w = tid >> 6, l = tid & 63;
    const int gm = blockIdx.x, gn = blockIdx.y;
    const int wm = w >> 1, wn = w & 1;
    const int rowIn = l >> 2;            // 0..15 within 16-row segment
    const int kc = (l & 3) << 3;         // k offset 0,8,16,24
    f32v4 acc[4][4] = {};

    for (int k0 = 0; k0 < K; k0 += 32) {
        #pragma unroll
        for (int r = 0; r < 2; ++r) {
            const int seg = r * 4 + w;          // 0..7
            const int row = seg * 16 + rowIn;   // 0..127
            const u16* gpA;
            if (AMODE == 0) {
                gpA = A + (size_t)(gm * 128 + row) * K + (k0 + kc);
            } else {
                int grow = gm * 128 + row;
                int bimg = grow >> 14, m = grow & 16383;
                int y = m >> 7, xx2 = m & 127;
                int kk2 = k0 + kc;
                int tap = kk2 >> 8, ic = kk2 & 255;
                int t3 = tap / 3;
                int py = y + t3 - 1, px = xx2 + (tap - t3 * 3) - 1;
                bool ok = ((unsigned)py < 128u) && ((unsigned)px < 128u);
                gpA = ok ? (A + (((size_t)((bimg << 14) + (py << 7) + px)) << 8) + ic) : zp;
            }
            gload16(gpA, lA + seg * 512);
            const u16* gpB = Bw + (size_t)(gn * 128 + row) * K + (k0 + kc);
            gload16(gpB, lB + seg * 512);
        }
        __syncthreads();
        bf16v8 af[4], bf[4];
        #pragma unroll
        for (int i = 0; i < 4; ++i) {
            af[i] = *(const bf16v8*)&lA[((wm << 6) + (i << 4) + (l & 15)) * 32 + ((l >> 4) << 3)];
            bf[i] = *(const bf16v8*)&lB[((wn << 6) + (i << 4) + (l & 15)) * 32 + ((l >> 4) << 3)];
        }
        #pragma unroll
        for (int i = 0; i < 4; ++i)
            #pragma unroll
            for (int j = 0; j < 4; ++j)
                acc[i][j] = __builtin_amdgcn_mfma_f32_16x16x32_bf16(af[i], bf[j], acc[i][j], 0, 0, 0);
        __syncthreads();
    }

    const int l15 = l & 15, l4 = l >> 4;
    #pragma unroll
    for (int i = 0; i < 4; ++i) {
        int row = gm * 128 + (wm << 6) + (i << 4) + (l4 << 2);
        #pragma unroll
        for (int j = 0; j < 4; ++j) {
            int col = gn * 128 + (wn << 6) + (j << 4) + l15;
            float bv = bias ? bias[col] : 0.0f;
            #pragma unroll
            for (int r = 0; r < 4; ++r) {
                float val = acc[i][j][r] + bv;
                if (OUTBF) ((u16*)Cout)[(size_t)(row + r) * N + col] = f2bf(val);
                else       ((float*)Cout)[(size_t)(row + r) * N + col] = val;
            }
        }
    }
}

// ---------------- GN stats stage 1, 64-pixel chunks (grid 512) --------------
__global__ __launch_bounds__(256)
void stats1_bf_kernel(const u16* __restrict__ a, float* __restrict__ part)
{
    __shared__ float ls[256], lss[256];
    const int blk = blockIdx.x;
    const size_t base = (size_t)blk * 64 * CC;
    const int tid = threadIdx.x;
    float s = 0.f, ss = 0.f;
    for (int p = 0; p < 64; ++p) {
        float v = bf2f(a[base + (size_t)p * CC + tid]);
        s += v; ss += v * v;
    }
    ls[tid] = s; lss[tid] = ss;
    __syncthreads();
    if (tid < 8) {
        float S = 0.f, SS = 0.f;
        for (int j = 0; j < 32; ++j) { S += ls[tid * 32 + j]; SS += lss[tid * 32 + j]; }
        part[(blk * 8 + tid) * 2] = S;
        part[(blk * 8 + tid) * 2 + 1] = SS;
    }
}

// stage 1, fp32 y2 + inline-GN1(raw r1), 64-pixel chunks (grid 512)
__global__ __launch_bounds__(256)
void stats1_mix_kernel(const float* __restrict__ a, const u16* __restrict__ r1raw,
                       const float2* __restrict__ st1, const float* __restrict__ g1g,
                       const float* __restrict__ g1b, float* __restrict__ part)
{
    __shared__ float ls[256], lss[256];
    const int blk = blockIdx.x;
    const int bb = blk >> 8;
    const size_t base = (size_t)blk * 64 * CC;
    const int tid = threadIdx.x;
    const float2 st = st1[bb * 8 + (tid >> 5)];
    const float gg = g1g[tid] * st.y;
    const float gb = g1b[tid] - st.x * st.y * g1g[tid];
    float s = 0.f, ss = 0.f;
    for (int p = 0; p < 64; ++p) {
        float v = a[base + (size_t)p * CC + tid]
                + bf2f(r1raw[base + (size_t)p * CC + tid]) * gg + gb;
        s += v; ss += v * v;
    }
    ls[tid] = s; lss[tid] = ss;
    __syncthreads();
    if (tid < 8) {
        float S = 0.f, SS = 0.f;
        for (int j = 0; j < 32; ++j) { S += ls[tid * 32 + j]; SS += lss[tid * 32 + j]; }
        part[(blk * 8 + tid) * 2] = S;
        part[(blk * 8 + tid) * 2 + 1] = SS;
    }
}

// stage 2: reduce 256 chunks/batch with parallel threads (launch <<<1,256>>>)
__global__ __launch_bounds__(256)
void stats2_kernel(const float* __restrict__ part, float2* __restrict__ stats, int NG)
{
    __shared__ float ls[256], lss[256];
    const int P = 2 * NG, TP = 256 / P;
    const int t = threadIdx.x;
    const int pr = t / TP, sub = t % TP;
    const int bb = pr / NG, g = pr % NG;
    const int j0 = (NG == 8) ? g : 0, jn = (NG == 8) ? 1 : 8;
    float S = 0.f, SS = 0.f;
    for (int q = sub; q < 256; q += TP)
        for (int j = 0; j < jn; ++j) {
            int idx = ((bb * 256 + q) * 8 + j0 + j) * 2;
            S += part[idx]; SS += part[idx + 1];
        }
    ls[t] = S; lss[t] = SS;
    __syncthreads();
    if (sub == 0) {
        float S2 = 0.f, SS2 = 0.f;
        for (int k = 0; k < TP; ++k) { S2 += ls[pr * TP + k]; SS2 += lss[pr * TP + k]; }
        const float cnt = (256.0f / NG) * 16384.0f;
        float mu = S2 / cnt;
        float var = SS2 / cnt - mu * mu;
        stats[bb * NG + g] = make_float2(mu, rsqrtf(var + 1e-5f));
    }
}

// ---------------- conv_offset tail: GN(1)+ReLU -> grouped 1x1 -> tanh -------
__global__ __launch_bounds__(256)
void offset_kernel(const u16* __restrict__ t, const float2* __restrict__ stats_t,
                   const float* __restrict__ gng, const float* __restrict__ gnb,
                   const float* __restrict__ w2, u16* __restrict__ pos)
{
    __shared__ float lt[4 * 256];
    const int tid = threadIdx.x;
    const int bm0 = blockIdx.x * 4;
    const int b = bm0 >> 14;
    const float2 st = stats_t[b];
    for (int idx = tid; idx < 1024; idx += 256) {
        int pix = idx >> 8, c = idx & 255;
        float v = bf2f(t[(size_t)(bm0 + pix) * CC + c]);
        v = (v - st.x) * st.y * gng[c] + gnb[c];
        lt[idx] = fmaxf(v, 0.0f);
    }
    __syncthreads();
    const int pix = tid >> 6, go = tid & 63;
    const int g = go >> 3, o = go & 7;
    float s = 0.f;
    #pragma unroll
    for (int ci = 0; ci < 32; ++ci) {
        int ce = (ci + g * 4) & 31;                 // bank rotation
        s += w2[(g * 8 + o) * 32 + ce] * lt[pix * 256 + g * 32 + ce];
    }
    const int m = (bm0 + pix) & 16383;
    const int p = o >> 1, c2 = o & 1;
    pos[((((size_t)b * NHH + g) * PTS + p) * MM + m) * 2 + c2] = f2bf(tanhf(s));
}

// ---------------- channel-attention pooling (grid 512) ----------------
__global__ __launch_bounds__(256)
void pool1_kernel(const u16* __restrict__ xc, float* __restrict__ pmax,
                  float* __restrict__ psum)
{
    const int blk = blockIdx.x;
    const size_t base = (size_t)blk * 64 * CC;
    const int tid = threadIdx.x;
    float mx = -1e30f, s = 0.f;
    for (int p = 0; p < 64; ++p) {
        float v = bf2f(xc[base + (size_t)p * CC + tid]);
        mx = fmaxf(mx, v); s += v;
    }
    pmax[blk * 256 + tid] = mx;
    psum[blk * 256 + tid] = s;
}

__global__ __launch_bounds__(256)
void pool2_gate_kernel(const float* __restrict__ pmax, const float* __restrict__ psum,
                       const float* __restrict__ ca_w, float* __restrict__ gate)
{
    __shared__ float sv[256];
    const int bb = blockIdx.x, tid = threadIdx.x;
    float mx = -1e30f, s = 0.f;
    for (int q = 0; q < 256; ++q) {
        mx = fmaxf(mx, pmax[(bb * 256 + q) * 256 + tid]);
        s += psum[(bb * 256 + q) * 256 + tid];
    }
    sv[tid] = mx + s * (1.0f / 16384.0f);   // mx + av
    __syncthreads();
    float acc = 0.f;
    for (int ci = 0; ci < 256; ++ci) acc += ca_w[tid * 256 + ci] * sv[ci];
    gate[bb * 256 + tid] = 1.0f / (1.0f + __expf(-acc));
}

// fold (1+gate[b,c]) into wkh/wvh columns, per batch -> bf16
__global__ __launch_bounds__(256)
void scalekv_kernel(const float* __restrict__ wkh, const float* __restrict__ wvh,
                    const float* __restrict__ gate, u16* __restrict__ wkhs,
                    u16* __restrict__ wvhs)
{
    const int n1 = 512 * 256;                   // per-batch weight count
    for (int i = blockIdx.x * 256 + threadIdx.x; i < 4 * n1;
         i += gridDim.x * 256) {
        int which = i / (2 * n1);               // 0: kh, 1: vh
        int r = i % (2 * n1);
        int b = r / n1, j = r % n1;
        float gsc = 1.0f + gate[b * 256 + (j & 255)];
        if (which == 0) wkhs[b * n1 + j] = f2bf(wkh[j] * gsc);
        else            wvhs[b * n1 + j] = f2bf(wvh[j] * gsc);
    }
}

// ---------------- zero the pad border of xckv (777 border pixels / batch) ---
__global__ __launch_bounds__(256)
void padzero_kernel(u16* __restrict__ xckv)
{
    const int total = 2 * 777 * 256;            // u32 writes
    for (int i = blockIdx.x * 256 + threadIdx.x; i < total;
         i += gridDim.x * 256) {
        int b = i / (777 * 256);
        int r = i % (777 * 256);
        int pix = r >> 8, w = r & 255;
        int py, px;
        if (pix < 393) {                        // rows 0, 129, 130 (full width)
            int rr = pix / PD;
            py = (rr == 0) ? 0 : (128 + rr);    // 0, 129, 130
            px = pix - rr * PD;
        } else {                                // cols 0, 129, 130 for rows 1..128
            int r2 = pix - 393;
            py = 1 + r2 / 3;
            int cc = r2 % 3;
            px = (cc == 0) ? 0 : (128 + cc);
        }
        *(unsigned*)&xckv[(((size_t)b * PDPIX + py * PD + px) << 9) + w * 2] = 0u;
    }
}

// ---------------- per-head projection maps, interleaved k|v, padded layout --
__global__ __launch_bounds__(256)
void projkv_kernel(const u16* __restrict__ xc, const float* __restrict__ wk,
                   const float* __restrict__ wv, u16* __restrict__ xckv)
{
    __shared__ float la[256];
    const int tid = threadIdx.x;
    const int g = tid >> 5;
    float wkr[32], wvr[32];
    #pragma unroll
    for (int dd = 0; dd < 32; ++dd) {
        wkr[dd] = wk[tid * 32 + dd];   // wk[(nh*32+d)*32+e]
        wvr[dd] = wv[tid * 32 + dd];
    }
    const int m0 = blockIdx.x * 32;
    for (int i = 0; i < 32; ++i) {
        const size_t bm = m0 + i;
        la[tid] = bf2f(xc[bm * CC + tid]);
        __syncthreads();
        float ok = 0.f, ov = 0.f;
        #pragma unroll
        for (int dd = 0; dd < 32; ++dd) {
            ok += wkr[dd] * la[g * 32 + dd];
            ov += wvr[dd] * la[g * 32 + dd];
        }
        unsigned pack = (unsigned)f2bf(ok) | ((unsigned)f2bf(ov) << 16);
        const int b = (int)(bm >> 14), m = (int)(bm & 16383);
        const int y = m >> 7, x = m & 127;
        *(unsigned*)&xckv[(((size_t)b * PDPIX + (y + 1) * PD + (x + 1)) << 9) + tid * 2] = pack;
        __syncthreads();
    }
}

// ---------------- fused deformable sampling + attention (padded, no guards) -
__global__ __launch_bounds__(256)
void attn_kernel(const u16* __restrict__ qp, const u16* __restrict__ xckv,
                 const u16* __restrict__ kh, const u16* __restrict__ vh,
                 const u16* __restrict__ pos, u16* __restrict__ attno)
{
    const int tid = threadIdx.x;
    const int g = tid >> 5, d = tid & 31;
    const int bh = blockIdx.y;
    const int b = bh >> 3, nh = bh & 7;
    const int co = nh * 32 + d;
    const size_t hb = (size_t)b * MM;
    const u16* xb = xckv + (((size_t)b * PDPIX) << 9) + co * 2;
    #pragma unroll
    for (int i = 0; i < 4; ++i) {
        const int m = blockIdx.x * 32 + i * 8 + g;
        const size_t bm = hb + m;
        const float qd = bf2f(qp[bm * CC + co]);   // pre-scaled by SCALEF
        const int yy = m >> 7, xx = m & 127;
        float kk[6], vv[6];
        #pragma unroll
        for (int p = 0; p < 4; ++p) {
            unsigned pxy = *(const unsigned*)&pos[((((size_t)b * NHH + nh) * PTS + p) * MM + m) * 2];
            float gy = (float)yy + 0.5f + bf2f((u16)pxy);
            float gx = (float)xx + 0.5f + bf2f((u16)(pxy >> 16));
            float fy0 = floorf(gy), fx0 = floorf(gx);
            int iy0 = (int)fy0, ix0 = (int)fx0;
            float fx = gx - fx0, fy = gy - fy0;
            float w00 = (1.f - fx) * (1.f - fy), w10 = fx * (1.f - fy);
            float w01 = (1.f - fx) * fy, w11 = fx * fy;
            const u16* t0 = xb + ((size_t)((iy0 + 1) * PD + ix0 + 1) << 9);
            unsigned kv00 = *(const unsigned*)t0;
            unsigned kv10 = *(const unsigned*)(t0 + 512);
            unsigned kv01 = *(const unsigned*)(t0 + PD * 512);
            unsigned kv11 = *(const unsigned*)(t0 + PD * 512 + 512);
            kk[p] = w00 * bf2f((u16)kv00) + w10 * bf2f((u16)kv10)
                  + w01 * bf2f((u16)kv01) + w11 * bf2f((u16)kv11);
            vv[p] = w00 * bf2f((u16)(kv00 >> 16)) + w10 * bf2f((u16)(kv10 >> 16))
                  + w01 * bf2f((u16)(kv01 >> 16)) + w11 * bf2f((u16)(kv11 >> 16));
        }
        #pragma unroll
        for (int p = 0; p < 2; ++p) {
            kk[4 + p] = bf2f(kh[bm * 512 + nh * 64 + p * 32 + d]);
            vv[4 + p] = bf2f(vh[bm * 512 + nh * 64 + p * 32 + d]);
        }
        float s[6];
        #pragma unroll
        for (int p = 0; p < 6; ++p) s[p] = rsum32(qd * kk[p]);
        float mx = s[0];
        #pragma unroll
        for (int p = 1; p < 6; ++p) mx = fmaxf(mx, s[p]);
        float es[6], ssum = 0.f;
        #pragma unroll
        for (int p = 0; p < 6; ++p) { es[p] = __expf(s[p] - mx); ssum += es[p]; }
        const float inv = 1.0f / ssum;
        float od = 0.f;
        #pragma unroll
        for (int p = 0; p < 6; ++p) od += es[p] * inv * vv[p];
        attno[bm * CC + co] = f2bf(od);
    }
}

// ---------------- r1 v2: tiled, barrier-free (32 pixels/block, grid 1024) ---
__global__ __launch_bounds__(256)
void r1_kernel(const u16* __restrict__ attno, const float* __restrict__ w_out,
               const float* __restrict__ b_out, const float* __restrict__ x_in,
               u16* __restrict__ r1)
{
    __shared__ u16 lx[256][36];    // x (bf16), [c][pix], padded stride
    __shared__ u16 lat[32][256];   // attno, [pix][c]
    const int tid = threadIdx.x;
    const int m0 = blockIdx.x * 32;
    const int b = m0 >> 14;
    const int mloc = m0 & 16383;
    // x tile: coalesced float4 along m
    {
        const int ml4 = (tid & 7) * 4, c32 = tid >> 3;
        for (int s = 0; s < 8; ++s) {
            int cl = s * 32 + c32;
            float4 v = *(const float4*)&x_in[((size_t)b * CC + cl) * MM + mloc + ml4];
            ushort4 sv = { f2bf(v.x), f2bf(v.y), f2bf(v.z), f2bf(v.w) };
            *(ushort4*)&lx[cl][ml4] = sv;
        }
    }
    // attno tile: uint4 copies (layout matches linear)
    {
        const uint4* src4 = (const uint4*)(attno + (size_t)m0 * CC);
        uint4* dst4 = (uint4*)&lat[0][0];
        #pragma unroll
        for (int s = 0; s < 4; ++s) dst4[s * 256 + tid] = src4[s * 256 + tid];
    }
    __syncthreads();
    const int g = tid >> 5;
    float wr[32];
    #pragma unroll
    for (int dd = 0; dd < 32; ++dd) wr[dd] = w_out[tid * 32 + dd];
    const float bo = b_out[tid];
    for (int i = 0; i < 32; ++i) {
        float o = bo + bf2f(lx[tid][i]);
        #pragma unroll
        for (int dd = 0; dd < 32; ++dd) o += wr[dd] * bf2f(lat[i][g * 32 + dd]);
        r1[(size_t)(m0 + i) * CC + tid] = f2bf(o);
    }
}

// ---------------- ffn1 v2: tiled, GN1 affine at load, barrier-free ----------
__global__ __launch_bounds__(256)
void ffn1_kernel(const u16* __restrict__ r1raw, const float2* __restrict__ st1,
                 const float* __restrict__ g1g, const float* __restrict__ g1b,
                 const float* __restrict__ w1, const float* __restrict__ b1,
                 u16* __restrict__ y1bf)
{
    __shared__ u16 ln[32][256];   // GN1-applied r1, [pix][c]
    const int tid = threadIdx.x;
    const int m0 = blockIdx.x * 32;
    const int b = m0 >> 14;
    {
        const uint4* src4 = (const uint4*)(r1raw + (size_t)m0 * CC);
        uint4* dst4 = (uint4*)&ln[0][0];
        const int cbase = (tid & 31) * 8;
        const float2 st = st1[b * 8 + (cbase >> 5)];
        float ga[8], bb2[8];
        #pragma unroll
        for (int k = 0; k < 8; ++k) {
            ga[k] = g1g[cbase + k] * st.y;
            bb2[k] = g1b[cbase + k] - st.x * st.y * g1g[cbase + k];
        }
        #pragma unroll
        for (int s = 0; s < 4; ++s) {
            uint4 v = src4[s * 256 + tid];
            unsigned wv[4] = { v.x, v.y, v.z, v.w };
            unsigned ow[4];
            #pragma unroll
            for (int q = 0; q < 4; ++q) {
                float lo = bf2f((u16)wv[q]) * ga[2 * q] + bb2[2 * q];
                float hi = bf2f((u16)(wv[q] >> 16)) * ga[2 * q + 1] + bb2[2 * q + 1];
                ow[q] = (unsigned)f2bf(lo) | ((unsigned)f2bf(hi) << 16);
            }
            uint4 o4; o4.x = ow[0]; o4.y = ow[1]; o4.z = ow[2]; o4.w = ow[3];
            dst4[s * 256 + tid] = o4;
        }
    }
    __syncthreads();
    float wr0[32], wr1[32];
    #pragma unroll
    for (int dd = 0; dd < 32; ++dd) {
        wr0[dd] = w1[tid * 32 + dd];
        wr1[dd] = w1[(tid + 256) * 32 + dd];
    }
    const float bb0 = b1[tid], bb1 = b1[tid + 256];
    const int g0 = tid >> 6, g1 = 4 + (tid >> 6);
    for (int i = 0; i < 32; ++i) {
        float o0 = bb0, o1 = bb1;
        #pragma unroll
        for (int dd = 0; dd < 32; ++dd) {
            o0 += wr0[dd] * bf2f(ln[i][g0 * 32 + dd]);
            o1 += wr1[dd] * bf2f(ln[i][g1 * 32 + dd]);
        }
        y1bf[(size_t)(m0 + i) * 512 + tid] = f2bf(fmaxf(o0, 0.f));
        y1bf[(size_t)(m0 + i) * 512 + tid + 256] = f2bf(fmaxf(o1, 0.f));
    }
}

// ---------------- final: GN2( y2 + GN1(r1) ) + transpose to NCHW ------------
__global__ __launch_bounds__(256)
void final_kernel(const float* __restrict__ y2, const u16* __restrict__ r1raw,
                  const float2* __restrict__ st1, const float* __restrict__ g1g,
                  const float* __restrict__ g1b, const float2* __restrict__ stats,
                  const float* __restrict__ gg, const float* __restrict__ gb,
                  float* __restrict__ out)
{
    __shared__ float lt[64][65];
    const int m0 = blockIdx.x * 64, c0 = blockIdx.y * 64, b = blockIdx.z;
    const int tid = threadIdx.x;
    const float2 st = stats[b];
    {
        const int cl = tid & 63, m4 = tid >> 6;
        const int c = c0 + cl;
        const float2 s1 = st1[b * 8 + (c >> 5)];
        const float g1 = g1g[c], b1 = g1b[c];
        for (int s = 0; s < 16; ++s) {
            int ml = s * 4 + m4;
            size_t idx = ((size_t)b * MM + m0 + ml) * CC + c;
            float rv = (bf2f(r1raw[idx]) - s1.x) * s1.y * g1 + b1;
            float v = y2[idx] + rv;
            lt[cl][ml] = (v - st.x) * st.y * gg[c] + gb[c];
        }
    }
    __syncthreads();
    {
        const int mlw = tid & 63, c4 = tid >> 6;
        for (int s = 0; s < 16; ++s) {
            int clw = s * 4 + c4;
            out[((size_t)b * CC + c0 + clw) * MM + m0 + mlw] = lt[clw][mlw];
        }
    }
}

// diagnostic: written iff workspace is too small (absmax ~1000 signals it)
__global__ void sentinel_kernel(float* out) { out[threadIdx.x] = 1000.0f; }

// ============================ host side ============================
extern "C" void kernel_launch(void* const* d_in, const int* in_sizes, int n_in,
                              void* d_out, int out_size, void* d_ws, size_t ws_size,
                              hipStream_t stream)
{
    const float* q_in   = (const float*)d_in[0];
    const float* x_in   = (const float*)d_in[1];
    const float* off_w1 = (const float*)d_in[2];
    const float* off_b1 = (const float*)d_in[3];
    const float* off_gn_g = (const float*)d_in[4];
    const float* off_gn_b = (const float*)d_in[5];
    const float* off_w2 = (const float*)d_in[6];
    const float* wq     = (const float*)d_in[7];
    const float* wk     = (const float*)d_in[8];
    const float* wv     = (const float*)d_in[9];
    const float* wx     = (const float*)d_in[10];
    const float* w_out  = (const float*)d_in[11];
    const float* b_out  = (const float*)d_in[12];
    const float* wkh    = (const float*)d_in[13];
    const float* wvh    = (const float*)d_in[14];
    const float* ca_w   = (const float*)d_in[15];
    const float* gn1_g  = (const float*)d_in[16];
    const float* gn1_b  = (const float*)d_in[17];
    const float* ffn_w1 = (const float*)d_in[18];
    const float* ffn_b1 = (const float*)d_in[19];
    const float* ffn_w2 = (const float*)d_in[20];
    const float* ffn_b2 = (const float*)d_in[21];
    const float* gn2_g  = (const float*)d_in[22];
    const float* gn2_b  = (const float*)d_in[23];
    float* out = (float*)d_out;

    char* W = (char*)d_ws;
    size_t off = 0;
    auto AL = [&](size_t sz) -> char* {
        char* p = W + off;
        off += (sz + 255) & ~(size_t)255;
        return p;
    };
    u16* zp    = (u16*)AL(256);
    u16* w1t   = (u16*)AL(589824 * 2);
    u16* wqb   = (u16*)AL(65536 * 2);
    u16* wxb   = (u16*)AL(65536 * 2);
    u16* fw2b  = (u16*)AL(131072 * 2);
    u16* wkhs  = (u16*)AL(2 * 131072 * 2);     // per-batch gate-folded
    u16* wvhs  = (u16*)AL(2 * 131072 * 2);
    u16* slotA = (u16*)AL((size_t)BMTOT * CC * 2);   // qpe -> attno -> y2(lo)
    u16* slotC = (u16*)AL((size_t)BMTOT * CC * 2);   // t -> xc -> y2(hi)
    u16* slotD = (u16*)AL((size_t)BMTOT * CC * 2);   // qp
    u16* slotB = (u16*)AL((size_t)BMTOT * CC * 2);   // xpe -> xckv(lo) -> r1(raw)
    u16* slotE = (u16*)AL((size_t)BMTOT * CC * 2 + 1591296); // xckv(hi) + pad spill
    u16* slotG = (u16*)AL((size_t)BMTOT * 512 * 2);  // vh -> y1bf
    u16* pos   = (u16*)AL((size_t)BB * NHH * PTS * MM * 2 * 2);
    float* part  = (float*)AL(512 * 8 * 2 * 4);
    float* pmax  = (float*)AL(512 * 256 * 4);
    float* psum  = (float*)AL(512 * 256 * 4);
    float* gate  = (float*)AL(2 * 256 * 4);
    float2* stats_t  = (float2*)AL(2 * sizeof(float2));
    float2* stats_g1 = (float2*)AL(16 * sizeof(float2));
    float2* stats_g2 = (float2*)AL(2 * sizeof(float2));

    u16* qpe = slotA;  u16* attno = slotA;
    u16* t_b = slotC;  u16* xc  = slotC;
    u16* qp  = slotD;
    u16* xpe = slotB;
    u16* xckv = slotB;                       // spans slotB+slotE (35.1 MB padded)
    u16* r1  = slotB;                        // raw r1 after attn (xckv dead)
    u16* vh  = slotG;  u16* y1bf = slotG;
    u16* kh  = (u16*)d_out;                  // 33.5 MB, dead before final_kernel
    float* y2 = (float*)slotA;               // spans slotA+slotC (contiguous)

    if (off > ws_size) {                     // ws too small: absmax ~1000 signals it
        sentinel_kernel<<<1, 256, 0, stream>>>(out);
        return;
    }

    prep_kernel<<<3329, 256, 0, stream>>>(off_w1, wq, wx, ffn_w2,
                                          zp, w1t, wqb, wxb, fw2b);
    addpe_kernel<<<dim3(256, 4, 2), 256, 0, stream>>>(q_in, x_in, qpe, xpe);

    // conv_offset 3x3 (implicit im2col) -> t
    gemm_bt<1, 1><<<dim3(256, 2), 256, 0, stream>>>(qpe, w1t, off_b1, t_b, 2304, 256, zp);
    stats1_bf_kernel<<<512, 256, 0, stream>>>(t_b, part);
    stats2_kernel<<<1, 256, 0, stream>>>(part, stats_t, 1);
    offset_kernel<<<8192, 256, 0, stream>>>(t_b, stats_t, off_gn_g, off_gn_b, off_w2, pos);

    // qp projection (after conv GEMM so slotC reuse is safe)
    gemm_bt<0, 1><<<dim3(256, 2), 256, 0, stream>>>(qpe, wqb, nullptr, qp, 256, 256, zp);
    // x branch: conv -> xc (overwrites t, which is now dead)
    gemm_bt<0, 1><<<dim3(256, 2), 256, 0, stream>>>(xpe, wxb, nullptr, xc, 256, 256, zp);
    pool1_kernel<<<512, 256, 0, stream>>>(xc, pmax, psum);
    pool2_gate_kernel<<<2, 256, 0, stream>>>(pmax, psum, ca_w, gate);
    scalekv_kernel<<<2048, 256, 0, stream>>>(wkh, wvh, gate, wkhs, wvhs);
    // padded k/v maps (xpe dead after xc gemm; xckv overwrites slotB+slotE)
    padzero_kernel<<<1555, 256, 0, stream>>>(xckv);
    projkv_kernel<<<1024, 256, 0, stream>>>(xc, wk, wv, xckv);

    // kh/vh GEMMs with gate-folded per-batch weights
    for (int b = 0; b < 2; ++b) {
        gemm_bt<0, 1><<<dim3(128, 4), 256, 0, stream>>>(
            xc + (size_t)b * MM * CC, wkhs + (size_t)b * 131072, nullptr,
            kh + (size_t)b * MM * 512, 256, 512, zp);
        gemm_bt<0, 1><<<dim3(128, 4), 256, 0, stream>>>(
            xc + (size_t)b * MM * CC, wvhs + (size_t)b * 131072, nullptr,
            vh + (size_t)b * MM * 512, 256, 512, zp);
    }

    // fused deformable attention (padded map, no bounds checks)
    attn_kernel<<<dim3(512, 16), 256, 0, stream>>>(qp, xckv, kh, vh, pos, attno);

    // out proj + residual -> raw r1; GN1 stats; GN1 applied inline downstream
    r1_kernel<<<1024, 256, 0, stream>>>(attno, w_out, b_out, x_in, r1);
    stats1_bf_kernel<<<512, 256, 0, stream>>>(r1, part);
    stats2_kernel<<<1, 256, 0, stream>>>(part, stats_g1, 8);

    // FFN (GN1 inline)
    ffn1_kernel<<<1024, 256, 0, stream>>>(r1, stats_g1, gn1_g, gn1_b,
                                          ffn_w1, ffn_b1, y1bf);
    gemm_bt<0, 0><<<dim3(256, 2), 256, 0, stream>>>(y1bf, fw2b, ffn_b2, y2, 512, 256, zp);

    // GN2 stats over y2 + GN1(r1); final normalize + transpose
    stats1_mix_kernel<<<512, 256, 0, stream>>>(y2, r1, stats_g1, gn1_g, gn1_b, part);
    stats2_kernel<<<1, 256, 0, stream>>>(part, stats_g2, 1);
    final_kernel<<<dim3(256, 4, 2), 256, 0, stream>>>(y2, r1, stats_g1, gn1_g, gn1_b,
                                                      stats_g2, gn2_g, gn2_b, out);
}

// Round 13
// 590.764 us; speedup vs baseline: 1.6287x; 1.0096x over previous
//
#include <hip/hip_runtime.h>
#include <hip/hip_bf16.h>
#include <math.h>

typedef unsigned short u16;
typedef __attribute__((ext_vector_type(8))) unsigned short u16v8;
typedef __attribute__((ext_vector_type(8))) __bf16 bf16v8;
typedef __attribute__((ext_vector_type(4))) float f32v4;

#define BB 2
#define MM 16384           // H*W
#define CC 256
#define NHH 8
#define PTS 4
#define BMTOT 32768        // B*M
#define SCALEF 0.17677669529663687f
#define PECOEF 0.03597789207803197f   // ln(10000)/256
#define PD 131             // padded map dim (1 low, 2 high zero border)
#define PDPIX (PD*PD)      // 17161

__device__ __forceinline__ u16 f2bf(float f) {
    union { float f; unsigned u; } v; v.f = f;
    unsigned u = v.u;
    return (u16)((u + 0x7fffu + ((u >> 16) & 1u)) >> 16);
}
__device__ __forceinline__ float bf2f(u16 u) {
    union { unsigned u; float f; } v; v.u = ((unsigned)u) << 16; return v.f;
}
__device__ __forceinline__ float rsum32(float v) {
    #pragma unroll
    for (int m = 16; m; m >>= 1) v += __shfl_xor(v, m, 32);
    return v;
}
__device__ __forceinline__ void gload16(const void* g, void* l) {
    __builtin_amdgcn_global_load_lds(
        (const __attribute__((address_space(1))) void*)g,
        (__attribute__((address_space(3))) void*)l, 16, 0, 0);
}

// ---------------- prep: zero page + weight bf16 conversions ----------------
__global__ __launch_bounds__(256)
void prep_kernel(const float* __restrict__ off_w1, const float* __restrict__ wq,
                 const float* __restrict__ wx, const float* __restrict__ fw2,
                 u16* zp, u16* w1t, u16* wqb, u16* wxb, u16* fw2b)
{
    const size_t n_zp = 128, n_w1 = 589824, n_q = 65536, n_f2 = 131072;
    const size_t total = n_zp + n_w1 + 2 * n_q + n_f2;
    for (size_t i = (size_t)blockIdx.x * 256 + threadIdx.x; i < total;
         i += (size_t)gridDim.x * 256) {
        size_t j = i;
        if (j < n_zp) { zp[j] = 0; continue; }
        j -= n_zp;
        if (j < n_w1) {  // w1t[oc][tap*256+ic] = off_w1[oc][ic][tap]
            size_t oc = j / 2304, r = j % 2304, tap = r >> 8, ic = r & 255;
            w1t[j] = f2bf(off_w1[(oc * 256 + ic) * 9 + tap]);
            continue;
        }
        j -= n_w1;
        if (j < n_q) { wqb[j] = f2bf(wq[j] * SCALEF); continue; }
        j -= n_q;
        if (j < n_q) { wxb[j] = f2bf(wx[j]); continue; }
        j -= n_q;
        fw2b[j] = f2bf(fw2[j]);
    }
}

// ---------------- add positional encoding, transpose to pixel-major bf16 ----
__global__ __launch_bounds__(256)
void addpe_kernel(const float* __restrict__ q, const float* __restrict__ x,
                  u16* __restrict__ qpe, u16* __restrict__ xpe)
{
    __shared__ float lq[64][65], lx[64][65];
    const int m0 = blockIdx.x * 64, c0 = blockIdx.y * 64, b = blockIdx.z;
    const int tid = threadIdx.x;
    {
        const int ml = tid & 63, c4 = tid >> 6;
        for (int s = 0; s < 16; ++s) {
            int cl = s * 4 + c4;
            int c = c0 + cl, m = m0 + ml;
            float dv = __expf(-(float)(c & ~1) * PECOEF);
            float a = (float)m * dv;
            float pe = (c & 1) ? __cosf(a) : __sinf(a);
            size_t gi = ((size_t)b * CC + c) * MM + m;
            lq[cl][ml] = q[gi] + pe;
            lx[cl][ml] = x[gi] + pe;
        }
    }
    __syncthreads();
    {
        const int cl = tid & 63, m4 = tid >> 6;
        for (int s = 0; s < 16; ++s) {
            int ml = s * 4 + m4;
            size_t oi = ((size_t)b * MM + m0 + ml) * CC + c0 + cl;
            qpe[oi] = f2bf(lq[cl][ml]);
            xpe[oi] = f2bf(lx[cl][ml]);
        }
    }
}

// ---------------- bf16 MFMA GEMM, 64x128 tile (4 blocks/CU) -----------------
// C[row,col] = sum_k A[row,k]*W[col,k] (+bias)
// AMODE 0: A row-major bf16. AMODE 1: implicit im2col 3x3 pad=1.
// OUTBF: 1 -> store bf16, 0 -> store fp32.
template<int AMODE, int OUTBF>
__global__ __launch_bounds__(256, 4)
void gemm_bt(const u16* __restrict__ A, const u16* __restrict__ Bw,
             const float* __restrict__ bias, void* __restrict__ Cout,
             int K, int N, const u16* __restrict__ zp)
{
    __shared__ u16 lA[64 * 32];     // 4 KB
    __shared__ u16 lB[128 * 32];    // 8 KB
    const int tid = threadIdx.x;
    const int w = tid >> 6, l = tid & 63;
    const int gm = blockIdx.x, gn = blockIdx.y;
    const int wm = w >> 1, wn = w & 1;   // wave -> (row-half, col-half)
    const int rowIn = l >> 2;            // 0..15 within 16-row segment
    const int kc = (l & 3) << 3;         // k offset 0,8,16,24
    f32v4 acc[2][4] = {};

    for (int k0 = 0; k0 < K; k0 += 32) {
        // A: 64 rows = 4 segments; wave w stages segment w
        {
            const int row = w * 16 + rowIn;     // 0..63
            const u16* gpA;
            if (AMODE == 0) {
                gpA = A + (size_t)(gm * 64 + row) * K + (k0 + kc);
            } else {
                int grow = gm * 64 + row;
                int bimg = grow >> 14, m = grow & 16383;
                int y = m >> 7, xx2 = m & 127;
                int kk2 = k0 + kc;
                int tap = kk2 >> 8, ic = kk2 & 255;
                int t3 = tap / 3;
                int py = y + t3 - 1, px = xx2 + (tap - t3 * 3) - 1;
                bool ok = ((unsigned)py < 128u) && ((unsigned)px < 128u);
                gpA = ok ? (A + (((size_t)((bimg << 14) + (py << 7) + px)) << 8) + ic) : zp;
            }
            gload16(gpA, lA + w * 512);
        }
        // B: 128 rows = 8 segments; wave w stages segments w and w+4
        #pragma unroll
        for (int r = 0; r < 2; ++r) {
            const int seg = r * 4 + w;          // 0..7
            const int row = seg * 16 + rowIn;   // 0..127
            gload16(Bw + (size_t)(gn * 128 + row) * K + (k0 + kc), lB + seg * 512);
        }
        __syncthreads();
        bf16v8 af[2], bf[4];
        #pragma unroll
        for (int i = 0; i < 2; ++i)
            af[i] = *(const bf16v8*)&lA[((wm << 5) + (i << 4) + (l & 15)) * 32 + ((l >> 4) << 3)];
        #pragma unroll
        for (int j = 0; j < 4; ++j)
            bf[j] = *(const bf16v8*)&lB[((wn << 6) + (j << 4) + (l & 15)) * 32 + ((l >> 4) << 3)];
        #pragma unroll
        for (int i = 0; i < 2; ++i)
            #pragma unroll
            for (int j = 0; j < 4; ++j)
                acc[i][j] = __builtin_amdgcn_mfma_f32_16x16x32_bf16(af[i], bf[j], acc[i][j], 0, 0, 0);
        __syncthreads();
    }

    const int l15 = l & 15, l4 = l >> 4;
    #pragma unroll
    for (int i = 0; i < 2; ++i) {
        int row = gm * 64 + (wm << 5) + (i << 4) + (l4 << 2);
        #pragma unroll
        for (int j = 0; j < 4; ++j) {
            int col = gn * 128 + (wn << 6) + (j << 4) + l15;
            float bv = bias ? bias[col] : 0.0f;
            #pragma unroll
            for (int r = 0; r < 4; ++r) {
                float val = acc[i][j][r] + bv;
                if (OUTBF) ((u16*)Cout)[(size_t)(row + r) * N + col] = f2bf(val);
                else       ((float*)Cout)[(size_t)(row + r) * N + col] = val;
            }
        }
    }
}

// ---------------- GN stats stage 1, 64-pixel chunks (grid 512) --------------
__global__ __launch_bounds__(256)
void stats1_bf_kernel(const u16* __restrict__ a, float* __restrict__ part)
{
    __shared__ float ls[256], lss[256];
    const int blk = blockIdx.x;
    const size_t base = (size_t)blk * 64 * CC;
    const int tid = threadIdx.x;
    float s = 0.f, ss = 0.f;
    for (int p = 0; p < 64; ++p) {
        float v = bf2f(a[base + (size_t)p * CC + tid]);
        s += v; ss += v * v;
    }
    ls[tid] = s; lss[tid] = ss;
    __syncthreads();
    if (tid < 8) {
        float S = 0.f, SS = 0.f;
        for (int j = 0; j < 32; ++j) { S += ls[tid * 32 + j]; SS += lss[tid * 32 + j]; }
        part[(blk * 8 + tid) * 2] = S;
        part[(blk * 8 + tid) * 2 + 1] = SS;
    }
}

// stage 1, fp32 y2 + inline-GN1(raw r1), 64-pixel chunks (grid 512)
__global__ __launch_bounds__(256)
void stats1_mix_kernel(const float* __restrict__ a, const u16* __restrict__ r1raw,
                       const float2* __restrict__ st1, const float* __restrict__ g1g,
                       const float* __restrict__ g1b, float* __restrict__ part)
{
    __shared__ float ls[256], lss[256];
    const int blk = blockIdx.x;
    const int bb = blk >> 8;
    const size_t base = (size_t)blk * 64 * CC;
    const int tid = threadIdx.x;
    const float2 st = st1[bb * 8 + (tid >> 5)];
    const float gg = g1g[tid] * st.y;
    const float gb = g1b[tid] - st.x * st.y * g1g[tid];
    float s = 0.f, ss = 0.f;
    for (int p = 0; p < 64; ++p) {
        float v = a[base + (size_t)p * CC + tid]
                + bf2f(r1raw[base + (size_t)p * CC + tid]) * gg + gb;
        s += v; ss += v * v;
    }
    ls[tid] = s; lss[tid] = ss;
    __syncthreads();
    if (tid < 8) {
        float S = 0.f, SS = 0.f;
        for (int j = 0; j < 32; ++j) { S += ls[tid * 32 + j]; SS += lss[tid * 32 + j]; }
        part[(blk * 8 + tid) * 2] = S;
        part[(blk * 8 + tid) * 2 + 1] = SS;
    }
}

// stage 2: reduce 256 chunks/batch with parallel threads (launch <<<1,256>>>)
__global__ __launch_bounds__(256)
void stats2_kernel(const float* __restrict__ part, float2* __restrict__ stats, int NG)
{
    __shared__ float ls[256], lss[256];
    const int P = 2 * NG, TP = 256 / P;
    const int t = threadIdx.x;
    const int pr = t / TP, sub = t % TP;
    const int bb = pr / NG, g = pr % NG;
    const int j0 = (NG == 8) ? g : 0, jn = (NG == 8) ? 1 : 8;
    float S = 0.f, SS = 0.f;
    for (int q = sub; q < 256; q += TP)
        for (int j = 0; j < jn; ++j) {
            int idx = ((bb * 256 + q) * 8 + j0 + j) * 2;
            S += part[idx]; SS += part[idx + 1];
        }
    ls[t] = S; lss[t] = SS;
    __syncthreads();
    if (sub == 0) {
        float S2 = 0.f, SS2 = 0.f;
        for (int k = 0; k < TP; ++k) { S2 += ls[pr * TP + k]; SS2 += lss[pr * TP + k]; }
        const float cnt = (256.0f / NG) * 16384.0f;
        float mu = S2 / cnt;
        float var = SS2 / cnt - mu * mu;
        stats[bb * NG + g] = make_float2(mu, rsqrtf(var + 1e-5f));
    }
}

// ---------------- conv_offset tail: GN(1)+ReLU -> grouped 1x1 -> tanh -------
__global__ __launch_bounds__(256)
void offset_kernel(const u16* __restrict__ t, const float2* __restrict__ stats_t,
                   const float* __restrict__ gng, const float* __restrict__ gnb,
                   const float* __restrict__ w2, u16* __restrict__ pos)
{
    __shared__ float lt[4 * 256];
    const int tid = threadIdx.x;
    const int bm0 = blockIdx.x * 4;
    const int b = bm0 >> 14;
    const float2 st = stats_t[b];
    for (int idx = tid; idx < 1024; idx += 256) {
        int pix = idx >> 8, c = idx & 255;
        float v = bf2f(t[(size_t)(bm0 + pix) * CC + c]);
        v = (v - st.x) * st.y * gng[c] + gnb[c];
        lt[idx] = fmaxf(v, 0.0f);
    }
    __syncthreads();
    const int pix = tid >> 6, go = tid & 63;
    const int g = go >> 3, o = go & 7;
    float s = 0.f;
    #pragma unroll
    for (int ci = 0; ci < 32; ++ci) {
        int ce = (ci + g * 4) & 31;                 // bank rotation
        s += w2[(g * 8 + o) * 32 + ce] * lt[pix * 256 + g * 32 + ce];
    }
    const int m = (bm0 + pix) & 16383;
    const int p = o >> 1, c2 = o & 1;
    pos[((((size_t)b * NHH + g) * PTS + p) * MM + m) * 2 + c2] = f2bf(tanhf(s));
}

// ---------------- channel-attention pooling (grid 512) ----------------
__global__ __launch_bounds__(256)
void pool1_kernel(const u16* __restrict__ xc, float* __restrict__ pmax,
                  float* __restrict__ psum)
{
    const int blk = blockIdx.x;
    const size_t base = (size_t)blk * 64 * CC;
    const int tid = threadIdx.x;
    float mx = -1e30f, s = 0.f;
    for (int p = 0; p < 64; ++p) {
        float v = bf2f(xc[base + (size_t)p * CC + tid]);
        mx = fmaxf(mx, v); s += v;
    }
    pmax[blk * 256 + tid] = mx;
    psum[blk * 256 + tid] = s;
}

__global__ __launch_bounds__(256)
void pool2_gate_kernel(const float* __restrict__ pmax, const float* __restrict__ psum,
                       const float* __restrict__ ca_w, float* __restrict__ gate)
{
    __shared__ float sv[256];
    const int bb = blockIdx.x, tid = threadIdx.x;
    float mx = -1e30f, s = 0.f;
    for (int q = 0; q < 256; ++q) {
        mx = fmaxf(mx, pmax[(bb * 256 + q) * 256 + tid]);
        s += psum[(bb * 256 + q) * 256 + tid];
    }
    sv[tid] = mx + s * (1.0f / 16384.0f);   // mx + av
    __syncthreads();
    float acc = 0.f;
    for (int ci = 0; ci < 256; ++ci) acc += ca_w[tid * 256 + ci] * sv[ci];
    gate[bb * 256 + tid] = 1.0f / (1.0f + __expf(-acc));
}

// fold (1+gate[b,c]) into wkh/wvh columns, per batch -> bf16
__global__ __launch_bounds__(256)
void scalekv_kernel(const float* __restrict__ wkh, const float* __restrict__ wvh,
                    const float* __restrict__ gate, u16* __restrict__ wkhs,
                    u16* __restrict__ wvhs)
{
    const int n1 = 512 * 256;                   // per-batch weight count
    for (int i = blockIdx.x * 256 + threadIdx.x; i < 4 * n1;
         i += gridDim.x * 256) {
        int which = i / (2 * n1);               // 0: kh, 1: vh
        int r = i % (2 * n1);
        int b = r / n1, j = r % n1;
        float gsc = 1.0f + gate[b * 256 + (j & 255)];
        if (which == 0) wkhs[b * n1 + j] = f2bf(wkh[j] * gsc);
        else            wvhs[b * n1 + j] = f2bf(wvh[j] * gsc);
    }
}

// ---------------- zero the pad border of xckv (777 border pixels / batch) ---
__global__ __launch_bounds__(256)
void padzero_kernel(u16* __restrict__ xckv)
{
    const int total = 2 * 777 * 256;            // u32 writes
    for (int i = blockIdx.x * 256 + threadIdx.x; i < total;
         i += gridDim.x * 256) {
        int b = i / (777 * 256);
        int r = i % (777 * 256);
        int pix = r >> 8, w = r & 255;
        int py, px;
        if (pix < 393) {                        // rows 0, 129, 130 (full width)
            int rr = pix / PD;
            py = (rr == 0) ? 0 : (128 + rr);    // 0, 129, 130
            px = pix - rr * PD;
        } else {                                // cols 0, 129, 130 for rows 1..128
            int r2 = pix - 393;
            py = 1 + r2 / 3;
            int cc = r2 % 3;
            px = (cc == 0) ? 0 : (128 + cc);
        }
        *(unsigned*)&xckv[(((size_t)b * PDPIX + py * PD + px) << 9) + w * 2] = 0u;
    }
}

// ---------------- per-head projection maps, interleaved k|v, padded layout --
__global__ __launch_bounds__(256)
void projkv_kernel(const u16* __restrict__ xc, const float* __restrict__ wk,
                   const float* __restrict__ wv, u16* __restrict__ xckv)
{
    __shared__ float la[256];
    const int tid = threadIdx.x;
    const int g = tid >> 5;
    float wkr[32], wvr[32];
    #pragma unroll
    for (int dd = 0; dd < 32; ++dd) {
        wkr[dd] = wk[tid * 32 + dd];   // wk[(nh*32+d)*32+e]
        wvr[dd] = wv[tid * 32 + dd];
    }
    const int m0 = blockIdx.x * 32;
    for (int i = 0; i < 32; ++i) {
        const size_t bm = m0 + i;
        la[tid] = bf2f(xc[bm * CC + tid]);
        __syncthreads();
        float ok = 0.f, ov = 0.f;
        #pragma unroll
        for (int dd = 0; dd < 32; ++dd) {
            ok += wkr[dd] * la[g * 32 + dd];
            ov += wvr[dd] * la[g * 32 + dd];
        }
        unsigned pack = (unsigned)f2bf(ok) | ((unsigned)f2bf(ov) << 16);
        const int b = (int)(bm >> 14), m = (int)(bm & 16383);
        const int y = m >> 7, x = m & 127;
        *(unsigned*)&xckv[(((size_t)b * PDPIX + (y + 1) * PD + (x + 1)) << 9) + tid * 2] = pack;
        __syncthreads();
    }
}

// ---------------- fused deformable sampling + attention (padded, no guards) -
__global__ __launch_bounds__(256)
void attn_kernel(const u16* __restrict__ qp, const u16* __restrict__ xckv,
                 const u16* __restrict__ kh, const u16* __restrict__ vh,
                 const u16* __restrict__ pos, u16* __restrict__ attno)
{
    const int tid = threadIdx.x;
    const int g = tid >> 5, d = tid & 31;
    const int bh = blockIdx.y;
    const int b = bh >> 3, nh = bh & 7;
    const int co = nh * 32 + d;
    const size_t hb = (size_t)b * MM;
    const u16* xb = xckv + (((size_t)b * PDPIX) << 9) + co * 2;
    #pragma unroll
    for (int i = 0; i < 4; ++i) {
        const int m = blockIdx.x * 32 + i * 8 + g;
        const size_t bm = hb + m;
        const float qd = bf2f(qp[bm * CC + co]);   // pre-scaled by SCALEF
        const int yy = m >> 7, xx = m & 127;
        float kk[6], vv[6];
        #pragma unroll
        for (int p = 0; p < 4; ++p) {
            unsigned pxy = *(const unsigned*)&pos[((((size_t)b * NHH + nh) * PTS + p) * MM + m) * 2];
            float gy = (float)yy + 0.5f + bf2f((u16)pxy);
            float gx = (float)xx + 0.5f + bf2f((u16)(pxy >> 16));
            float fy0 = floorf(gy), fx0 = floorf(gx);
            int iy0 = (int)fy0, ix0 = (int)fx0;
            float fx = gx - fx0, fy = gy - fy0;
            float w00 = (1.f - fx) * (1.f - fy), w10 = fx * (1.f - fy);
            float w01 = (1.f - fx) * fy, w11 = fx * fy;
            const u16* t0 = xb + ((size_t)((iy0 + 1) * PD + ix0 + 1) << 9);
            unsigned kv00 = *(const unsigned*)t0;
            unsigned kv10 = *(const unsigned*)(t0 + 512);
            unsigned kv01 = *(const unsigned*)(t0 + PD * 512);
            unsigned kv11 = *(const unsigned*)(t0 + PD * 512 + 512);
            kk[p] = w00 * bf2f((u16)kv00) + w10 * bf2f((u16)kv10)
                  + w01 * bf2f((u16)kv01) + w11 * bf2f((u16)kv11);
            vv[p] = w00 * bf2f((u16)(kv00 >> 16)) + w10 * bf2f((u16)(kv10 >> 16))
                  + w01 * bf2f((u16)(kv01 >> 16)) + w11 * bf2f((u16)(kv11 >> 16));
        }
        #pragma unroll
        for (int p = 0; p < 2; ++p) {
            kk[4 + p] = bf2f(kh[bm * 512 + nh * 64 + p * 32 + d]);
            vv[4 + p] = bf2f(vh[bm * 512 + nh * 64 + p * 32 + d]);
        }
        float s[6];
        #pragma unroll
        for (int p = 0; p < 6; ++p) s[p] = rsum32(qd * kk[p]);
        float mx = s[0];
        #pragma unroll
        for (int p = 1; p < 6; ++p) mx = fmaxf(mx, s[p]);
        float es[6], ssum = 0.f;
        #pragma unroll
        for (int p = 0; p < 6; ++p) { es[p] = __expf(s[p] - mx); ssum += es[p]; }
        const float inv = 1.0f / ssum;
        float od = 0.f;
        #pragma unroll
        for (int p = 0; p < 6; ++p) od += es[p] * inv * vv[p];
        attno[bm * CC + co] = f2bf(od);
    }
}

// ---------------- r1 v2: tiled, barrier-free (32 pixels/block, grid 1024) ---
__global__ __launch_bounds__(256)
void r1_kernel(const u16* __restrict__ attno, const float* __restrict__ w_out,
               const float* __restrict__ b_out, const float* __restrict__ x_in,
               u16* __restrict__ r1)
{
    __shared__ u16 lx[256][36];    // x (bf16), [c][pix], padded stride
    __shared__ u16 lat[32][256];   // attno, [pix][c]
    const int tid = threadIdx.x;
    const int m0 = blockIdx.x * 32;
    const int b = m0 >> 14;
    const int mloc = m0 & 16383;
    // x tile: coalesced float4 along m
    {
        const int ml4 = (tid & 7) * 4, c32 = tid >> 3;
        for (int s = 0; s < 8; ++s) {
            int cl = s * 32 + c32;
            float4 v = *(const float4*)&x_in[((size_t)b * CC + cl) * MM + mloc + ml4];
            ushort4 sv = { f2bf(v.x), f2bf(v.y), f2bf(v.z), f2bf(v.w) };
            *(ushort4*)&lx[cl][ml4] = sv;
        }
    }
    // attno tile: uint4 copies (layout matches linear)
    {
        const uint4* src4 = (const uint4*)(attno + (size_t)m0 * CC);
        uint4* dst4 = (uint4*)&lat[0][0];
        #pragma unroll
        for (int s = 0; s < 4; ++s) dst4[s * 256 + tid] = src4[s * 256 + tid];
    }
    __syncthreads();
    const int g = tid >> 5;
    float wr[32];
    #pragma unroll
    for (int dd = 0; dd < 32; ++dd) wr[dd] = w_out[tid * 32 + dd];
    const float bo = b_out[tid];
    for (int i = 0; i < 32; ++i) {
        float o = bo + bf2f(lx[tid][i]);
        #pragma unroll
        for (int dd = 0; dd < 32; ++dd) o += wr[dd] * bf2f(lat[i][g * 32 + dd]);
        r1[(size_t)(m0 + i) * CC + tid] = f2bf(o);
    }
}

// ---------------- ffn1 v2: tiled, GN1 affine at load, barrier-free ----------
__global__ __launch_bounds__(256)
void ffn1_kernel(const u16* __restrict__ r1raw, const float2* __restrict__ st1,
                 const float* __restrict__ g1g, const float* __restrict__ g1b,
                 const float* __restrict__ w1, const float* __restrict__ b1,
                 u16* __restrict__ y1bf)
{
    __shared__ u16 ln[32][256];   // GN1-applied r1, [pix][c]
    const int tid = threadIdx.x;
    const int m0 = blockIdx.x * 32;
    const int b = m0 >> 14;
    {
        const uint4* src4 = (const uint4*)(r1raw + (size_t)m0 * CC);
        uint4* dst4 = (uint4*)&ln[0][0];
        const int cbase = (tid & 31) * 8;
        const float2 st = st1[b * 8 + (cbase >> 5)];
        float ga[8], bb2[8];
        #pragma unroll
        for (int k = 0; k < 8; ++k) {
            ga[k] = g1g[cbase + k] * st.y;
            bb2[k] = g1b[cbase + k] - st.x * st.y * g1g[cbase + k];
        }
        #pragma unroll
        for (int s = 0; s < 4; ++s) {
            uint4 v = src4[s * 256 + tid];
            unsigned wv[4] = { v.x, v.y, v.z, v.w };
            unsigned ow[4];
            #pragma unroll
            for (int q = 0; q < 4; ++q) {
                float lo = bf2f((u16)wv[q]) * ga[2 * q] + bb2[2 * q];
                float hi = bf2f((u16)(wv[q] >> 16)) * ga[2 * q + 1] + bb2[2 * q + 1];
                ow[q] = (unsigned)f2bf(lo) | ((unsigned)f2bf(hi) << 16);
            }
            uint4 o4; o4.x = ow[0]; o4.y = ow[1]; o4.z = ow[2]; o4.w = ow[3];
            dst4[s * 256 + tid] = o4;
        }
    }
    __syncthreads();
    float wr0[32], wr1[32];
    #pragma unroll
    for (int dd = 0; dd < 32; ++dd) {
        wr0[dd] = w1[tid * 32 + dd];
        wr1[dd] = w1[(tid + 256) * 32 + dd];
    }
    const float bb0 = b1[tid], bb1 = b1[tid + 256];
    const int g0 = tid >> 6, g1 = 4 + (tid >> 6);
    for (int i = 0; i < 32; ++i) {
        float o0 = bb0, o1 = bb1;
        #pragma unroll
        for (int dd = 0; dd < 32; ++dd) {
            o0 += wr0[dd] * bf2f(ln[i][g0 * 32 + dd]);
            o1 += wr1[dd] * bf2f(ln[i][g1 * 32 + dd]);
        }
        y1bf[(size_t)(m0 + i) * 512 + tid] = f2bf(fmaxf(o0, 0.f));
        y1bf[(size_t)(m0 + i) * 512 + tid + 256] = f2bf(fmaxf(o1, 0.f));
    }
}

// ---------------- final: GN2( y2 + GN1(r1) ) + transpose to NCHW ------------
__global__ __launch_bounds__(256)
void final_kernel(const float* __restrict__ y2, const u16* __restrict__ r1raw,
                  const float2* __restrict__ st1, const float* __restrict__ g1g,
                  const float* __restrict__ g1b, const float2* __restrict__ stats,
                  const float* __restrict__ gg, const float* __restrict__ gb,
                  float* __restrict__ out)
{
    __shared__ float lt[64][65];
    const int m0 = blockIdx.x * 64, c0 = blockIdx.y * 64, b = blockIdx.z;
    const int tid = threadIdx.x;
    const float2 st = stats[b];
    {
        const int cl = tid & 63, m4 = tid >> 6;
        const int c = c0 + cl;
        const float2 s1 = st1[b * 8 + (c >> 5)];
        const float g1 = g1g[c], b1 = g1b[c];
        for (int s = 0; s < 16; ++s) {
            int ml = s * 4 + m4;
            size_t idx = ((size_t)b * MM + m0 + ml) * CC + c;
            float rv = (bf2f(r1raw[idx]) - s1.x) * s1.y * g1 + b1;
            float v = y2[idx] + rv;
            lt[cl][ml] = (v - st.x) * st.y * gg[c] + gb[c];
        }
    }
    __syncthreads();
    {
        const int mlw = tid & 63, c4 = tid >> 6;
        for (int s = 0; s < 16; ++s) {
            int clw = s * 4 + c4;
            out[((size_t)b * CC + c0 + clw) * MM + m0 + mlw] = lt[clw][mlw];
        }
    }
}

// diagnostic: written iff workspace is too small (absmax ~1000 signals it)
__global__ void sentinel_kernel(float* out) { out[threadIdx.x] = 1000.0f; }

// ============================ host side ============================
extern "C" void kernel_launch(void* const* d_in, const int* in_sizes, int n_in,
                              void* d_out, int out_size, void* d_ws, size_t ws_size,
                              hipStream_t stream)
{
    const float* q_in   = (const float*)d_in[0];
    const float* x_in   = (const float*)d_in[1];
    const float* off_w1 = (const float*)d_in[2];
    const float* off_b1 = (const float*)d_in[3];
    const float* off_gn_g = (const float*)d_in[4];
    const float* off_gn_b = (const float*)d_in[5];
    const float* off_w2 = (const float*)d_in[6];
    const float* wq     = (const float*)d_in[7];
    const float* wk     = (const float*)d_in[8];
    const float* wv     = (const float*)d_in[9];
    const float* wx     = (const float*)d_in[10];
    const float* w_out  = (const float*)d_in[11];
    const float* b_out  = (const float*)d_in[12];
    const float* wkh    = (const float*)d_in[13];
    const float* wvh    = (const float*)d_in[14];
    const float* ca_w   = (const float*)d_in[15];
    const float* gn1_g  = (const float*)d_in[16];
    const float* gn1_b  = (const float*)d_in[17];
    const float* ffn_w1 = (const float*)d_in[18];
    const float* ffn_b1 = (const float*)d_in[19];
    const float* ffn_w2 = (const float*)d_in[20];
    const float* ffn_b2 = (const float*)d_in[21];
    const float* gn2_g  = (const float*)d_in[22];
    const float* gn2_b  = (const float*)d_in[23];
    float* out = (float*)d_out;

    char* W = (char*)d_ws;
    size_t off = 0;
    auto AL = [&](size_t sz) -> char* {
        char* p = W + off;
        off += (sz + 255) & ~(size_t)255;
        return p;
    };
    u16* zp    = (u16*)AL(256);
    u16* w1t   = (u16*)AL(589824 * 2);
    u16* wqb   = (u16*)AL(65536 * 2);
    u16* wxb   = (u16*)AL(65536 * 2);
    u16* fw2b  = (u16*)AL(131072 * 2);
    u16* wkhs  = (u16*)AL(2 * 131072 * 2);     // per-batch gate-folded
    u16* wvhs  = (u16*)AL(2 * 131072 * 2);
    u16* slotA = (u16*)AL((size_t)BMTOT * CC * 2);   // qpe -> attno -> y2(lo)
    u16* slotC = (u16*)AL((size_t)BMTOT * CC * 2);   // t -> xc -> y2(hi)
    u16* slotD = (u16*)AL((size_t)BMTOT * CC * 2);   // qp
    u16* slotB = (u16*)AL((size_t)BMTOT * CC * 2);   // xpe -> xckv(lo) -> r1(raw)
    u16* slotE = (u16*)AL((size_t)BMTOT * CC * 2 + 1591296); // xckv(hi) + pad spill
    u16* slotG = (u16*)AL((size_t)BMTOT * 512 * 2);  // vh -> y1bf
    u16* pos   = (u16*)AL((size_t)BB * NHH * PTS * MM * 2 * 2);
    float* part  = (float*)AL(512 * 8 * 2 * 4);
    float* pmax  = (float*)AL(512 * 256 * 4);
    float* psum  = (float*)AL(512 * 256 * 4);
    float* gate  = (float*)AL(2 * 256 * 4);
    float2* stats_t  = (float2*)AL(2 * sizeof(float2));
    float2* stats_g1 = (float2*)AL(16 * sizeof(float2));
    float2* stats_g2 = (float2*)AL(2 * sizeof(float2));

    u16* qpe = slotA;  u16* attno = slotA;
    u16* t_b = slotC;  u16* xc  = slotC;
    u16* qp  = slotD;
    u16* xpe = slotB;
    u16* xckv = slotB;                       // spans slotB+slotE (35.1 MB padded)
    u16* r1  = slotB;                        // raw r1 after attn (xckv dead)
    u16* vh  = slotG;  u16* y1bf = slotG;
    u16* kh  = (u16*)d_out;                  // 33.5 MB, dead before final_kernel
    float* y2 = (float*)slotA;               // spans slotA+slotC (contiguous)

    if (off > ws_size) {                     // ws too small: absmax ~1000 signals it
        sentinel_kernel<<<1, 256, 0, stream>>>(out);
        return;
    }

    prep_kernel<<<3329, 256, 0, stream>>>(off_w1, wq, wx, ffn_w2,
                                          zp, w1t, wqb, wxb, fw2b);
    addpe_kernel<<<dim3(256, 4, 2), 256, 0, stream>>>(q_in, x_in, qpe, xpe);

    // conv_offset 3x3 (implicit im2col) -> t   [64x128 tile: grid 512x2]
    gemm_bt<1, 1><<<dim3(512, 2), 256, 0, stream>>>(qpe, w1t, off_b1, t_b, 2304, 256, zp);
    stats1_bf_kernel<<<512, 256, 0, stream>>>(t_b, part);
    stats2_kernel<<<1, 256, 0, stream>>>(part, stats_t, 1);
    offset_kernel<<<8192, 256, 0, stream>>>(t_b, stats_t, off_gn_g, off_gn_b, off_w2, pos);

    // qp projection (after conv GEMM so slotC reuse is safe)
    gemm_bt<0, 1><<<dim3(512, 2), 256, 0, stream>>>(qpe, wqb, nullptr, qp, 256, 256, zp);
    // x branch: conv -> xc (overwrites t, which is now dead)
    gemm_bt<0, 1><<<dim3(512, 2), 256, 0, stream>>>(xpe, wxb, nullptr, xc, 256, 256, zp);
    pool1_kernel<<<512, 256, 0, stream>>>(xc, pmax, psum);
    pool2_gate_kernel<<<2, 256, 0, stream>>>(pmax, psum, ca_w, gate);
    scalekv_kernel<<<2048, 256, 0, stream>>>(wkh, wvh, gate, wkhs, wvhs);
    // padded k/v maps (xpe dead after xc gemm; xckv overwrites slotB+slotE)
    padzero_kernel<<<1555, 256, 0, stream>>>(xckv);
    projkv_kernel<<<1024, 256, 0, stream>>>(xc, wk, wv, xckv);

    // kh/vh GEMMs with gate-folded per-batch weights [grid 256x4]
    for (int b = 0; b < 2; ++b) {
        gemm_bt<0, 1><<<dim3(256, 4), 256, 0, stream>>>(
            xc + (size_t)b * MM * CC, wkhs + (size_t)b * 131072, nullptr,
            kh + (size_t)b * MM * 512, 256, 512, zp);
        gemm_bt<0, 1><<<dim3(256, 4), 256, 0, stream>>>(
            xc + (size_t)b * MM * CC, wvhs + (size_t)b * 131072, nullptr,
            vh + (size_t)b * MM * 512, 256, 512, zp);
    }

    // fused deformable attention (padded map, no bounds checks)
    attn_kernel<<<dim3(512, 16), 256, 0, stream>>>(qp, xckv, kh, vh, pos, attno);

    // out proj + residual -> raw r1; GN1 stats; GN1 applied inline downstream
    r1_kernel<<<1024, 256, 0, stream>>>(attno, w_out, b_out, x_in, r1);
    stats1_bf_kernel<<<512, 256, 0, stream>>>(r1, part);
    stats2_kernel<<<1, 256, 0, stream>>>(part, stats_g1, 8);

    // FFN (GN1 inline)
    ffn1_kernel<<<1024, 256, 0, stream>>>(r1, stats_g1, gn1_g, gn1_b,
                                          ffn_w1, ffn_b1, y1bf);
    gemm_bt<0, 0><<<dim3(512, 2), 256, 0, stream>>>(y1bf, fw2b, ffn_b2, y2, 512, 256, zp);

    // GN2 stats over y2 + GN1(r1); final normalize + transpose
    stats1_mix_kernel<<<512, 256, 0, stream>>>(y2, r1, stats_g1, gn1_g, gn1_b, part);
    stats2_kernel<<<1, 256, 0, stream>>>(part, stats_g2, 1);
    final_kernel<<<dim3(256, 4, 2), 256, 0, stream>>>(y2, r1, stats_g1, gn1_g, gn1_b,
                                                      stats_g2, gn2_g, gn2_b, out);
}